// Round 1
// baseline (1365.311 us; speedup 1.0000x reference)
//
#include <hip/hip_runtime.h>
#include <math.h>

#define B_ 4
#define N_ 1024
#define C_ 1024
#define H_ 16
#define D_ 64
#define P_ 5
#define BN_ (B_*N_)

__device__ __forceinline__ float gelu_f(float x){
  float x3 = x*x*x;
  return 0.5f*x*(1.0f + tanhf(0.7978845608028654f*(x + 0.044715f*x3)));
}
__device__ __forceinline__ float sigmoid_f(float x){ return 1.0f/(1.0f+expf(-x)); }

// ---------------- generic tiled fp32 GEMM: C = A(M,K)@W(K,Nn) (+bias, +gelu) ----
// 64x64 tile, BK=16, 256 threads, 4x4 per-thread microtile. All dims %64==0, K%16==0.
template<int ACT>
__global__ __launch_bounds__(256) void gemm64(const float* __restrict__ A,
    const float* __restrict__ W, const float* __restrict__ bias,
    float* __restrict__ Cout, int M, int Nn, int K) {
  __shared__ __align__(16) float sA[16][68];
  __shared__ __align__(16) float sB[16][68];
  const int tid = threadIdx.x;
  const int tx = tid & 15, ty = tid >> 4;
  const int row0 = blockIdx.y * 64, col0 = blockIdx.x * 64;
  const int lm = tid >> 2, lk = (tid & 3) << 2;   // A: row lm, k lk..lk+3
  const int lb = tid >> 4, lc = (tid & 15) << 2;  // B: k lb, col lc..lc+3
  float acc[4][4] = {};
  for (int k0 = 0; k0 < K; k0 += 16) {
    float4 av = *(const float4*)(A + (size_t)(row0 + lm) * K + k0 + lk);
    sA[lk+0][lm] = av.x; sA[lk+1][lm] = av.y; sA[lk+2][lm] = av.z; sA[lk+3][lm] = av.w;
    float4 bv = *(const float4*)(W + (size_t)(k0 + lb) * Nn + col0 + lc);
    *(float4*)(&sB[lb][lc]) = bv;
    __syncthreads();
    #pragma unroll
    for (int kk = 0; kk < 16; ++kk) {
      float a0[4], b0[4];
      *(float4*)a0 = *(const float4*)(&sA[kk][ty << 2]);
      *(float4*)b0 = *(const float4*)(&sB[kk][tx << 2]);
      #pragma unroll
      for (int i = 0; i < 4; ++i)
        #pragma unroll
        for (int j = 0; j < 4; ++j) acc[i][j] = fmaf(a0[i], b0[j], acc[i][j]);
    }
    __syncthreads();
  }
  #pragma unroll
  for (int i = 0; i < 4; ++i) {
    int r = row0 + (ty << 2) + i;
    #pragma unroll
    for (int j = 0; j < 4; ++j) {
      int c = col0 + (tx << 2) + j;
      float v = acc[i][j] + (bias ? bias[c] : 0.0f);
      if (ACT == 1) v = gelu_f(v);
      Cout[(size_t)r * Nn + c] = v;
    }
  }
}

// ---------------- skinny GEMM (Nn = 16 or 80): one block per row --------------
__global__ void gemm_small(const float* __restrict__ A, const float* __restrict__ W,
    const float* __restrict__ bias, float* __restrict__ Cout, int Nn, int K) {
  const int row = blockIdx.x;
  const int c = threadIdx.x;
  if (c >= Nn) return;
  const float* a = A + (size_t)row * K;
  float acc = bias[c];
  for (int k = 0; k < K; k += 4) {
    float4 a4 = *(const float4*)(a + k);
    acc = fmaf(a4.x, W[(size_t)(k+0)*Nn + c], acc);
    acc = fmaf(a4.y, W[(size_t)(k+1)*Nn + c], acc);
    acc = fmaf(a4.z, W[(size_t)(k+2)*Nn + c], acc);
    acc = fmaf(a4.w, W[(size_t)(k+3)*Nn + c], acc);
  }
  Cout[(size_t)row * Nn + c] = acc;
}

// ---------------- DeltaNet: per-chunk prep (normalize, A, triangular solves) ---
// block = (bh*16 + g); normalizes q (in place, *0.125) and k (in place) in qkv,
// computes w = M^{-1} kb, u = M^{-1} (v*beta) with M = I + tril(kb k^T, -1).
__global__ __launch_bounds__(256) void delta_prep(float* __restrict__ qkv,
    float* __restrict__ gW, float* __restrict__ gU) {
  const int bx = blockIdx.x;
  const int bh = bx >> 4, g = bx & 15;
  const int b = bh >> 4, h = bh & 15;
  const int n0 = g * 64;
  const int tid = threadIdx.x;
  __shared__ float sK[64][65];
  __shared__ float sV[64][65];
  __shared__ float sW[64][65];
  __shared__ float sM[64][65];
  __shared__ float sBeta[64];

  const size_t rowbase = (size_t)b * N_ + n0;
  for (int i = 0; i < 16; ++i) {
    int idx = tid + i * 256; int r = idx >> 6, d = idx & 63;
    size_t off = (rowbase + r) * 3072 + h * 64 + d;
    sK[r][d] = qkv[off + 1024];
    sV[r][d] = qkv[off + 2048];
  }
  if (tid < 64) sBeta[tid] = 1.0f - 0.9f * (float)(n0 + tid) / 1023.0f;
  __syncthreads();

  if (tid < 64) {            // q: l2norm * d^-0.5, in registers, write back
    size_t off = (rowbase + tid) * 3072 + h * 64;
    float4 qv[16]; float ss = 0.f;
    #pragma unroll
    for (int i = 0; i < 16; ++i) {
      qv[i] = *(const float4*)(qkv + off + 4*i);
      ss += qv[i].x*qv[i].x + qv[i].y*qv[i].y + qv[i].z*qv[i].z + qv[i].w*qv[i].w;
    }
    float sc = rsqrtf(ss + 1e-6f) * 0.125f;
    #pragma unroll
    for (int i = 0; i < 16; ++i) {
      float4 t = qv[i]; t.x *= sc; t.y *= sc; t.z *= sc; t.w *= sc;
      *(float4*)(qkv + off + 4*i) = t;
    }
  } else if (tid < 128) {    // k: l2norm in LDS
    int r = tid - 64; float ss = 0.f;
    for (int d = 0; d < 64; ++d) ss += sK[r][d] * sK[r][d];
    float sc = rsqrtf(ss + 1e-6f);
    for (int d = 0; d < 64; ++d) sK[r][d] *= sc;
  } else if (tid < 192) {    // v *= beta
    int r = tid - 128; float bt = sBeta[r];
    for (int d = 0; d < 64; ++d) sV[r][d] *= bt;
  }
  __syncthreads();

  // write normalized k back to qkv (scan/outk read it)
  for (int i = 0; i < 16; ++i) {
    int idx = tid + i * 256; int r = idx >> 6, d = idx & 63;
    qkv[(rowbase + r) * 3072 + 1024 + h * 64 + d] = sK[r][d];
  }
  // A = tril(beta_r * khat khat^T, -1)
  {
    const int tx = tid & 15, ty = tid >> 4;
    const int r0 = ty * 4, c0 = tx * 4;
    float acc[4][4] = {};
    #pragma unroll 4
    for (int d = 0; d < 64; ++d) {
      float a0[4], b0[4];
      #pragma unroll
      for (int i = 0; i < 4; ++i) a0[i] = sK[r0+i][d];
      #pragma unroll
      for (int j = 0; j < 4; ++j) b0[j] = sK[c0+j][d];
      #pragma unroll
      for (int i = 0; i < 4; ++i)
        #pragma unroll
        for (int j = 0; j < 4; ++j) acc[i][j] = fmaf(a0[i], b0[j], acc[i][j]);
    }
    #pragma unroll
    for (int i = 0; i < 4; ++i)
      #pragma unroll
      for (int j = 0; j < 4; ++j) {
        int r = r0 + i, c = c0 + j;
        sM[r][c] = (r > c) ? sBeta[r] * acc[i][j] : 0.f;
      }
  }
  __syncthreads();

  // forward substitution, one lane per RHS column (lane-independent, no barriers)
  if (tid < 64) {
    int c = tid;
    for (int i = 0; i < 64; ++i) {
      float acc = sBeta[i] * sK[i][c];   // kb RHS
      #pragma unroll 4
      for (int j = 0; j < i; ++j) acc -= sM[i][j] * sW[j][c];
      sW[i][c] = acc;
    }
  } else if (tid < 128) {
    int c = tid - 64;
    for (int i = 0; i < 64; ++i) {
      float acc = sV[i][c];              // v*beta RHS (in place)
      #pragma unroll 4
      for (int j = 0; j < i; ++j) acc -= sM[i][j] * sV[j][c];
      sV[i][c] = acc;
    }
  }
  __syncthreads();

  const size_t obase = (size_t)(bh * 16 + g) * 4096;
  for (int i = 0; i < 16; ++i) {
    int idx = tid + i * 256;
    gW[obase + idx] = sW[idx >> 6][idx & 63];
    gU[obase + idx] = sV[idx >> 6][idx & 63];
  }
}

// ---------------- DeltaNet: sequential chunk scan, stores S_g per chunk --------
__global__ __launch_bounds__(256) void delta_scan(const float* __restrict__ qkv,
    const float* __restrict__ gW, const float* __restrict__ gU,
    float* __restrict__ gS) {
  const int bh = blockIdx.x; const int b = bh >> 4, h = bh & 15;
  const int tid = threadIdx.x; const int tx = tid & 15, ty = tid >> 4;
  __shared__ float sS[64][65], sK[64][65], sW[64][65], sU[64][65];
  float Sreg[4][4] = {};
  const int e0 = ty * 4, d0 = tx * 4;
  for (int g = 0; g < 16; ++g) {
    const size_t obase = (size_t)(bh * 16 + g) * 4096;
    for (int i = 0; i < 16; ++i) {
      int idx = tid + i * 256; int r = idx >> 6, d = idx & 63;
      sK[r][d] = qkv[((size_t)b * N_ + g * 64 + r) * 3072 + 1024 + h * 64 + d];
      sW[r][d] = gW[obase + idx];
      sU[r][d] = gU[obase + idx];
    }
    #pragma unroll
    for (int i = 0; i < 4; ++i)
      #pragma unroll
      for (int j = 0; j < 4; ++j) {
        sS[e0+i][d0+j] = Sreg[i][j];
        gS[obase + (size_t)(e0+i) * 64 + d0 + j] = Sreg[i][j];
      }
    __syncthreads();
    // u_adj = U - W @ S   (in place into sU; each element owner-written)
    {
      float acc[4][4] = {};
      #pragma unroll 4
      for (int kk = 0; kk < 64; ++kk) {
        float a0[4], b0[4];
        #pragma unroll
        for (int i = 0; i < 4; ++i) a0[i] = sW[e0+i][kk];
        #pragma unroll
        for (int j = 0; j < 4; ++j) b0[j] = sS[kk][d0+j];
        #pragma unroll
        for (int i = 0; i < 4; ++i)
          #pragma unroll
          for (int j = 0; j < 4; ++j) acc[i][j] = fmaf(a0[i], b0[j], acc[i][j]);
      }
      #pragma unroll
      for (int i = 0; i < 4; ++i)
        #pragma unroll
        for (int j = 0; j < 4; ++j) sU[e0+i][d0+j] -= acc[i][j];
    }
    __syncthreads();
    // S += K^T @ u_adj
    #pragma unroll 4
    for (int c = 0; c < 64; ++c) {
      float a0[4], b0[4];
      #pragma unroll
      for (int i = 0; i < 4; ++i) a0[i] = sK[c][e0+i];
      #pragma unroll
      for (int j = 0; j < 4; ++j) b0[j] = sU[c][d0+j];
      #pragma unroll
      for (int i = 0; i < 4; ++i)
        #pragma unroll
        for (int j = 0; j < 4; ++j) Sreg[i][j] = fmaf(a0[i], b0[j], Sreg[i][j]);
    }
    __syncthreads();
  }
}

// ---------------- DeltaNet: per-chunk output o = q@S + tril(q k^T) @ u_adj ----
__global__ __launch_bounds__(256) void delta_outk(const float* __restrict__ qkv,
    const float* __restrict__ gW, const float* __restrict__ gU,
    const float* __restrict__ gS, float* __restrict__ dOut) {
  const int bx = blockIdx.x; const int bh = bx >> 4, g = bx & 15;
  const int b = bh >> 4, h = bh & 15;
  const int tid = threadIdx.x; const int tx = tid & 15, ty = tid >> 4;
  __shared__ float sQ[64][65], sK[64][65], sW[64][65], sU[64][65], sS[64][65], sA[64][65];
  const size_t obase = (size_t)(bh * 16 + g) * 4096;
  for (int i = 0; i < 16; ++i) {
    int idx = tid + i * 256; int r = idx >> 6, d = idx & 63;
    size_t qoff = ((size_t)b * N_ + g * 64 + r) * 3072 + h * 64 + d;
    sQ[r][d] = qkv[qoff];
    sK[r][d] = qkv[qoff + 1024];
    sW[r][d] = gW[obase + idx];
    sU[r][d] = gU[obase + idx];
    sS[r][d] = gS[obase + idx];
  }
  __syncthreads();
  const int r0 = ty * 4, c0 = tx * 4;
  // attn = tril(qhat khat^T) incl diagonal
  {
    float acc[4][4] = {};
    #pragma unroll 4
    for (int d = 0; d < 64; ++d) {
      float a0[4], b0[4];
      #pragma unroll
      for (int i = 0; i < 4; ++i) a0[i] = sQ[r0+i][d];
      #pragma unroll
      for (int j = 0; j < 4; ++j) b0[j] = sK[c0+j][d];
      #pragma unroll
      for (int i = 0; i < 4; ++i)
        #pragma unroll
        for (int j = 0; j < 4; ++j) acc[i][j] = fmaf(a0[i], b0[j], acc[i][j]);
    }
    #pragma unroll
    for (int i = 0; i < 4; ++i)
      #pragma unroll
      for (int j = 0; j < 4; ++j) {
        int r = r0 + i, c = c0 + j;
        sA[r][c] = (r >= c) ? acc[i][j] : 0.f;
      }
  }
  // u_adj = U - W @ S (in place)
  {
    float acc[4][4] = {};
    #pragma unroll 4
    for (int kk = 0; kk < 64; ++kk) {
      float a0[4], b0[4];
      #pragma unroll
      for (int i = 0; i < 4; ++i) a0[i] = sW[r0+i][kk];
      #pragma unroll
      for (int j = 0; j < 4; ++j) b0[j] = sS[kk][c0+j];
      #pragma unroll
      for (int i = 0; i < 4; ++i)
        #pragma unroll
        for (int j = 0; j < 4; ++j) acc[i][j] = fmaf(a0[i], b0[j], acc[i][j]);
    }
    #pragma unroll
    for (int i = 0; i < 4; ++i)
      #pragma unroll
      for (int j = 0; j < 4; ++j) sU[r0+i][c0+j] -= acc[i][j];
  }
  __syncthreads();
  // o = qhat @ S + attn @ u_adj
  {
    float acc[4][4] = {};
    #pragma unroll 4
    for (int kk = 0; kk < 64; ++kk) {
      float a0[4], b0[4];
      #pragma unroll
      for (int i = 0; i < 4; ++i) a0[i] = sQ[r0+i][kk];
      #pragma unroll
      for (int j = 0; j < 4; ++j) b0[j] = sS[kk][c0+j];
      #pragma unroll
      for (int i = 0; i < 4; ++i)
        #pragma unroll
        for (int j = 0; j < 4; ++j) acc[i][j] = fmaf(a0[i], b0[j], acc[i][j]);
    }
    #pragma unroll 4
    for (int kk = 0; kk < 64; ++kk) {
      float a0[4], b0[4];
      #pragma unroll
      for (int i = 0; i < 4; ++i) a0[i] = sA[r0+i][kk];
      #pragma unroll
      for (int j = 0; j < 4; ++j) b0[j] = sU[kk][c0+j];
      #pragma unroll
      for (int i = 0; i < 4; ++i)
        #pragma unroll
        for (int j = 0; j < 4; ++j) acc[i][j] = fmaf(a0[i], b0[j], acc[i][j]);
    }
    #pragma unroll
    for (int i = 0; i < 4; ++i)
      #pragma unroll
      for (int j = 0; j < 4; ++j) {
        int r = r0 + i, c = c0 + j;
        dOut[(((size_t)b * N_ + g * 64 + r) * H_ + h) * 64 + c] = acc[i][j];
      }
  }
}

// ---------------- fused FIR + cross-mix + gating + ctx -----------------------
__global__ __launch_bounds__(256) void paths_k(const float* __restrict__ qkv,
    const float* __restrict__ dOut, const float* __restrict__ idb,
    const float* __restrict__ gateL, const float* __restrict__ prL,
    const float* __restrict__ g2L, const float* __restrict__ fir_s,
    const float* __restrict__ fir_l, const float* __restrict__ mix,
    const float* __restrict__ idlog, float* __restrict__ ctx,
    float* __restrict__ entAcc) {
  const int bn = blockIdx.x; const int b = bn >> 10, n = bn & 1023;
  const int tid = threadIdx.x;
  __shared__ float fS[16][64], fL[16][64];
  __shared__ float sMix[256];
  __shared__ float sWg[16][5], sIdg[16], sEnt[16];
  sMix[tid] = mix[tid];

  // FIR (K=3 and K=7), causal
  #pragma unroll
  for (int i = 0; i < 4; ++i) {
    int idx = tid + i * 256; int hh = idx >> 6, d = idx & 63;
    float accs = 0.f, accl = 0.f;
    #pragma unroll
    for (int j = 0; j < 7; ++j) {
      int t = n - 6 + j;
      float vv = (t >= 0) ? qkv[((size_t)b * 1024 + t) * 3072 + 2048 + idx] : 0.f;
      accl = fmaf(fir_l[(size_t)idx * 7 + j], vv, accl);
      if (j >= 4) accs = fmaf(fir_s[(size_t)idx * 3 + (j - 4)], vv, accs);
    }
    fS[hh][d] = accs; fL[hh][d] = accl;
  }
  __syncthreads();

  // cross-head mix into registers
  float fsm[4], flm[4];
  #pragma unroll
  for (int i = 0; i < 4; ++i) {
    int idx = tid + i * 256; int gg = idx >> 6, d = idx & 63;
    float as = fS[gg][d], al = fL[gg][d];
    #pragma unroll
    for (int hh = 0; hh < 16; ++hh) {
      float m = sMix[hh * 16 + gg];
      as = fmaf(fS[hh][d], m, as);
      al = fmaf(fL[hh][d], m, al);
    }
    fsm[i] = as; flm[i] = al;
  }

  // per-head softmaxes + entropies + id gate (threads 0..15)
  if (tid < 16) {
    float pl[5], lp[5];
    #pragma unroll
    for (int p = 0; p < 5; ++p) pl[p] = prL[(size_t)bn * 80 + tid * 5 + p];
    float mx = pl[0];
    #pragma unroll
    for (int p = 1; p < 5; ++p) mx = fmaxf(mx, pl[p]);
    float s = 0.f;
    #pragma unroll
    for (int p = 0; p < 5; ++p) { pl[p] = expf(pl[p] - mx); s += pl[p]; }
    float inv = 1.f / s, e1 = 0.f;
    #pragma unroll
    for (int p = 0; p < 5; ++p) {
      float prob = pl[p] * inv;
      lp[p] = logf(prob + 1e-8f);
      e1 -= prob * lp[p];
    }
    float gl[5];
    #pragma unroll
    for (int p = 0; p < 5; ++p) gl[p] = g2L[(size_t)bn * 80 + tid * 5 + p] + lp[p];
    float mx2 = gl[0];
    #pragma unroll
    for (int p = 1; p < 5; ++p) mx2 = fmaxf(mx2, gl[p]);
    float s2 = 0.f;
    #pragma unroll
    for (int p = 0; p < 5; ++p) { gl[p] = expf(gl[p] - mx2); s2 += gl[p]; }
    float inv2 = 1.f / s2, e2 = 0.f;
    #pragma unroll
    for (int p = 0; p < 5; ++p) {
      float w = gl[p] * inv2;
      sWg[tid][p] = w;
      e2 -= w * logf(w + 1e-8f);
    }
    sEnt[tid] = e1 + e2;
    sIdg[tid] = sigmoid_f(gateL[(size_t)bn * 16 + tid]) * sigmoid_f(idlog[tid]);
  }
  __syncthreads();

  // combine paths -> ctx
  #pragma unroll
  for (int i = 0; i < 4; ++i) {
    int idx = tid + i * 256; int hh = idx >> 6;
    float w0 = sWg[hh][0], w1 = sWg[hh][1], w2 = sWg[hh][2], w3 = sWg[hh][3], w4 = sWg[hh][4];
    float dv = dOut[(size_t)bn * 1024 + idx];
    float vv = qkv[(size_t)bn * 3072 + 2048 + idx];
    float iv = idb[(size_t)bn * 1024 + idx] * sIdg[hh];
    ctx[(size_t)bn * 1024 + idx] = w0*fsm[i] + w1*flm[i] + w2*dv + w3*vv + w4*iv;
  }
  if (tid == 0) {
    float s = 0.f;
    #pragma unroll
    for (int hh = 0; hh < 16; ++hh) s += sEnt[hh];
    atomicAdd(entAcc, s);
  }
}

__global__ void zero_ent(float* e) { e[0] = 0.f; }
__global__ void ent_fin(const float* __restrict__ e, float* __restrict__ dst) {
  dst[0] = e[0] * (1.0f / 65536.0f);
}

// ---------------- host launcher ----------------------------------------------
extern "C" void kernel_launch(void* const* d_in, const int* in_sizes, int n_in,
                              void* d_out, int out_size, void* d_ws, size_t ws_size,
                              hipStream_t stream) {
  (void)in_sizes; (void)n_in; (void)out_size; (void)ws_size;
  const float* x       = (const float*)d_in[0];
  const float* W_qkv   = (const float*)d_in[1];
  const float* W_id    = (const float*)d_in[2];
  const float* W_gate  = (const float*)d_in[3];
  const float* b_gate  = (const float*)d_in[4];
  const float* idlog   = (const float*)d_in[5];
  const float* fir_s   = (const float*)d_in[6];
  const float* fir_l   = (const float*)d_in[7];
  const float* mix     = (const float*)d_in[8];
  const float* W_prune = (const float*)d_in[9];
  const float* b_prune = (const float*)d_in[10];
  const float* W_g1    = (const float*)d_in[11];
  const float* b_g1    = (const float*)d_in[12];
  const float* W_g2    = (const float*)d_in[13];
  const float* b_g2    = (const float*)d_in[14];
  const float* W_proj  = (const float*)d_in[15];
  const float* b_proj  = (const float*)d_in[16];
  float* out = (float*)d_out;

  float* ws   = (float*)d_ws;
  float* qkv  = ws;                      // 4096 x 3072
  float* idb  = qkv + 12582912;          // 4096 x 1024
  float* gate = idb + 4194304;           // 4096 x 16
  float* prl  = gate + 65536;            // 4096 x 80
  float* hbuf = prl + 327680;            // 4096 x 1024 (gelu(g1); reused as ctx)
  float* g2l  = hbuf + 4194304;          // 4096 x 80
  float* gW   = g2l + 327680;            // 64 bh x 16 g x 64 x 64
  float* gU   = gW + 4194304;
  float* gS   = gU + 4194304;
  float* dOut = gS + 4194304;            // (b,n,h,d)
  float* entA = dOut + 4194304;          // 1 float
  float* ctx  = hbuf;                    // alias: hbuf dead after g2 GEMM

  // projections from x
  gemm64<0><<<dim3(48, 64), 256, 0, stream>>>(x, W_qkv, nullptr, qkv, BN_, 3072, 1024);
  gemm64<0><<<dim3(16, 64), 256, 0, stream>>>(x, W_id, nullptr, idb, BN_, 1024, 1024);
  gemm_small<<<BN_, 64, 0, stream>>>(x, W_gate, b_gate, gate, 16, 1024);
  gemm_small<<<BN_, 128, 0, stream>>>(x, W_prune, b_prune, prl, 80, 1024);
  gemm64<1><<<dim3(16, 64), 256, 0, stream>>>(x, W_g1, b_g1, hbuf, BN_, 1024, 1024);
  gemm_small<<<BN_, 128, 0, stream>>>(hbuf, W_g2, b_g2, g2l, 80, 1024);

  // delta rule
  delta_prep<<<1024, 256, 0, stream>>>(qkv, gW, gU);
  delta_scan<<<64, 256, 0, stream>>>(qkv, gW, gU, gS);
  delta_outk<<<1024, 256, 0, stream>>>(qkv, gW, gU, gS, dOut);

  // fused paths + gating
  zero_ent<<<1, 1, 0, stream>>>(entA);
  paths_k<<<BN_, 256, 0, stream>>>(qkv, dOut, idb, gate, prl, g2l,
                                   fir_s, fir_l, mix, idlog, ctx, entA);

  // output projection + entropy scalar
  gemm64<0><<<dim3(16, 64), 256, 0, stream>>>(ctx, W_proj, b_proj, out, BN_, 1024, 1024);
  ent_fin<<<1, 1, 0, stream>>>(entA, out + 4194304);
}

// Round 2
// 801.701 us; speedup vs baseline: 1.7030x; 1.7030x over previous
//
#include <hip/hip_runtime.h>
#include <math.h>

#define B_ 4
#define N_ 1024
#define C_ 1024
#define H_ 16
#define D_ 64
#define P_ 5
#define BN_ (B_*N_)

typedef unsigned int u32;
typedef unsigned short u16;
typedef __attribute__((ext_vector_type(8))) short bf16x8;
typedef __attribute__((ext_vector_type(4))) float f32x4;

__device__ __forceinline__ float gelu_f(float x){
  float x3 = x*x*x;
  return 0.5f*x*(1.0f + tanhf(0.7978845608028654f*(x + 0.044715f*x3)));
}
__device__ __forceinline__ float sigmoid_f(float x){ return 1.0f/(1.0f+expf(-x)); }

__device__ __forceinline__ u16 f2bf(float f) {
  u32 u = __float_as_uint(f);
  u32 r = u + 0x7fffu + ((u >> 16) & 1u);
  return (u16)(r >> 16);
}

__device__ __forceinline__ void gload16(const void* g, void* l) {
  __builtin_amdgcn_global_load_lds((const __attribute__((address_space(1))) u32*)g,
                                   (__attribute__((address_space(3))) u32*)l, 16, 0, 0);
}

// ---------------- fp32 -> bf16 elementwise cast (8 elems/thread) --------------
__global__ __launch_bounds__(256) void conv_bf16(const float* __restrict__ in,
    u16* __restrict__ out, int n8) {
  int i = blockIdx.x * 256 + threadIdx.x;
  if (i >= n8) return;
  const float4* p = (const float4*)in + (size_t)i * 2;
  float4 a = p[0], b = p[1];
  uint4 o;
  o.x = (u32)f2bf(a.x) | ((u32)f2bf(a.y) << 16);
  o.y = (u32)f2bf(a.z) | ((u32)f2bf(a.w) << 16);
  o.z = (u32)f2bf(b.x) | ((u32)f2bf(b.y) << 16);
  o.w = (u32)f2bf(b.z) | ((u32)f2bf(b.w) << 16);
  *(uint4*)(out + (size_t)i * 8) = o;
}

// ---------------- fp32 [K][N] -> bf16 [N][K] transpose cast -------------------
__global__ __launch_bounds__(256) void conv_wt(const float* __restrict__ W,
    u16* __restrict__ Wt, int K, int Nn) {
  __shared__ float t[32][33];
  int c0 = blockIdx.x * 32, r0 = blockIdx.y * 32;
  int tx = threadIdx.x & 31, ty = threadIdx.x >> 5;   // 8 rows per pass
  #pragma unroll
  for (int i = 0; i < 4; ++i) {
    int r = ty + i * 8;
    t[r][tx] = W[(size_t)(r0 + r) * Nn + c0 + tx];
  }
  __syncthreads();
  #pragma unroll
  for (int i = 0; i < 4; ++i) {
    int r = ty + i * 8;                                 // col of W
    Wt[(size_t)(c0 + r) * K + r0 + tx] = f2bf(t[tx][r]);
  }
}

// ---------------- bf16 MFMA GEMM: C = A(M,K) @ Bt(N,K)^T (+bias, +gelu) -------
// 128x128 tile, BK=32, 256 threads (4 waves 2x2), global_load_lds staging.
template<int ACT>
__global__ __launch_bounds__(256) void gemm_mfma(const u16* __restrict__ A,
    const u16* __restrict__ Bt, const float* __restrict__ bias,
    float* __restrict__ Cout, int M, int Nn, int K) {
  __shared__ __align__(16) u16 lA[128 * 32];
  __shared__ __align__(16) u16 lB[128 * 32];
  const int tid = threadIdx.x;
  const int lane = tid & 63, wid = tid >> 6;
  const int wr = wid >> 1, wc = wid & 1;
  const int r16 = lane & 15, kq = lane >> 4;
  const int row0 = blockIdx.y * 128, col0 = blockIdx.x * 128;
  const int c0 = wid * 2;
  const int srow = lane >> 2;          // row within 16-row chunk
  const int skoff = (lane & 3) * 8;    // k element offset

  f32x4 acc[4][4] = {};
  for (int k0 = 0; k0 < K; k0 += 32) {
    #pragma unroll
    for (int s = 0; s < 2; ++s) {
      int c = c0 + s;
      int rt = c * 16 + srow;
      gload16(A  + (size_t)(row0 + rt) * K + k0 + skoff, &lA[c * 512]);
      gload16(Bt + (size_t)(col0 + rt) * K + k0 + skoff, &lB[c * 512]);
    }
    __syncthreads();
    bf16x8 af[4], bfv[4];
    #pragma unroll
    for (int m = 0; m < 4; ++m)
      af[m] = *(const bf16x8*)&lA[(wr * 64 + m * 16 + r16) * 32 + kq * 8];
    #pragma unroll
    for (int n = 0; n < 4; ++n)
      bfv[n] = *(const bf16x8*)&lB[(wc * 64 + n * 16 + r16) * 32 + kq * 8];
    #pragma unroll
    for (int m = 0; m < 4; ++m)
      #pragma unroll
      for (int n = 0; n < 4; ++n)
        acc[m][n] = __builtin_amdgcn_mfma_f32_16x16x32_bf16(af[m], bfv[n], acc[m][n], 0, 0, 0);
    __syncthreads();
  }
  #pragma unroll
  for (int n = 0; n < 4; ++n) {
    int col = col0 + wc * 64 + n * 16 + r16;
    float bs = bias ? bias[col] : 0.0f;
    #pragma unroll
    for (int m = 0; m < 4; ++m) {
      int rowb = row0 + wr * 64 + m * 16 + kq * 4;
      #pragma unroll
      for (int r = 0; r < 4; ++r) {
        float v = acc[m][n][r] + bs;
        if (ACT == 1) v = gelu_f(v);
        Cout[(size_t)(rowb + r) * Nn + col] = v;
      }
    }
  }
}

// ---------------- skinny GEMM (Nn = 16 or 80): one block per row --------------
__global__ void gemm_small(const float* __restrict__ A, const float* __restrict__ W,
    const float* __restrict__ bias, float* __restrict__ Cout, int Nn, int K) {
  const int row = blockIdx.x;
  const int c = threadIdx.x;
  if (c >= Nn) return;
  const float* a = A + (size_t)row * K;
  float acc = bias[c];
  for (int k = 0; k < K; k += 4) {
    float4 a4 = *(const float4*)(a + k);
    acc = fmaf(a4.x, W[(size_t)(k+0)*Nn + c], acc);
    acc = fmaf(a4.y, W[(size_t)(k+1)*Nn + c], acc);
    acc = fmaf(a4.z, W[(size_t)(k+2)*Nn + c], acc);
    acc = fmaf(a4.w, W[(size_t)(k+3)*Nn + c], acc);
  }
  Cout[(size_t)row * Nn + c] = acc;
}

// ---------------- DeltaNet: per-chunk prep (normalize, A, triangular solves) ---
__global__ __launch_bounds__(256) void delta_prep(float* __restrict__ qkv,
    float* __restrict__ gW, float* __restrict__ gU) {
  const int bx = blockIdx.x;
  const int bh = bx >> 4, g = bx & 15;
  const int b = bh >> 4, h = bh & 15;
  const int n0 = g * 64;
  const int tid = threadIdx.x;
  __shared__ float sK[64][65];
  __shared__ float sV[64][65];
  __shared__ float sW[64][65];
  __shared__ float sM[64][65];
  __shared__ float sBeta[64];

  const size_t rowbase = (size_t)b * N_ + n0;
  for (int i = 0; i < 16; ++i) {
    int idx = tid + i * 256; int r = idx >> 6, d = idx & 63;
    size_t off = (rowbase + r) * 3072 + h * 64 + d;
    sK[r][d] = qkv[off + 1024];
    sV[r][d] = qkv[off + 2048];
  }
  if (tid < 64) sBeta[tid] = 1.0f - 0.9f * (float)(n0 + tid) / 1023.0f;
  __syncthreads();

  if (tid < 64) {            // q: l2norm * d^-0.5, in registers, write back
    size_t off = (rowbase + tid) * 3072 + h * 64;
    float4 qv[16]; float ss = 0.f;
    #pragma unroll
    for (int i = 0; i < 16; ++i) {
      qv[i] = *(const float4*)(qkv + off + 4*i);
      ss += qv[i].x*qv[i].x + qv[i].y*qv[i].y + qv[i].z*qv[i].z + qv[i].w*qv[i].w;
    }
    float sc = rsqrtf(ss + 1e-6f) * 0.125f;
    #pragma unroll
    for (int i = 0; i < 16; ++i) {
      float4 t = qv[i]; t.x *= sc; t.y *= sc; t.z *= sc; t.w *= sc;
      *(float4*)(qkv + off + 4*i) = t;
    }
  } else if (tid < 128) {    // k: l2norm in LDS
    int r = tid - 64; float ss = 0.f;
    for (int d = 0; d < 64; ++d) ss += sK[r][d] * sK[r][d];
    float sc = rsqrtf(ss + 1e-6f);
    for (int d = 0; d < 64; ++d) sK[r][d] *= sc;
  } else if (tid < 192) {    // v *= beta
    int r = tid - 128; float bt = sBeta[r];
    for (int d = 0; d < 64; ++d) sV[r][d] *= bt;
  }
  __syncthreads();

  for (int i = 0; i < 16; ++i) {
    int idx = tid + i * 256; int r = idx >> 6, d = idx & 63;
    qkv[(rowbase + r) * 3072 + 1024 + h * 64 + d] = sK[r][d];
  }
  // A = tril(beta_r * khat khat^T, -1)
  {
    const int tx = tid & 15, ty = tid >> 4;
    const int r0 = ty * 4, cc0 = tx * 4;
    float acc[4][4] = {};
    #pragma unroll 4
    for (int d = 0; d < 64; ++d) {
      float a0[4], b0[4];
      #pragma unroll
      for (int i = 0; i < 4; ++i) a0[i] = sK[r0+i][d];
      #pragma unroll
      for (int j = 0; j < 4; ++j) b0[j] = sK[cc0+j][d];
      #pragma unroll
      for (int i = 0; i < 4; ++i)
        #pragma unroll
        for (int j = 0; j < 4; ++j) acc[i][j] = fmaf(a0[i], b0[j], acc[i][j]);
    }
    #pragma unroll
    for (int i = 0; i < 4; ++i)
      #pragma unroll
      for (int j = 0; j < 4; ++j) {
        int r = r0 + i, c = cc0 + j;
        sM[r][c] = (r > c) ? sBeta[r] * acc[i][j] : 0.f;
      }
  }
  __syncthreads();

  if (tid < 64) {
    int c = tid;
    for (int i = 0; i < 64; ++i) {
      float acc = sBeta[i] * sK[i][c];
      #pragma unroll 4
      for (int j = 0; j < i; ++j) acc -= sM[i][j] * sW[j][c];
      sW[i][c] = acc;
    }
  } else if (tid < 128) {
    int c = tid - 64;
    for (int i = 0; i < 64; ++i) {
      float acc = sV[i][c];
      #pragma unroll 4
      for (int j = 0; j < i; ++j) acc -= sM[i][j] * sV[j][c];
      sV[i][c] = acc;
    }
  }
  __syncthreads();

  const size_t obase = (size_t)(bh * 16 + g) * 4096;
  for (int i = 0; i < 16; ++i) {
    int idx = tid + i * 256;
    gW[obase + idx] = sW[idx >> 6][idx & 63];
    gU[obase + idx] = sV[idx >> 6][idx & 63];
  }
}

// ---------------- DeltaNet: sequential chunk scan, stores S_g per chunk --------
__global__ __launch_bounds__(256) void delta_scan(const float* __restrict__ qkv,
    const float* __restrict__ gW, const float* __restrict__ gU,
    float* __restrict__ gS) {
  const int bh = blockIdx.x; const int b = bh >> 4, h = bh & 15;
  const int tid = threadIdx.x; const int tx = tid & 15, ty = tid >> 4;
  __shared__ float sS[64][65], sK[64][65], sW[64][65], sU[64][65];
  float Sreg[4][4] = {};
  const int e0 = ty * 4, d0 = tx * 4;
  for (int g = 0; g < 16; ++g) {
    const size_t obase = (size_t)(bh * 16 + g) * 4096;
    for (int i = 0; i < 16; ++i) {
      int idx = tid + i * 256; int r = idx >> 6, d = idx & 63;
      sK[r][d] = qkv[((size_t)b * N_ + g * 64 + r) * 3072 + 1024 + h * 64 + d];
      sW[r][d] = gW[obase + idx];
      sU[r][d] = gU[obase + idx];
    }
    #pragma unroll
    for (int i = 0; i < 4; ++i)
      #pragma unroll
      for (int j = 0; j < 4; ++j) {
        sS[e0+i][d0+j] = Sreg[i][j];
        gS[obase + (size_t)(e0+i) * 64 + d0 + j] = Sreg[i][j];
      }
    __syncthreads();
    {
      float acc[4][4] = {};
      #pragma unroll 4
      for (int kk = 0; kk < 64; ++kk) {
        float a0[4], b0[4];
        #pragma unroll
        for (int i = 0; i < 4; ++i) a0[i] = sW[e0+i][kk];
        #pragma unroll
        for (int j = 0; j < 4; ++j) b0[j] = sS[kk][d0+j];
        #pragma unroll
        for (int i = 0; i < 4; ++i)
          #pragma unroll
          for (int j = 0; j < 4; ++j) acc[i][j] = fmaf(a0[i], b0[j], acc[i][j]);
      }
      #pragma unroll
      for (int i = 0; i < 4; ++i)
        #pragma unroll
        for (int j = 0; j < 4; ++j) sU[e0+i][d0+j] -= acc[i][j];
    }
    __syncthreads();
    #pragma unroll 4
    for (int c = 0; c < 64; ++c) {
      float a0[4], b0[4];
      #pragma unroll
      for (int i = 0; i < 4; ++i) a0[i] = sK[c][e0+i];
      #pragma unroll
      for (int j = 0; j < 4; ++j) b0[j] = sU[c][d0+j];
      #pragma unroll
      for (int i = 0; i < 4; ++i)
        #pragma unroll
        for (int j = 0; j < 4; ++j) Sreg[i][j] = fmaf(a0[i], b0[j], Sreg[i][j]);
    }
    __syncthreads();
  }
}

// ---------------- DeltaNet: per-chunk output o = q@S + tril(q k^T) @ u_adj ----
__global__ __launch_bounds__(256) void delta_outk(const float* __restrict__ qkv,
    const float* __restrict__ gW, const float* __restrict__ gU,
    const float* __restrict__ gS, float* __restrict__ dOut) {
  const int bx = blockIdx.x; const int bh = bx >> 4, g = bx & 15;
  const int b = bh >> 4, h = bh & 15;
  const int tid = threadIdx.x; const int tx = tid & 15, ty = tid >> 4;
  __shared__ float sQ[64][65], sK[64][65], sW[64][65], sU[64][65], sS[64][65], sA[64][65];
  const size_t obase = (size_t)(bh * 16 + g) * 4096;
  for (int i = 0; i < 16; ++i) {
    int idx = tid + i * 256; int r = idx >> 6, d = idx & 63;
    size_t qoff = ((size_t)b * N_ + g * 64 + r) * 3072 + h * 64 + d;
    sQ[r][d] = qkv[qoff];
    sK[r][d] = qkv[qoff + 1024];
    sW[r][d] = gW[obase + idx];
    sU[r][d] = gU[obase + idx];
    sS[r][d] = gS[obase + idx];
  }
  __syncthreads();
  const int r0 = ty * 4, cc0 = tx * 4;
  {
    float acc[4][4] = {};
    #pragma unroll 4
    for (int d = 0; d < 64; ++d) {
      float a0[4], b0[4];
      #pragma unroll
      for (int i = 0; i < 4; ++i) a0[i] = sQ[r0+i][d];
      #pragma unroll
      for (int j = 0; j < 4; ++j) b0[j] = sK[cc0+j][d];
      #pragma unroll
      for (int i = 0; i < 4; ++i)
        #pragma unroll
        for (int j = 0; j < 4; ++j) acc[i][j] = fmaf(a0[i], b0[j], acc[i][j]);
    }
    #pragma unroll
    for (int i = 0; i < 4; ++i)
      #pragma unroll
      for (int j = 0; j < 4; ++j) {
        int r = r0 + i, c = cc0 + j;
        sA[r][c] = (r >= c) ? acc[i][j] : 0.f;
      }
  }
  {
    float acc[4][4] = {};
    #pragma unroll 4
    for (int kk = 0; kk < 64; ++kk) {
      float a0[4], b0[4];
      #pragma unroll
      for (int i = 0; i < 4; ++i) a0[i] = sW[r0+i][kk];
      #pragma unroll
      for (int j = 0; j < 4; ++j) b0[j] = sS[kk][cc0+j];
      #pragma unroll
      for (int i = 0; i < 4; ++i)
        #pragma unroll
        for (int j = 0; j < 4; ++j) acc[i][j] = fmaf(a0[i], b0[j], acc[i][j]);
    }
    #pragma unroll
    for (int i = 0; i < 4; ++i)
      #pragma unroll
      for (int j = 0; j < 4; ++j) sU[r0+i][cc0+j] -= acc[i][j];
  }
  __syncthreads();
  {
    float acc[4][4] = {};
    #pragma unroll 4
    for (int kk = 0; kk < 64; ++kk) {
      float a0[4], b0[4];
      #pragma unroll
      for (int i = 0; i < 4; ++i) a0[i] = sQ[r0+i][kk];
      #pragma unroll
      for (int j = 0; j < 4; ++j) b0[j] = sS[kk][cc0+j];
      #pragma unroll
      for (int i = 0; i < 4; ++i)
        #pragma unroll
        for (int j = 0; j < 4; ++j) acc[i][j] = fmaf(a0[i], b0[j], acc[i][j]);
    }
    #pragma unroll 4
    for (int kk = 0; kk < 64; ++kk) {
      float a0[4], b0[4];
      #pragma unroll
      for (int i = 0; i < 4; ++i) a0[i] = sA[r0+i][kk];
      #pragma unroll
      for (int j = 0; j < 4; ++j) b0[j] = sU[kk][cc0+j];
      #pragma unroll
      for (int i = 0; i < 4; ++i)
        #pragma unroll
        for (int j = 0; j < 4; ++j) acc[i][j] = fmaf(a0[i], b0[j], acc[i][j]);
    }
    #pragma unroll
    for (int i = 0; i < 4; ++i)
      #pragma unroll
      for (int j = 0; j < 4; ++j) {
        int r = r0 + i, c = cc0 + j;
        dOut[(((size_t)b * N_ + g * 64 + r) * H_ + h) * 64 + c] = acc[i][j];
      }
  }
}

// ---------------- fused FIR + cross-mix + gating + ctx -----------------------
__global__ __launch_bounds__(256) void paths_k(const float* __restrict__ qkv,
    const float* __restrict__ dOut, const float* __restrict__ idb,
    const float* __restrict__ gateL, const float* __restrict__ prL,
    const float* __restrict__ g2L, const float* __restrict__ fir_s,
    const float* __restrict__ fir_l, const float* __restrict__ mix,
    const float* __restrict__ idlog, float* __restrict__ ctx,
    float* __restrict__ entAcc) {
  const int bn = blockIdx.x; const int b = bn >> 10, n = bn & 1023;
  const int tid = threadIdx.x;
  __shared__ float fS[16][64], fL[16][64];
  __shared__ float sMix[256];
  __shared__ float sWg[16][5], sIdg[16], sEnt[16];
  sMix[tid] = mix[tid];

  #pragma unroll
  for (int i = 0; i < 4; ++i) {
    int idx = tid + i * 256; int hh = idx >> 6, d = idx & 63;
    float accs = 0.f, accl = 0.f;
    #pragma unroll
    for (int j = 0; j < 7; ++j) {
      int t = n - 6 + j;
      float vv = (t >= 0) ? qkv[((size_t)b * 1024 + t) * 3072 + 2048 + idx] : 0.f;
      accl = fmaf(fir_l[(size_t)idx * 7 + j], vv, accl);
      if (j >= 4) accs = fmaf(fir_s[(size_t)idx * 3 + (j - 4)], vv, accs);
    }
    fS[hh][d] = accs; fL[hh][d] = accl;
  }
  __syncthreads();

  float fsm[4], flm[4];
  #pragma unroll
  for (int i = 0; i < 4; ++i) {
    int idx = tid + i * 256; int gg = idx >> 6, d = idx & 63;
    float as = fS[gg][d], al = fL[gg][d];
    #pragma unroll
    for (int hh = 0; hh < 16; ++hh) {
      float m = sMix[hh * 16 + gg];
      as = fmaf(fS[hh][d], m, as);
      al = fmaf(fL[hh][d], m, al);
    }
    fsm[i] = as; flm[i] = al;
  }

  if (tid < 16) {
    float pl[5], lp[5];
    #pragma unroll
    for (int p = 0; p < 5; ++p) pl[p] = prL[(size_t)bn * 80 + tid * 5 + p];
    float mx = pl[0];
    #pragma unroll
    for (int p = 1; p < 5; ++p) mx = fmaxf(mx, pl[p]);
    float s = 0.f;
    #pragma unroll
    for (int p = 0; p < 5; ++p) { pl[p] = expf(pl[p] - mx); s += pl[p]; }
    float inv = 1.f / s, e1 = 0.f;
    #pragma unroll
    for (int p = 0; p < 5; ++p) {
      float prob = pl[p] * inv;
      lp[p] = logf(prob + 1e-8f);
      e1 -= prob * lp[p];
    }
    float gl[5];
    #pragma unroll
    for (int p = 0; p < 5; ++p) gl[p] = g2L[(size_t)bn * 80 + tid * 5 + p] + lp[p];
    float mx2 = gl[0];
    #pragma unroll
    for (int p = 1; p < 5; ++p) mx2 = fmaxf(mx2, gl[p]);
    float s2 = 0.f;
    #pragma unroll
    for (int p = 0; p < 5; ++p) { gl[p] = expf(gl[p] - mx2); s2 += gl[p]; }
    float inv2 = 1.f / s2, e2 = 0.f;
    #pragma unroll
    for (int p = 0; p < 5; ++p) {
      float w = gl[p] * inv2;
      sWg[tid][p] = w;
      e2 -= w * logf(w + 1e-8f);
    }
    sEnt[tid] = e1 + e2;
    sIdg[tid] = sigmoid_f(gateL[(size_t)bn * 16 + tid]) * sigmoid_f(idlog[tid]);
  }
  __syncthreads();

  #pragma unroll
  for (int i = 0; i < 4; ++i) {
    int idx = tid + i * 256; int hh = idx >> 6;
    float w0 = sWg[hh][0], w1 = sWg[hh][1], w2 = sWg[hh][2], w3 = sWg[hh][3], w4 = sWg[hh][4];
    float dv = dOut[(size_t)bn * 1024 + idx];
    float vv = qkv[(size_t)bn * 3072 + 2048 + idx];
    float iv = idb[(size_t)bn * 1024 + idx] * sIdg[hh];
    ctx[(size_t)bn * 1024 + idx] = w0*fsm[i] + w1*flm[i] + w2*dv + w3*vv + w4*iv;
  }
  if (tid == 0) {
    float s = 0.f;
    #pragma unroll
    for (int hh = 0; hh < 16; ++hh) s += sEnt[hh];
    atomicAdd(entAcc, s);
  }
}

__global__ void zero_ent(float* e) { e[0] = 0.f; }
__global__ void ent_fin(const float* __restrict__ e, float* __restrict__ dst) {
  dst[0] = e[0] * (1.0f / 65536.0f);
}

// ---------------- host launcher ----------------------------------------------
extern "C" void kernel_launch(void* const* d_in, const int* in_sizes, int n_in,
                              void* d_out, int out_size, void* d_ws, size_t ws_size,
                              hipStream_t stream) {
  (void)in_sizes; (void)n_in; (void)out_size; (void)ws_size;
  const float* x       = (const float*)d_in[0];
  const float* W_qkv   = (const float*)d_in[1];
  const float* W_id    = (const float*)d_in[2];
  const float* W_gate  = (const float*)d_in[3];
  const float* b_gate  = (const float*)d_in[4];
  const float* idlog   = (const float*)d_in[5];
  const float* fir_s   = (const float*)d_in[6];
  const float* fir_l   = (const float*)d_in[7];
  const float* mix     = (const float*)d_in[8];
  const float* W_prune = (const float*)d_in[9];
  const float* b_prune = (const float*)d_in[10];
  const float* W_g1    = (const float*)d_in[11];
  const float* b_g1    = (const float*)d_in[12];
  const float* W_g2    = (const float*)d_in[13];
  const float* b_g2    = (const float*)d_in[14];
  const float* W_proj  = (const float*)d_in[15];
  const float* b_proj  = (const float*)d_in[16];
  float* out = (float*)d_out;

  float* ws   = (float*)d_ws;
  float* qkv  = ws;                      // 4096 x 3072
  float* idb  = qkv + 12582912;          // 4096 x 1024
  float* gate = idb + 4194304;           // 4096 x 16
  float* prl  = gate + 65536;            // 4096 x 80
  float* hbuf = prl + 327680;            // 4096 x 1024 (gelu(g1); reused as ctx)
  float* g2l  = hbuf + 4194304;          // 4096 x 80
  float* gW   = g2l + 327680;            // 64 bh x 16 g x 64 x 64
  float* gU   = gW + 4194304;
  float* gS   = gU + 4194304;
  float* dOut = gS + 4194304;            // (b,n,h,d)
  float* entA = dOut + 4194304;          // 1 float
  float* ctx  = hbuf;                    // alias: hbuf dead after g2 GEMM

  // bf16 scratch aliased into gW/gU (dead until delta_prep / after delta_outk)
  u16* xb     = (u16*)gW;                          // 4096x1024 bf16 (2,097,152 fl)
  u16* wqkvT  = (u16*)(gW + 2097152);              // 3072x1024 bf16 (1,572,864 fl)
  u16* widT   = (u16*)gU;                          // 1024x1024 bf16 (524,288 fl)
  u16* wg1T   = (u16*)(gU + 524288);               // 1024x1024 bf16
  u16* ctxb   = (u16*)gW;                          // post-delta: 4096x1024 bf16
  u16* wprojT = (u16*)(gW + 2097152);              // post-delta: 1024x1024 bf16

  // casts
  conv_bf16<<<2048, 256, 0, stream>>>(x, xb, 524288);
  conv_wt<<<dim3(96, 32), 256, 0, stream>>>(W_qkv, wqkvT, 1024, 3072);
  conv_wt<<<dim3(32, 32), 256, 0, stream>>>(W_id,  widT,  1024, 1024);
  conv_wt<<<dim3(32, 32), 256, 0, stream>>>(W_g1,  wg1T,  1024, 1024);

  // projections from x (bf16 MFMA)
  gemm_mfma<0><<<dim3(24, 32), 256, 0, stream>>>(xb, wqkvT, nullptr, qkv, BN_, 3072, 1024);
  gemm_mfma<0><<<dim3(8, 32), 256, 0, stream>>>(xb, widT, nullptr, idb, BN_, 1024, 1024);
  gemm_mfma<1><<<dim3(8, 32), 256, 0, stream>>>(xb, wg1T, b_g1, hbuf, BN_, 1024, 1024);
  gemm_small<<<BN_, 64, 0, stream>>>(x, W_gate, b_gate, gate, 16, 1024);
  gemm_small<<<BN_, 128, 0, stream>>>(x, W_prune, b_prune, prl, 80, 1024);
  gemm_small<<<BN_, 128, 0, stream>>>(hbuf, W_g2, b_g2, g2l, 80, 1024);

  // delta rule (overwrites gW/gU — bf16 staging above is dead by now)
  delta_prep<<<1024, 256, 0, stream>>>(qkv, gW, gU);
  delta_scan<<<64, 256, 0, stream>>>(qkv, gW, gU, gS);
  delta_outk<<<1024, 256, 0, stream>>>(qkv, gW, gU, gS, dOut);

  // fused paths + gating
  zero_ent<<<1, 1, 0, stream>>>(entA);
  paths_k<<<BN_, 256, 0, stream>>>(qkv, dOut, idb, gate, prl, g2l,
                                   fir_s, fir_l, mix, idlog, ctx, entA);

  // output projection (bf16 MFMA) + entropy scalar
  conv_bf16<<<2048, 256, 0, stream>>>(ctx, ctxb, 524288);
  conv_wt<<<dim3(32, 32), 256, 0, stream>>>(W_proj, wprojT, 1024, 1024);
  gemm_mfma<0><<<dim3(8, 32), 256, 0, stream>>>(ctxb, wprojT, b_proj, out, BN_, 1024, 1024);
  ent_fin<<<1, 1, 0, stream>>>(entA, out + 4194304);
}

// Round 3
// 554.474 us; speedup vs baseline: 2.4624x; 1.4459x over previous
//
#include <hip/hip_runtime.h>
#include <math.h>

#define B_ 4
#define N_ 1024
#define C_ 1024
#define H_ 16
#define D_ 64
#define P_ 5
#define BN_ (B_*N_)

typedef unsigned int u32;
typedef unsigned short u16;
typedef __attribute__((ext_vector_type(8))) short bf16x8;
typedef __attribute__((ext_vector_type(4))) float f32x4;

__device__ __forceinline__ float gelu_f(float x){
  float x3 = x*x*x;
  return 0.5f*x*(1.0f + tanhf(0.7978845608028654f*(x + 0.044715f*x3)));
}
__device__ __forceinline__ float sigmoid_f(float x){ return 1.0f/(1.0f+expf(-x)); }

__device__ __forceinline__ u16 f2bf(float f) {
  u32 u = __float_as_uint(f);
  u32 r = u + 0x7fffu + ((u >> 16) & 1u);
  return (u16)(r >> 16);
}

__device__ __forceinline__ void gload16(const void* g, void* l) {
  __builtin_amdgcn_global_load_lds((const __attribute__((address_space(1))) u32*)g,
                                   (__attribute__((address_space(3))) u32*)l, 16, 0, 0);
}

// ---------------- fp32 -> bf16 elementwise cast (8 elems/thread) --------------
__global__ __launch_bounds__(256) void conv_bf16(const float* __restrict__ in,
    u16* __restrict__ out, int n8) {
  int i = blockIdx.x * 256 + threadIdx.x;
  if (i >= n8) return;
  const float4* p = (const float4*)in + (size_t)i * 2;
  float4 a = p[0], b = p[1];
  uint4 o;
  o.x = (u32)f2bf(a.x) | ((u32)f2bf(a.y) << 16);
  o.y = (u32)f2bf(a.z) | ((u32)f2bf(a.w) << 16);
  o.z = (u32)f2bf(b.x) | ((u32)f2bf(b.y) << 16);
  o.w = (u32)f2bf(b.z) | ((u32)f2bf(b.w) << 16);
  *(uint4*)(out + (size_t)i * 8) = o;
}

// ------- fp32 [K][Nn] -> bf16 [Nn][K] transpose cast, guarded, with row offset
__global__ __launch_bounds__(256) void conv_wt(const float* __restrict__ W,
    u16* __restrict__ Wt, int K, int Nn, int roff) {
  __shared__ float t[32][33];
  int c0 = blockIdx.x * 32, r0 = blockIdx.y * 32;
  int tx = threadIdx.x & 31, ty = threadIdx.x >> 5;
  #pragma unroll
  for (int i = 0; i < 4; ++i) {
    int r = ty + i * 8;
    t[r][tx] = (c0 + tx < Nn) ? W[(size_t)(r0 + r) * Nn + c0 + tx] : 0.f;
  }
  __syncthreads();
  #pragma unroll
  for (int i = 0; i < 4; ++i) {
    int r = ty + i * 8;
    if (c0 + r < Nn)
      Wt[(size_t)(roff + c0 + r) * K + r0 + tx] = f2bf(t[tx][r]);
  }
}

// --------- bias concat: cb1 = [b_gate(16) | b_prune(80) | 0], cb2 = [b_g2(80)|0]
__global__ void bias_cat(const float* __restrict__ bg, const float* __restrict__ bp,
    const float* __restrict__ bg2, float* __restrict__ cb1, float* __restrict__ cb2) {
  int t = threadIdx.x;
  if (t < 128) cb1[t] = (t < 16) ? bg[t] : (t < 96 ? bp[t - 16] : 0.f);
  else { int c = t - 128; cb2[c] = (c < 80) ? bg2[c] : 0.f; }
}

// ---------------- bf16 MFMA GEMM: C = A(M,K) @ Bt(Nn,K)^T (+bias, +gelu) ------
// 128x128 tile, BK=32, 256 threads (4 waves 2x2), global_load_lds staging.
// Ns = real output column count / row stride (<= Nn); stores guarded on col<Ns.
template<int ACT>
__global__ __launch_bounds__(256) void gemm_mfma(const u16* __restrict__ A,
    const u16* __restrict__ Bt, const float* __restrict__ bias,
    float* __restrict__ Cout, int M, int Nn, int K, int Ns) {
  __shared__ __align__(16) u16 lA[128 * 32];
  __shared__ __align__(16) u16 lB[128 * 32];
  const int tid = threadIdx.x;
  const int lane = tid & 63, wid = tid >> 6;
  const int wr = wid >> 1, wc = wid & 1;
  const int r16 = lane & 15, kq = lane >> 4;
  const int row0 = blockIdx.y * 128, col0 = blockIdx.x * 128;
  const int c0 = wid * 2;
  const int srow = lane >> 2;
  const int skoff = (lane & 3) * 8;

  f32x4 acc[4][4] = {};
  for (int k0 = 0; k0 < K; k0 += 32) {
    #pragma unroll
    for (int s = 0; s < 2; ++s) {
      int c = c0 + s;
      int rt = c * 16 + srow;
      gload16(A  + (size_t)(row0 + rt) * K + k0 + skoff, &lA[c * 512]);
      gload16(Bt + (size_t)(col0 + rt) * K + k0 + skoff, &lB[c * 512]);
    }
    __syncthreads();
    bf16x8 af[4], bfv[4];
    #pragma unroll
    for (int m = 0; m < 4; ++m)
      af[m] = *(const bf16x8*)&lA[(wr * 64 + m * 16 + r16) * 32 + kq * 8];
    #pragma unroll
    for (int n = 0; n < 4; ++n)
      bfv[n] = *(const bf16x8*)&lB[(wc * 64 + n * 16 + r16) * 32 + kq * 8];
    #pragma unroll
    for (int m = 0; m < 4; ++m)
      #pragma unroll
      for (int n = 0; n < 4; ++n)
        acc[m][n] = __builtin_amdgcn_mfma_f32_16x16x32_bf16(af[m], bfv[n], acc[m][n], 0, 0, 0);
    __syncthreads();
  }
  #pragma unroll
  for (int n = 0; n < 4; ++n) {
    int col = col0 + wc * 64 + n * 16 + r16;
    if (col >= Ns) continue;
    float bs = bias ? bias[col] : 0.0f;
    #pragma unroll
    for (int m = 0; m < 4; ++m) {
      int rowb = row0 + wr * 64 + m * 16 + kq * 4;
      #pragma unroll
      for (int r = 0; r < 4; ++r) {
        float v = acc[m][n][r] + bs;
        if (ACT == 1) v = gelu_f(v);
        Cout[(size_t)(rowb + r) * Ns + col] = v;
      }
    }
  }
}

// ---------------- DeltaNet: per-chunk prep (normalize, A, triangular solves) ---
__global__ __launch_bounds__(256) void delta_prep(float* __restrict__ qkv,
    float* __restrict__ gW, float* __restrict__ gU) {
  const int bx = blockIdx.x;
  const int bh = bx >> 4, g = bx & 15;
  const int b = bh >> 4, h = bh & 15;
  const int n0 = g * 64;
  const int tid = threadIdx.x;
  __shared__ float sK[64][65];
  __shared__ float sV[64][65];
  __shared__ float sW[64][65];
  __shared__ float sM[64][65];
  __shared__ float sBeta[64];

  const size_t rowbase = (size_t)b * N_ + n0;
  for (int i = 0; i < 16; ++i) {
    int idx = tid + i * 256; int r = idx >> 6, d = idx & 63;
    size_t off = (rowbase + r) * 3072 + h * 64 + d;
    sK[r][d] = qkv[off + 1024];
    sV[r][d] = qkv[off + 2048];
  }
  if (tid < 64) sBeta[tid] = 1.0f - 0.9f * (float)(n0 + tid) / 1023.0f;
  __syncthreads();

  if (tid < 64) {
    size_t off = (rowbase + tid) * 3072 + h * 64;
    float4 qv[16]; float ss = 0.f;
    #pragma unroll
    for (int i = 0; i < 16; ++i) {
      qv[i] = *(const float4*)(qkv + off + 4*i);
      ss += qv[i].x*qv[i].x + qv[i].y*qv[i].y + qv[i].z*qv[i].z + qv[i].w*qv[i].w;
    }
    float sc = rsqrtf(ss + 1e-6f) * 0.125f;
    #pragma unroll
    for (int i = 0; i < 16; ++i) {
      float4 t = qv[i]; t.x *= sc; t.y *= sc; t.z *= sc; t.w *= sc;
      *(float4*)(qkv + off + 4*i) = t;
    }
  } else if (tid < 128) {
    int r = tid - 64; float ss = 0.f;
    for (int d = 0; d < 64; ++d) ss += sK[r][d] * sK[r][d];
    float sc = rsqrtf(ss + 1e-6f);
    for (int d = 0; d < 64; ++d) sK[r][d] *= sc;
  } else if (tid < 192) {
    int r = tid - 128; float bt = sBeta[r];
    for (int d = 0; d < 64; ++d) sV[r][d] *= bt;
  }
  __syncthreads();

  for (int i = 0; i < 16; ++i) {
    int idx = tid + i * 256; int r = idx >> 6, d = idx & 63;
    qkv[(rowbase + r) * 3072 + 1024 + h * 64 + d] = sK[r][d];
  }
  {
    const int tx = tid & 15, ty = tid >> 4;
    const int r0 = ty * 4, cc0 = tx * 4;
    float acc[4][4] = {};
    #pragma unroll 4
    for (int d = 0; d < 64; ++d) {
      float a0[4], b0[4];
      #pragma unroll
      for (int i = 0; i < 4; ++i) a0[i] = sK[r0+i][d];
      #pragma unroll
      for (int j = 0; j < 4; ++j) b0[j] = sK[cc0+j][d];
      #pragma unroll
      for (int i = 0; i < 4; ++i)
        #pragma unroll
        for (int j = 0; j < 4; ++j) acc[i][j] = fmaf(a0[i], b0[j], acc[i][j]);
    }
    #pragma unroll
    for (int i = 0; i < 4; ++i)
      #pragma unroll
      for (int j = 0; j < 4; ++j) {
        int r = r0 + i, c = cc0 + j;
        sM[r][c] = (r > c) ? sBeta[r] * acc[i][j] : 0.f;
      }
  }
  __syncthreads();

  if (tid < 64) {
    int c = tid;
    for (int i = 0; i < 64; ++i) {
      float acc = sBeta[i] * sK[i][c];
      #pragma unroll 4
      for (int j = 0; j < i; ++j) acc -= sM[i][j] * sW[j][c];
      sW[i][c] = acc;
    }
  } else if (tid < 128) {
    int c = tid - 64;
    for (int i = 0; i < 64; ++i) {
      float acc = sV[i][c];
      #pragma unroll 4
      for (int j = 0; j < i; ++j) acc -= sM[i][j] * sV[j][c];
      sV[i][c] = acc;
    }
  }
  __syncthreads();

  const size_t obase = (size_t)(bh * 16 + g) * 4096;
  for (int i = 0; i < 16; ++i) {
    int idx = tid + i * 256;
    gW[obase + idx] = sW[idx >> 6][idx & 63];
    gU[obase + idx] = sV[idx >> 6][idx & 63];
  }
}

// ---------------- DeltaNet: sequential chunk scan, stores S_g per chunk --------
__global__ __launch_bounds__(256) void delta_scan(const float* __restrict__ qkv,
    const float* __restrict__ gW, const float* __restrict__ gU,
    float* __restrict__ gS) {
  const int bh = blockIdx.x; const int b = bh >> 4, h = bh & 15;
  const int tid = threadIdx.x; const int tx = tid & 15, ty = tid >> 4;
  __shared__ float sS[64][65], sK[64][65], sW[64][65], sU[64][65];
  float Sreg[4][4] = {};
  const int e0 = ty * 4, d0 = tx * 4;
  for (int g = 0; g < 16; ++g) {
    const size_t obase = (size_t)(bh * 16 + g) * 4096;
    for (int i = 0; i < 16; ++i) {
      int idx = tid + i * 256; int r = idx >> 6, d = idx & 63;
      sK[r][d] = qkv[((size_t)b * N_ + g * 64 + r) * 3072 + 1024 + h * 64 + d];
      sW[r][d] = gW[obase + idx];
      sU[r][d] = gU[obase + idx];
    }
    #pragma unroll
    for (int i = 0; i < 4; ++i)
      #pragma unroll
      for (int j = 0; j < 4; ++j) {
        sS[e0+i][d0+j] = Sreg[i][j];
        gS[obase + (size_t)(e0+i) * 64 + d0 + j] = Sreg[i][j];
      }
    __syncthreads();
    {
      float acc[4][4] = {};
      #pragma unroll 4
      for (int kk = 0; kk < 64; ++kk) {
        float a0[4], b0[4];
        #pragma unroll
        for (int i = 0; i < 4; ++i) a0[i] = sW[e0+i][kk];
        #pragma unroll
        for (int j = 0; j < 4; ++j) b0[j] = sS[kk][d0+j];
        #pragma unroll
        for (int i = 0; i < 4; ++i)
          #pragma unroll
          for (int j = 0; j < 4; ++j) acc[i][j] = fmaf(a0[i], b0[j], acc[i][j]);
      }
      #pragma unroll
      for (int i = 0; i < 4; ++i)
        #pragma unroll
        for (int j = 0; j < 4; ++j) sU[e0+i][d0+j] -= acc[i][j];
    }
    __syncthreads();
    #pragma unroll 4
    for (int c = 0; c < 64; ++c) {
      float a0[4], b0[4];
      #pragma unroll
      for (int i = 0; i < 4; ++i) a0[i] = sK[c][e0+i];
      #pragma unroll
      for (int j = 0; j < 4; ++j) b0[j] = sU[c][d0+j];
      #pragma unroll
      for (int i = 0; i < 4; ++i)
        #pragma unroll
        for (int j = 0; j < 4; ++j) Sreg[i][j] = fmaf(a0[i], b0[j], Sreg[i][j]);
    }
    __syncthreads();
  }
}

// ---------------- DeltaNet: per-chunk output o = q@S + tril(q k^T) @ u_adj ----
__global__ __launch_bounds__(256) void delta_outk(const float* __restrict__ qkv,
    const float* __restrict__ gW, const float* __restrict__ gU,
    const float* __restrict__ gS, float* __restrict__ dOut) {
  const int bx = blockIdx.x; const int bh = bx >> 4, g = bx & 15;
  const int b = bh >> 4, h = bh & 15;
  const int tid = threadIdx.x; const int tx = tid & 15, ty = tid >> 4;
  __shared__ float sQ[64][65], sK[64][65], sW[64][65], sU[64][65], sS[64][65], sA[64][65];
  const size_t obase = (size_t)(bh * 16 + g) * 4096;
  for (int i = 0; i < 16; ++i) {
    int idx = tid + i * 256; int r = idx >> 6, d = idx & 63;
    size_t qoff = ((size_t)b * N_ + g * 64 + r) * 3072 + h * 64 + d;
    sQ[r][d] = qkv[qoff];
    sK[r][d] = qkv[qoff + 1024];
    sW[r][d] = gW[obase + idx];
    sU[r][d] = gU[obase + idx];
    sS[r][d] = gS[obase + idx];
  }
  __syncthreads();
  const int r0 = ty * 4, cc0 = tx * 4;
  {
    float acc[4][4] = {};
    #pragma unroll 4
    for (int d = 0; d < 64; ++d) {
      float a0[4], b0[4];
      #pragma unroll
      for (int i = 0; i < 4; ++i) a0[i] = sQ[r0+i][d];
      #pragma unroll
      for (int j = 0; j < 4; ++j) b0[j] = sK[cc0+j][d];
      #pragma unroll
      for (int i = 0; i < 4; ++i)
        #pragma unroll
        for (int j = 0; j < 4; ++j) acc[i][j] = fmaf(a0[i], b0[j], acc[i][j]);
    }
    #pragma unroll
    for (int i = 0; i < 4; ++i)
      #pragma unroll
      for (int j = 0; j < 4; ++j) {
        int r = r0 + i, c = cc0 + j;
        sA[r][c] = (r >= c) ? acc[i][j] : 0.f;
      }
  }
  {
    float acc[4][4] = {};
    #pragma unroll 4
    for (int kk = 0; kk < 64; ++kk) {
      float a0[4], b0[4];
      #pragma unroll
      for (int i = 0; i < 4; ++i) a0[i] = sW[r0+i][kk];
      #pragma unroll
      for (int j = 0; j < 4; ++j) b0[j] = sS[kk][cc0+j];
      #pragma unroll
      for (int i = 0; i < 4; ++i)
        #pragma unroll
        for (int j = 0; j < 4; ++j) acc[i][j] = fmaf(a0[i], b0[j], acc[i][j]);
    }
    #pragma unroll
    for (int i = 0; i < 4; ++i)
      #pragma unroll
      for (int j = 0; j < 4; ++j) sU[r0+i][cc0+j] -= acc[i][j];
  }
  __syncthreads();
  {
    float acc[4][4] = {};
    #pragma unroll 4
    for (int kk = 0; kk < 64; ++kk) {
      float a0[4], b0[4];
      #pragma unroll
      for (int i = 0; i < 4; ++i) a0[i] = sQ[r0+i][kk];
      #pragma unroll
      for (int j = 0; j < 4; ++j) b0[j] = sS[kk][cc0+j];
      #pragma unroll
      for (int i = 0; i < 4; ++i)
        #pragma unroll
        for (int j = 0; j < 4; ++j) acc[i][j] = fmaf(a0[i], b0[j], acc[i][j]);
    }
    #pragma unroll 4
    for (int kk = 0; kk < 64; ++kk) {
      float a0[4], b0[4];
      #pragma unroll
      for (int i = 0; i < 4; ++i) a0[i] = sA[r0+i][kk];
      #pragma unroll
      for (int j = 0; j < 4; ++j) b0[j] = sU[kk][cc0+j];
      #pragma unroll
      for (int i = 0; i < 4; ++i)
        #pragma unroll
        for (int j = 0; j < 4; ++j) acc[i][j] = fmaf(a0[i], b0[j], acc[i][j]);
    }
    #pragma unroll
    for (int i = 0; i < 4; ++i)
      #pragma unroll
      for (int j = 0; j < 4; ++j) {
        int r = r0 + i, c = cc0 + j;
        dOut[(((size_t)b * N_ + g * 64 + r) * H_ + h) * 64 + c] = acc[i][j];
      }
  }
}

// ---------------- fused FIR + cross-mix + gating + ctx -----------------------
// gp: gate+prune logits, stride 96: [0:16]=gate, [16:96]=prune
__global__ __launch_bounds__(256) void paths_k(const float* __restrict__ qkv,
    const float* __restrict__ dOut, const float* __restrict__ idb,
    const float* __restrict__ gp, const float* __restrict__ g2L,
    const float* __restrict__ fir_s, const float* __restrict__ fir_l,
    const float* __restrict__ mix, const float* __restrict__ idlog,
    float* __restrict__ ctx, float* __restrict__ entAcc) {
  const int bn = blockIdx.x; const int b = bn >> 10, n = bn & 1023;
  const int tid = threadIdx.x;
  __shared__ float fS[16][64], fL[16][64];
  __shared__ float sMix[256];
  __shared__ float sWg[16][5], sIdg[16], sEnt[16];
  sMix[tid] = mix[tid];

  #pragma unroll
  for (int i = 0; i < 4; ++i) {
    int idx = tid + i * 256; int hh = idx >> 6, d = idx & 63;
    float accs = 0.f, accl = 0.f;
    #pragma unroll
    for (int j = 0; j < 7; ++j) {
      int t = n - 6 + j;
      float vv = (t >= 0) ? qkv[((size_t)b * 1024 + t) * 3072 + 2048 + idx] : 0.f;
      accl = fmaf(fir_l[(size_t)idx * 7 + j], vv, accl);
      if (j >= 4) accs = fmaf(fir_s[(size_t)idx * 3 + (j - 4)], vv, accs);
    }
    fS[hh][d] = accs; fL[hh][d] = accl;
  }
  __syncthreads();

  float fsm[4], flm[4];
  #pragma unroll
  for (int i = 0; i < 4; ++i) {
    int idx = tid + i * 256; int gg = idx >> 6, d = idx & 63;
    float as = fS[gg][d], al = fL[gg][d];
    #pragma unroll
    for (int hh = 0; hh < 16; ++hh) {
      float m = sMix[hh * 16 + gg];
      as = fmaf(fS[hh][d], m, as);
      al = fmaf(fL[hh][d], m, al);
    }
    fsm[i] = as; flm[i] = al;
  }

  if (tid < 16) {
    float pl[5], lp[5];
    #pragma unroll
    for (int p = 0; p < 5; ++p) pl[p] = gp[(size_t)bn * 96 + 16 + tid * 5 + p];
    float mx = pl[0];
    #pragma unroll
    for (int p = 1; p < 5; ++p) mx = fmaxf(mx, pl[p]);
    float s = 0.f;
    #pragma unroll
    for (int p = 0; p < 5; ++p) { pl[p] = expf(pl[p] - mx); s += pl[p]; }
    float inv = 1.f / s, e1 = 0.f;
    #pragma unroll
    for (int p = 0; p < 5; ++p) {
      float prob = pl[p] * inv;
      lp[p] = logf(prob + 1e-8f);
      e1 -= prob * lp[p];
    }
    float gl[5];
    #pragma unroll
    for (int p = 0; p < 5; ++p) gl[p] = g2L[(size_t)bn * 80 + tid * 5 + p] + lp[p];
    float mx2 = gl[0];
    #pragma unroll
    for (int p = 1; p < 5; ++p) mx2 = fmaxf(mx2, gl[p]);
    float s2 = 0.f;
    #pragma unroll
    for (int p = 0; p < 5; ++p) { gl[p] = expf(gl[p] - mx2); s2 += gl[p]; }
    float inv2 = 1.f / s2, e2 = 0.f;
    #pragma unroll
    for (int p = 0; p < 5; ++p) {
      float w = gl[p] * inv2;
      sWg[tid][p] = w;
      e2 -= w * logf(w + 1e-8f);
    }
    sEnt[tid] = e1 + e2;
    sIdg[tid] = sigmoid_f(gp[(size_t)bn * 96 + tid]) * sigmoid_f(idlog[tid]);
  }
  __syncthreads();

  #pragma unroll
  for (int i = 0; i < 4; ++i) {
    int idx = tid + i * 256; int hh = idx >> 6;
    float w0 = sWg[hh][0], w1 = sWg[hh][1], w2 = sWg[hh][2], w3 = sWg[hh][3], w4 = sWg[hh][4];
    float dv = dOut[(size_t)bn * 1024 + idx];
    float vv = qkv[(size_t)bn * 3072 + 2048 + idx];
    float iv = idb[(size_t)bn * 1024 + idx] * sIdg[hh];
    ctx[(size_t)bn * 1024 + idx] = w0*fsm[i] + w1*flm[i] + w2*dv + w3*vv + w4*iv;
  }
  if (tid == 0) {
    float s = 0.f;
    #pragma unroll
    for (int hh = 0; hh < 16; ++hh) s += sEnt[hh];
    atomicAdd(entAcc, s);
  }
}

__global__ void zero_ent(float* e) { e[0] = 0.f; }
__global__ void ent_fin(const float* __restrict__ e, float* __restrict__ dst) {
  dst[0] = e[0] * (1.0f / 65536.0f);
}

// ---------------- host launcher ----------------------------------------------
extern "C" void kernel_launch(void* const* d_in, const int* in_sizes, int n_in,
                              void* d_out, int out_size, void* d_ws, size_t ws_size,
                              hipStream_t stream) {
  (void)in_sizes; (void)n_in; (void)out_size; (void)ws_size;
  const float* x       = (const float*)d_in[0];
  const float* W_qkv   = (const float*)d_in[1];
  const float* W_id    = (const float*)d_in[2];
  const float* W_gate  = (const float*)d_in[3];
  const float* b_gate  = (const float*)d_in[4];
  const float* idlog   = (const float*)d_in[5];
  const float* fir_s   = (const float*)d_in[6];
  const float* fir_l   = (const float*)d_in[7];
  const float* mix     = (const float*)d_in[8];
  const float* W_prune = (const float*)d_in[9];
  const float* b_prune = (const float*)d_in[10];
  const float* W_g1    = (const float*)d_in[11];
  const float* b_g1    = (const float*)d_in[12];
  const float* W_g2    = (const float*)d_in[13];
  const float* b_g2    = (const float*)d_in[14];
  const float* W_proj  = (const float*)d_in[15];
  const float* b_proj  = (const float*)d_in[16];
  float* out = (float*)d_out;

  float* ws   = (float*)d_ws;
  float* qkv  = ws;                      // 4096 x 3072
  float* idb  = qkv + 12582912;          // 4096 x 1024
  float* gp   = idb + 4194304;           // 4096 x 96 (gate|prune logits)
  float* hbuf = gp + 393216;             // 4096 x 1024 (gelu(g1); reused as ctx)
  float* g2l  = hbuf + 4194304;          // 4096 x 80
  float* gW   = g2l + 327680;            // 64 bh x 16 g x 64 x 64
  float* gU   = gW + 4194304;
  float* gS   = gU + 4194304;
  float* dOut = gS + 4194304;            // (b,n,h,d)
  float* entA = dOut + 4194304;          // 1 float
  float* ctx  = hbuf;                    // alias: hbuf dead after g2 GEMM

  // bf16 scratch aliased into gW/gU (dead until delta_prep / after delta_outk)
  u16* xb     = (u16*)gW;                          // 4096x1024 bf16 (2M fl)
  u16* wqkvT  = (u16*)(gW + 2097152);              // 3072x1024 bf16 (1.5M fl)
  u16* widT   = (u16*)gU;                          // 1024x1024 bf16 (0.5M fl)
  u16* wg1T   = (u16*)(gU + 524288);               // 1024x1024 bf16 (0.5M fl)
  u16* hb16   = (u16*)(gU + 1048576);              // 4096x1024 bf16 (2M fl)
  u16* catGP  = (u16*)(gU + 3145728);              // 128x1024 bf16 (64K fl)
  u16* catG2  = (u16*)(gU + 3211264);              // 128x1024 bf16 (64K fl)
  float* cb1  = gS;                                // 128 fl (dead before delta_scan)
  float* cb2  = gS + 128;                          // 128 fl
  u16* ctxb   = (u16*)gW;                          // post-delta: 4096x1024 bf16
  u16* wprojT = (u16*)(gW + 2097152);              // post-delta: 1024x1024 bf16

  // casts + weight transposes
  conv_bf16<<<2048, 256, 0, stream>>>(x, xb, 524288);
  conv_wt<<<dim3(96, 32), 256, 0, stream>>>(W_qkv, wqkvT, 1024, 3072, 0);
  conv_wt<<<dim3(32, 32), 256, 0, stream>>>(W_id,  widT,  1024, 1024, 0);
  conv_wt<<<dim3(32, 32), 256, 0, stream>>>(W_g1,  wg1T,  1024, 1024, 0);
  conv_wt<<<dim3(1, 32),  256, 0, stream>>>(W_gate,  catGP, 1024, 16, 0);
  conv_wt<<<dim3(3, 32),  256, 0, stream>>>(W_prune, catGP, 1024, 80, 16);
  conv_wt<<<dim3(3, 32),  256, 0, stream>>>(W_g2,    catG2, 1024, 80, 0);
  hipMemsetAsync(catGP + 96 * 1024, 0, 32 * 1024 * sizeof(u16), stream);
  hipMemsetAsync(catG2 + 80 * 1024, 0, 48 * 1024 * sizeof(u16), stream);
  bias_cat<<<1, 256, 0, stream>>>(b_gate, b_prune, b_g2, cb1, cb2);

  // projections from x (bf16 MFMA)
  gemm_mfma<0><<<dim3(24, 32), 256, 0, stream>>>(xb, wqkvT, nullptr, qkv, BN_, 3072, 1024, 3072);
  gemm_mfma<0><<<dim3(8, 32), 256, 0, stream>>>(xb, widT, nullptr, idb, BN_, 1024, 1024, 1024);
  gemm_mfma<1><<<dim3(8, 32), 256, 0, stream>>>(xb, wg1T, b_g1, hbuf, BN_, 1024, 1024, 1024);
  gemm_mfma<0><<<dim3(1, 32), 256, 0, stream>>>(xb, catGP, cb1, gp, BN_, 128, 1024, 96);
  conv_bf16<<<2048, 256, 0, stream>>>(hbuf, hb16, 524288);
  gemm_mfma<0><<<dim3(1, 32), 256, 0, stream>>>(hb16, catG2, cb2, g2l, BN_, 128, 1024, 80);

  // delta rule (overwrites gW/gU — bf16 staging above is dead by now)
  delta_prep<<<1024, 256, 0, stream>>>(qkv, gW, gU);
  delta_scan<<<64, 256, 0, stream>>>(qkv, gW, gU, gS);
  delta_outk<<<1024, 256, 0, stream>>>(qkv, gW, gU, gS, dOut);

  // fused paths + gating
  zero_ent<<<1, 1, 0, stream>>>(entA);
  paths_k<<<BN_, 256, 0, stream>>>(qkv, dOut, idb, gp, g2l,
                                   fir_s, fir_l, mix, idlog, ctx, entA);

  // output projection (bf16 MFMA) + entropy scalar
  conv_bf16<<<2048, 256, 0, stream>>>(ctx, ctxb, 524288);
  conv_wt<<<dim3(32, 32), 256, 0, stream>>>(W_proj, wprojT, 1024, 1024, 0);
  gemm_mfma<0><<<dim3(8, 32), 256, 0, stream>>>(ctxb, wprojT, b_proj, out, BN_, 1024, 1024, 1024);
  ent_fin<<<1, 1, 0, stream>>>(entA, out + 4194304);
}

// Round 4
// 477.802 us; speedup vs baseline: 2.8575x; 1.1605x over previous
//
#include <hip/hip_runtime.h>
#include <math.h>

#define B_ 4
#define N_ 1024
#define C_ 1024
#define H_ 16
#define D_ 64
#define P_ 5
#define BN_ (B_*N_)

typedef unsigned int u32;
typedef unsigned short u16;
typedef __attribute__((ext_vector_type(8))) short bf16x8;
typedef __attribute__((ext_vector_type(4))) float f32x4;

__device__ __forceinline__ float gelu_f(float x){
  float x3 = x*x*x;
  return 0.5f*x*(1.0f + tanhf(0.7978845608028654f*(x + 0.044715f*x3)));
}
__device__ __forceinline__ float sigmoid_f(float x){ return 1.0f/(1.0f+expf(-x)); }

__device__ __forceinline__ u16 f2bf(float f) {
  u32 u = __float_as_uint(f);
  u32 r = u + 0x7fffu + ((u >> 16) & 1u);
  return (u16)(r >> 16);
}

__device__ __forceinline__ void gload16(const void* g, void* l) {
  __builtin_amdgcn_global_load_lds((const __attribute__((address_space(1))) u32*)g,
                                   (__attribute__((address_space(3))) u32*)l, 16, 0, 0);
}

// ---------------- fp32 -> bf16 elementwise cast (8 elems/thread) --------------
__global__ __launch_bounds__(256) void conv_bf16(const float* __restrict__ in,
    u16* __restrict__ out, int n8) {
  int i = blockIdx.x * 256 + threadIdx.x;
  if (i >= n8) return;
  const float4* p = (const float4*)in + (size_t)i * 2;
  float4 a = p[0], b = p[1];
  uint4 o;
  o.x = (u32)f2bf(a.x) | ((u32)f2bf(a.y) << 16);
  o.y = (u32)f2bf(a.z) | ((u32)f2bf(a.w) << 16);
  o.z = (u32)f2bf(b.x) | ((u32)f2bf(b.y) << 16);
  o.w = (u32)f2bf(b.z) | ((u32)f2bf(b.w) << 16);
  *(uint4*)(out + (size_t)i * 8) = o;
}

// ------- fp32 [K][Nn] -> bf16 [Nn][K] transpose cast, guarded, with row offset
__global__ __launch_bounds__(256) void conv_wt(const float* __restrict__ W,
    u16* __restrict__ Wt, int K, int Nn, int roff) {
  __shared__ float t[32][33];
  int c0 = blockIdx.x * 32, r0 = blockIdx.y * 32;
  int tx = threadIdx.x & 31, ty = threadIdx.x >> 5;
  #pragma unroll
  for (int i = 0; i < 4; ++i) {
    int r = ty + i * 8;
    t[r][tx] = (c0 + tx < Nn) ? W[(size_t)(r0 + r) * Nn + c0 + tx] : 0.f;
  }
  __syncthreads();
  #pragma unroll
  for (int i = 0; i < 4; ++i) {
    int r = ty + i * 8;
    if (c0 + r < Nn)
      Wt[(size_t)(roff + c0 + r) * K + r0 + tx] = f2bf(t[tx][r]);
  }
}

// --------- bias concat: cb1 = [b_gate(16) | b_prune(80) | 0], cb2 = [b_g2(80)|0]
__global__ void bias_cat(const float* __restrict__ bg, const float* __restrict__ bp,
    const float* __restrict__ bg2, float* __restrict__ cb1, float* __restrict__ cb2) {
  int t = threadIdx.x;
  if (t < 128) cb1[t] = (t < 16) ? bg[t] : (t < 96 ? bp[t - 16] : 0.f);
  else { int c = t - 128; cb2[c] = (c < 80) ? bg2[c] : 0.f; }
}

// ---------------- bf16 MFMA GEMM: C = A(M,K) @ Bt(Nn,K)^T (+bias, +gelu) ------
// OBF=1: write bf16 (u16) output instead of fp32.
template<int ACT, int OBF>
__global__ __launch_bounds__(256) void gemm_mfma(const u16* __restrict__ A,
    const u16* __restrict__ Bt, const float* __restrict__ bias,
    float* __restrict__ Cout, int M, int Nn, int K, int Ns) {
  __shared__ __align__(16) u16 lA[128 * 32];
  __shared__ __align__(16) u16 lB[128 * 32];
  const int tid = threadIdx.x;
  const int lane = tid & 63, wid = tid >> 6;
  const int wr = wid >> 1, wc = wid & 1;
  const int r16 = lane & 15, kq = lane >> 4;
  const int row0 = blockIdx.y * 128, col0 = blockIdx.x * 128;
  const int c0 = wid * 2;
  const int srow = lane >> 2;
  const int skoff = (lane & 3) * 8;

  f32x4 acc[4][4] = {};
  for (int k0 = 0; k0 < K; k0 += 32) {
    #pragma unroll
    for (int s = 0; s < 2; ++s) {
      int c = c0 + s;
      int rt = c * 16 + srow;
      gload16(A  + (size_t)(row0 + rt) * K + k0 + skoff, &lA[c * 512]);
      gload16(Bt + (size_t)(col0 + rt) * K + k0 + skoff, &lB[c * 512]);
    }
    __syncthreads();
    bf16x8 af[4], bfv[4];
    #pragma unroll
    for (int m = 0; m < 4; ++m)
      af[m] = *(const bf16x8*)&lA[(wr * 64 + m * 16 + r16) * 32 + kq * 8];
    #pragma unroll
    for (int n = 0; n < 4; ++n)
      bfv[n] = *(const bf16x8*)&lB[(wc * 64 + n * 16 + r16) * 32 + kq * 8];
    #pragma unroll
    for (int m = 0; m < 4; ++m)
      #pragma unroll
      for (int n = 0; n < 4; ++n)
        acc[m][n] = __builtin_amdgcn_mfma_f32_16x16x32_bf16(af[m], bfv[n], acc[m][n], 0, 0, 0);
    __syncthreads();
  }
  #pragma unroll
  for (int n = 0; n < 4; ++n) {
    int col = col0 + wc * 64 + n * 16 + r16;
    if (col >= Ns) continue;
    float bs = bias ? bias[col] : 0.0f;
    #pragma unroll
    for (int m = 0; m < 4; ++m) {
      int rowb = row0 + wr * 64 + m * 16 + kq * 4;
      #pragma unroll
      for (int r = 0; r < 4; ++r) {
        float v = acc[m][n][r] + bs;
        if (ACT == 1) v = gelu_f(v);
        if (OBF) ((u16*)Cout)[(size_t)(rowb + r) * Ns + col] = f2bf(v);
        else     Cout[(size_t)(rowb + r) * Ns + col] = v;
      }
    }
  }
}

// ---------------- DeltaNet: per-chunk prep (normalize, M, register solves) ----
__global__ __launch_bounds__(256) void delta_prep(float* __restrict__ qkv,
    float* __restrict__ gW, float* __restrict__ gU) {
  const int bx = blockIdx.x;
  const int bh = bx >> 4, g = bx & 15;
  const int b = bh >> 4, h = bh & 15;
  const int n0 = g * 64;
  const int tid = threadIdx.x;
  __shared__ float sK[64][65];
  __shared__ float sV[64][65];
  __shared__ __align__(16) float sMT[64][68];  // M^T, upper (per-row) zeroed
  __shared__ float sPart[64][8];
  __shared__ float sBeta[64];

  const size_t rowbase = (size_t)b * N_ + n0;
  for (int i = 0; i < 16; ++i) {
    int idx = tid + i * 256; int r = idx >> 6, d = idx & 63;
    size_t off = (rowbase + r) * 3072 + h * 64 + d;
    sK[r][d] = qkv[off + 1024];
    sV[r][d] = qkv[off + 2048];
  }
  if (tid < 64) sBeta[tid] = 1.0f - 0.9f * (float)(n0 + tid) / 1023.0f;
  __syncthreads();

  // parallel norms: thread = (row rr_, quarter qd)
  const int rr_ = tid >> 2, qd = tid & 3;
  float ps = 0.f;
  #pragma unroll
  for (int j = 0; j < 16; ++j) { float v = sK[rr_][qd*16+j]; ps = fmaf(v, v, ps); }
  sPart[rr_][qd] = ps;
  const size_t qbase = (rowbase + rr_) * 3072 + h * 64 + qd * 16;
  float4 qv[4]; float qs = 0.f;
  #pragma unroll
  for (int j = 0; j < 4; ++j) {
    qv[j] = *(const float4*)(qkv + qbase + 4*j);
    qs += qv[j].x*qv[j].x + qv[j].y*qv[j].y + qv[j].z*qv[j].z + qv[j].w*qv[j].w;
  }
  sPart[rr_][4+qd] = qs;
  __syncthreads();
  const float ksc = rsqrtf(sPart[rr_][0]+sPart[rr_][1]+sPart[rr_][2]+sPart[rr_][3] + 1e-6f);
  const float qsc = rsqrtf(sPart[rr_][4]+sPart[rr_][5]+sPart[rr_][6]+sPart[rr_][7] + 1e-6f) * 0.125f;
  #pragma unroll
  for (int j = 0; j < 16; ++j) {
    float v = sK[rr_][qd*16+j] * ksc;
    sK[rr_][qd*16+j] = v;
    qkv[qbase + 1024 + j] = v;           // khat writeback
  }
  #pragma unroll
  for (int j = 0; j < 4; ++j) {
    float4 t = qv[j]; t.x *= qsc; t.y *= qsc; t.z *= qsc; t.w *= qsc;
    *(float4*)(qkv + qbase + 4*j) = t;   // qhat writeback
  }
  __syncthreads();

  // M^T[c][r] = (r>c) ? beta_r * khat_r . khat_c : 0   (microtile GEMM)
  {
    const int tx = tid & 15, ty = tid >> 4;
    const int r0 = ty * 4, cc0 = tx * 4;
    float acc[4][4] = {};
    #pragma unroll 4
    for (int d = 0; d < 64; ++d) {
      float a0[4], b0[4];
      #pragma unroll
      for (int i = 0; i < 4; ++i) a0[i] = sK[r0+i][d];
      #pragma unroll
      for (int j = 0; j < 4; ++j) b0[j] = sK[cc0+j][d];
      #pragma unroll
      for (int i = 0; i < 4; ++i)
        #pragma unroll
        for (int j = 0; j < 4; ++j) acc[i][j] = fmaf(a0[i], b0[j], acc[i][j]);
    }
    #pragma unroll
    for (int i = 0; i < 4; ++i)
      #pragma unroll
      for (int j = 0; j < 4; ++j) {
        int r = r0 + i, c = cc0 + j;
        sMT[c][r] = (r > c) ? sBeta[r] * acc[i][j] : 0.f;
      }
  }
  __syncthreads();

  // register-resident forward substitution; lanes 0-63: kb RHS, 64-127: v*beta RHS
  if (tid < 128) {
    const int c = tid & 63;
    float a[64];
    if (tid < 64) {
      #pragma unroll
      for (int i = 0; i < 64; ++i) a[i] = sBeta[i] * sK[i][c];
    } else {
      #pragma unroll
      for (int i = 0; i < 64; ++i) a[i] = sBeta[i] * sV[i][c];
    }
    #pragma unroll
    for (int i = 0; i < 64; ++i) {
      const float wi = a[i];
      #pragma unroll
      for (int j4 = 0; j4 < 16; ++j4) {
        const float4 m = *(const float4*)&sMT[i][j4 * 4];  // broadcast read
        a[j4*4+0] = fmaf(-m.x, wi, a[j4*4+0]);
        a[j4*4+1] = fmaf(-m.y, wi, a[j4*4+1]);
        a[j4*4+2] = fmaf(-m.z, wi, a[j4*4+2]);
        a[j4*4+3] = fmaf(-m.w, wi, a[j4*4+3]);
      }
    }
    float* dst = (tid < 64) ? gW : gU;
    const size_t obase = (size_t)(bh * 16 + g) * 4096;
    #pragma unroll
    for (int i = 0; i < 64; ++i) dst[obase + i * 64 + c] = a[i];
  }
}

// -------- DeltaNet: sequential chunk scan; stores S_g and u_adj per chunk -----
__global__ __launch_bounds__(256) void delta_scan(const float* __restrict__ qkv,
    const float* __restrict__ gW, float* __restrict__ gU,
    float* __restrict__ gS) {
  const int bh = blockIdx.x; const int b = bh >> 4, h = bh & 15;
  const int tid = threadIdx.x; const int tx = tid & 15, ty = tid >> 4;
  __shared__ float sS[64][65], sK[64][65], sW[64][65], sU[64][65];
  float Sreg[4][4] = {};
  const int e0 = ty * 4, d0 = tx * 4;
  for (int g = 0; g < 16; ++g) {
    const size_t obase = (size_t)(bh * 16 + g) * 4096;
    for (int i = 0; i < 16; ++i) {
      int idx = tid + i * 256; int r = idx >> 6, d = idx & 63;
      sK[r][d] = qkv[((size_t)b * N_ + g * 64 + r) * 3072 + 1024 + h * 64 + d];
      sW[r][d] = gW[obase + idx];
      sU[r][d] = gU[obase + idx];
    }
    #pragma unroll
    for (int i = 0; i < 4; ++i)
      #pragma unroll
      for (int j = 0; j < 4; ++j) {
        sS[e0+i][d0+j] = Sreg[i][j];
        gS[obase + (size_t)(e0+i) * 64 + d0 + j] = Sreg[i][j];
      }
    __syncthreads();
    {  // u_adj = U - W @ S  (in place into sU)
      float acc[4][4] = {};
      #pragma unroll 4
      for (int kk = 0; kk < 64; ++kk) {
        float a0[4], b0[4];
        #pragma unroll
        for (int i = 0; i < 4; ++i) a0[i] = sW[e0+i][kk];
        #pragma unroll
        for (int j = 0; j < 4; ++j) b0[j] = sS[kk][d0+j];
        #pragma unroll
        for (int i = 0; i < 4; ++i)
          #pragma unroll
          for (int j = 0; j < 4; ++j) acc[i][j] = fmaf(a0[i], b0[j], acc[i][j]);
      }
      #pragma unroll
      for (int i = 0; i < 4; ++i)
        #pragma unroll
        for (int j = 0; j < 4; ++j) sU[e0+i][d0+j] -= acc[i][j];
    }
    __syncthreads();
    // persist u_adj for delta_outk (overwrites gU)
    for (int i = 0; i < 16; ++i) {
      int idx = tid + i * 256;
      gU[obase + idx] = sU[idx >> 6][idx & 63];
    }
    // S += K^T @ u_adj
    #pragma unroll 4
    for (int c = 0; c < 64; ++c) {
      float a0[4], b0[4];
      #pragma unroll
      for (int i = 0; i < 4; ++i) a0[i] = sK[c][e0+i];
      #pragma unroll
      for (int j = 0; j < 4; ++j) b0[j] = sU[c][d0+j];
      #pragma unroll
      for (int i = 0; i < 4; ++i)
        #pragma unroll
        for (int j = 0; j < 4; ++j) Sreg[i][j] = fmaf(a0[i], b0[j], Sreg[i][j]);
    }
    __syncthreads();
  }
}

// ---- DeltaNet: per-chunk output o = q@S + tril(q k^T) @ u_adj (u_adj given) --
__global__ __launch_bounds__(256) void delta_outk(const float* __restrict__ qkv,
    const float* __restrict__ gUadj, const float* __restrict__ gS,
    float* __restrict__ dOut) {
  const int bx = blockIdx.x; const int bh = bx >> 4, g = bx & 15;
  const int b = bh >> 4, h = bh & 15;
  const int tid = threadIdx.x; const int tx = tid & 15, ty = tid >> 4;
  __shared__ float sQ[64][65], sKA[64][65], sU[64][65], sS[64][65];
  const size_t obase = (size_t)(bh * 16 + g) * 4096;
  for (int i = 0; i < 16; ++i) {
    int idx = tid + i * 256; int r = idx >> 6, d = idx & 63;
    size_t qoff = ((size_t)b * N_ + g * 64 + r) * 3072 + h * 64 + d;
    sQ[r][d]  = qkv[qoff];
    sKA[r][d] = qkv[qoff + 1024];
    sU[r][d]  = gUadj[obase + idx];
    sS[r][d]  = gS[obase + idx];
  }
  __syncthreads();
  const int r0 = ty * 4, cc0 = tx * 4;
  float at[4][4] = {}, oc[4][4] = {};
  // attn = q k^T (tril applied at store) ; o1 = q @ S
  #pragma unroll 4
  for (int d = 0; d < 64; ++d) {
    float a0[4], b0[4];
    #pragma unroll
    for (int i = 0; i < 4; ++i) a0[i] = sQ[r0+i][d];
    #pragma unroll
    for (int j = 0; j < 4; ++j) b0[j] = sKA[cc0+j][d];
    #pragma unroll
    for (int i = 0; i < 4; ++i)
      #pragma unroll
      for (int j = 0; j < 4; ++j) at[i][j] = fmaf(a0[i], b0[j], at[i][j]);
  }
  #pragma unroll 4
  for (int kk = 0; kk < 64; ++kk) {
    float a0[4], b0[4];
    #pragma unroll
    for (int i = 0; i < 4; ++i) a0[i] = sQ[r0+i][kk];
    #pragma unroll
    for (int j = 0; j < 4; ++j) b0[j] = sS[kk][cc0+j];
    #pragma unroll
    for (int i = 0; i < 4; ++i)
      #pragma unroll
      for (int j = 0; j < 4; ++j) oc[i][j] = fmaf(a0[i], b0[j], oc[i][j]);
  }
  __syncthreads();
  #pragma unroll
  for (int i = 0; i < 4; ++i)
    #pragma unroll
    for (int j = 0; j < 4; ++j) {
      int r = r0 + i, c = cc0 + j;
      sKA[r][c] = (r >= c) ? at[i][j] : 0.f;   // reuse K's LDS for attn
    }
  __syncthreads();
  #pragma unroll 4
  for (int kk = 0; kk < 64; ++kk) {
    float a0[4], b0[4];
    #pragma unroll
    for (int i = 0; i < 4; ++i) a0[i] = sKA[r0+i][kk];
    #pragma unroll
    for (int j = 0; j < 4; ++j) b0[j] = sU[kk][cc0+j];
    #pragma unroll
    for (int i = 0; i < 4; ++i)
      #pragma unroll
      for (int j = 0; j < 4; ++j) oc[i][j] = fmaf(a0[i], b0[j], oc[i][j]);
  }
  #pragma unroll
  for (int i = 0; i < 4; ++i)
    #pragma unroll
    for (int j = 0; j < 4; ++j) {
      int r = r0 + i, c = cc0 + j;
      dOut[(((size_t)b * N_ + g * 64 + r) * H_ + h) * 64 + c] = oc[i][j];
    }
}

// ---------------- fused FIR + cross-mix + gating + ctx (bf16 out) -------------
// gp: gate+prune logits, stride 96: [0:16]=gate, [16:96]=prune
__global__ __launch_bounds__(256) void paths_k(const float* __restrict__ qkv,
    const float* __restrict__ dOut, const float* __restrict__ idb,
    const float* __restrict__ gp, const float* __restrict__ g2L,
    const float* __restrict__ fir_s, const float* __restrict__ fir_l,
    const float* __restrict__ mix, const float* __restrict__ idlog,
    u16* __restrict__ ctxb, float* __restrict__ entAcc) {
  const int bn = blockIdx.x; const int b = bn >> 10, n = bn & 1023;
  const int tid = threadIdx.x;
  __shared__ float fS[16][64], fL[16][64];
  __shared__ float sMix[256];
  __shared__ float sWg[16][5], sIdg[16], sEnt[16];
  sMix[tid] = mix[tid];

  #pragma unroll
  for (int i = 0; i < 4; ++i) {
    int idx = tid + i * 256; int hh = idx >> 6, d = idx & 63;
    float accs = 0.f, accl = 0.f;
    #pragma unroll
    for (int j = 0; j < 7; ++j) {
      int t = n - 6 + j;
      float vv = (t >= 0) ? qkv[((size_t)b * 1024 + t) * 3072 + 2048 + idx] : 0.f;
      accl = fmaf(fir_l[(size_t)idx * 7 + j], vv, accl);
      if (j >= 4) accs = fmaf(fir_s[(size_t)idx * 3 + (j - 4)], vv, accs);
    }
    fS[hh][d] = accs; fL[hh][d] = accl;
  }
  __syncthreads();

  float fsm[4], flm[4];
  #pragma unroll
  for (int i = 0; i < 4; ++i) {
    int idx = tid + i * 256; int gg = idx >> 6, d = idx & 63;
    float as = fS[gg][d], al = fL[gg][d];
    #pragma unroll
    for (int hh = 0; hh < 16; ++hh) {
      float m = sMix[hh * 16 + gg];
      as = fmaf(fS[hh][d], m, as);
      al = fmaf(fL[hh][d], m, al);
    }
    fsm[i] = as; flm[i] = al;
  }

  if (tid < 16) {
    float pl[5], lp[5];
    #pragma unroll
    for (int p = 0; p < 5; ++p) pl[p] = gp[(size_t)bn * 96 + 16 + tid * 5 + p];
    float mx = pl[0];
    #pragma unroll
    for (int p = 1; p < 5; ++p) mx = fmaxf(mx, pl[p]);
    float s = 0.f;
    #pragma unroll
    for (int p = 0; p < 5; ++p) { pl[p] = expf(pl[p] - mx); s += pl[p]; }
    float inv = 1.f / s, e1 = 0.f;
    #pragma unroll
    for (int p = 0; p < 5; ++p) {
      float prob = pl[p] * inv;
      lp[p] = logf(prob + 1e-8f);
      e1 -= prob * lp[p];
    }
    float gl[5];
    #pragma unroll
    for (int p = 0; p < 5; ++p) gl[p] = g2L[(size_t)bn * 80 + tid * 5 + p] + lp[p];
    float mx2 = gl[0];
    #pragma unroll
    for (int p = 1; p < 5; ++p) mx2 = fmaxf(mx2, gl[p]);
    float s2 = 0.f;
    #pragma unroll
    for (int p = 0; p < 5; ++p) { gl[p] = expf(gl[p] - mx2); s2 += gl[p]; }
    float inv2 = 1.f / s2, e2 = 0.f;
    #pragma unroll
    for (int p = 0; p < 5; ++p) {
      float w = gl[p] * inv2;
      sWg[tid][p] = w;
      e2 -= w * logf(w + 1e-8f);
    }
    sEnt[tid] = e1 + e2;
    sIdg[tid] = sigmoid_f(gp[(size_t)bn * 96 + tid]) * sigmoid_f(idlog[tid]);
  }
  __syncthreads();

  #pragma unroll
  for (int i = 0; i < 4; ++i) {
    int idx = tid + i * 256; int hh = idx >> 6;
    float w0 = sWg[hh][0], w1 = sWg[hh][1], w2 = sWg[hh][2], w3 = sWg[hh][3], w4 = sWg[hh][4];
    float dv = dOut[(size_t)bn * 1024 + idx];
    float vv = qkv[(size_t)bn * 3072 + 2048 + idx];
    float iv = idb[(size_t)bn * 1024 + idx] * sIdg[hh];
    ctxb[(size_t)bn * 1024 + idx] = f2bf(w0*fsm[i] + w1*flm[i] + w2*dv + w3*vv + w4*iv);
  }
  if (tid == 0) {
    float s = 0.f;
    #pragma unroll
    for (int hh = 0; hh < 16; ++hh) s += sEnt[hh];
    atomicAdd(entAcc, s);
  }
}

__global__ void zero_ent(float* e) { e[0] = 0.f; }
__global__ void ent_fin(const float* __restrict__ e, float* __restrict__ dst) {
  dst[0] = e[0] * (1.0f / 65536.0f);
}

// ---------------- host launcher ----------------------------------------------
extern "C" void kernel_launch(void* const* d_in, const int* in_sizes, int n_in,
                              void* d_out, int out_size, void* d_ws, size_t ws_size,
                              hipStream_t stream) {
  (void)in_sizes; (void)n_in; (void)out_size; (void)ws_size;
  const float* x       = (const float*)d_in[0];
  const float* W_qkv   = (const float*)d_in[1];
  const float* W_id    = (const float*)d_in[2];
  const float* W_gate  = (const float*)d_in[3];
  const float* b_gate  = (const float*)d_in[4];
  const float* idlog   = (const float*)d_in[5];
  const float* fir_s   = (const float*)d_in[6];
  const float* fir_l   = (const float*)d_in[7];
  const float* mix     = (const float*)d_in[8];
  const float* W_prune = (const float*)d_in[9];
  const float* b_prune = (const float*)d_in[10];
  const float* W_g1    = (const float*)d_in[11];
  const float* b_g1    = (const float*)d_in[12];
  const float* W_g2    = (const float*)d_in[13];
  const float* b_g2    = (const float*)d_in[14];
  const float* W_proj  = (const float*)d_in[15];
  const float* b_proj  = (const float*)d_in[16];
  float* out = (float*)d_out;

  float* ws   = (float*)d_ws;
  float* qkv  = ws;                      // 4096 x 3072
  float* idb  = qkv + 12582912;          // 4096 x 1024
  float* gp   = idb + 4194304;           // 4096 x 96 (gate|prune logits)
  float* hbuf = gp + 393216;             // (unused fp32 slot)
  float* g2l  = hbuf + 4194304;          // 4096 x 80
  float* gW   = g2l + 327680;            // 64 bh x 16 g x 64 x 64
  float* gU   = gW + 4194304;            // u, overwritten with u_adj by scan
  float* gS   = gU + 4194304;
  float* dOut = gS + 4194304;            // (b,n,h,d)
  float* entA = dOut + 4194304;          // 1 float

  // bf16 scratch aliased into gW/gU (dead until delta_prep overwrites)
  u16* xb     = (u16*)gW;                          // 4096x1024 bf16
  u16* wqkvT  = (u16*)(gW + 2097152);              // 3072x1024 bf16
  u16* widT   = (u16*)gU;                          // 1024x1024 bf16
  u16* wg1T   = (u16*)(gU + 524288);               // 1024x1024 bf16
  u16* hb16   = (u16*)(gU + 1048576);              // 4096x1024 bf16 (gelu out)
  u16* catGP  = (u16*)(gU + 3145728);              // 128x1024 bf16
  u16* catG2  = (u16*)(gU + 3211264);              // 128x1024 bf16
  float* cb1  = gS;                                // 128 fl (dead before scan)
  float* cb2  = gS + 128;                          // 128 fl
  u16* ctxb   = (u16*)gW;                          // post-scan: 4096x1024 bf16
  u16* wprojT = (u16*)(gW + 2097152);              // post-scan: 1024x1024 bf16

  // casts + weight transposes
  conv_bf16<<<2048, 256, 0, stream>>>(x, xb, 524288);
  conv_wt<<<dim3(96, 32), 256, 0, stream>>>(W_qkv, wqkvT, 1024, 3072, 0);
  conv_wt<<<dim3(32, 32), 256, 0, stream>>>(W_id,  widT,  1024, 1024, 0);
  conv_wt<<<dim3(32, 32), 256, 0, stream>>>(W_g1,  wg1T,  1024, 1024, 0);
  conv_wt<<<dim3(1, 32),  256, 0, stream>>>(W_gate,  catGP, 1024, 16, 0);
  conv_wt<<<dim3(3, 32),  256, 0, stream>>>(W_prune, catGP, 1024, 80, 16);
  conv_wt<<<dim3(3, 32),  256, 0, stream>>>(W_g2,    catG2, 1024, 80, 0);
  hipMemsetAsync(catGP + 96 * 1024, 0, 32 * 1024 * sizeof(u16), stream);
  hipMemsetAsync(catG2 + 80 * 1024, 0, 48 * 1024 * sizeof(u16), stream);
  bias_cat<<<1, 256, 0, stream>>>(b_gate, b_prune, b_g2, cb1, cb2);

  // projections from x (bf16 MFMA)
  gemm_mfma<0,0><<<dim3(24, 32), 256, 0, stream>>>(xb, wqkvT, nullptr, qkv, BN_, 3072, 1024, 3072);
  gemm_mfma<0,0><<<dim3(8, 32), 256, 0, stream>>>(xb, widT, nullptr, idb, BN_, 1024, 1024, 1024);
  gemm_mfma<1,1><<<dim3(8, 32), 256, 0, stream>>>(xb, wg1T, b_g1, (float*)hb16, BN_, 1024, 1024, 1024);
  gemm_mfma<0,0><<<dim3(1, 32), 256, 0, stream>>>(xb, catGP, cb1, gp, BN_, 128, 1024, 96);
  gemm_mfma<0,0><<<dim3(1, 32), 256, 0, stream>>>(hb16, catG2, cb2, g2l, BN_, 128, 1024, 80);

  // delta rule (overwrites gW/gU — bf16 staging above is dead by now)
  delta_prep<<<1024, 256, 0, stream>>>(qkv, gW, gU);
  delta_scan<<<64, 256, 0, stream>>>(qkv, gW, gU, gS);
  delta_outk<<<1024, 256, 0, stream>>>(qkv, gU, gS, dOut);

  // fused paths + gating (writes bf16 ctx directly into gW region)
  zero_ent<<<1, 1, 0, stream>>>(entA);
  paths_k<<<BN_, 256, 0, stream>>>(qkv, dOut, idb, gp, g2l,
                                   fir_s, fir_l, mix, idlog, ctxb, entA);

  // output projection (bf16 MFMA) + entropy scalar
  conv_wt<<<dim3(32, 32), 256, 0, stream>>>(W_proj, wprojT, 1024, 1024, 0);
  gemm_mfma<0,0><<<dim3(8, 32), 256, 0, stream>>>(ctxb, wprojT, b_proj, out, BN_, 1024, 1024, 1024);
  ent_fin<<<1, 1, 0, stream>>>(entA, out + 4194304);
}

// Round 5
// 439.867 us; speedup vs baseline: 3.1039x; 1.0862x over previous
//
#include <hip/hip_runtime.h>
#include <math.h>

#define B_ 4
#define N_ 1024
#define C_ 1024
#define H_ 16
#define D_ 64
#define P_ 5
#define BN_ (B_*N_)

typedef unsigned int u32;
typedef unsigned short u16;
typedef __attribute__((ext_vector_type(8))) short bf16x8;
typedef __attribute__((ext_vector_type(4))) float f32x4;

__device__ __forceinline__ float gelu_f(float x){
  float x3 = x*x*x;
  return 0.5f*x*(1.0f + tanhf(0.7978845608028654f*(x + 0.044715f*x3)));
}
__device__ __forceinline__ float sigmoid_f(float x){ return 1.0f/(1.0f+expf(-x)); }

__device__ __forceinline__ u16 f2bf(float f) {
  u32 u = __float_as_uint(f);
  u32 r = u + 0x7fffu + ((u >> 16) & 1u);
  return (u16)(r >> 16);
}

__device__ __forceinline__ void gload16(const void* g, void* l) {
  __builtin_amdgcn_global_load_lds((const __attribute__((address_space(1))) u32*)g,
                                   (__attribute__((address_space(3))) u32*)l, 16, 0, 0);
}

// ---------------- fp32 -> bf16 elementwise cast (8 elems/thread) --------------
__global__ __launch_bounds__(256) void conv_bf16(const float* __restrict__ in,
    u16* __restrict__ out, int n8) {
  int i = blockIdx.x * 256 + threadIdx.x;
  if (i >= n8) return;
  const float4* p = (const float4*)in + (size_t)i * 2;
  float4 a = p[0], b = p[1];
  uint4 o;
  o.x = (u32)f2bf(a.x) | ((u32)f2bf(a.y) << 16);
  o.y = (u32)f2bf(a.z) | ((u32)f2bf(a.w) << 16);
  o.z = (u32)f2bf(b.x) | ((u32)f2bf(b.y) << 16);
  o.w = (u32)f2bf(b.z) | ((u32)f2bf(b.w) << 16);
  *(uint4*)(out + (size_t)i * 8) = o;
}

// ------- fp32 [K][Nn] -> bf16 [Nn][K] transpose cast, guarded, with row offset
__global__ __launch_bounds__(256) void conv_wt(const float* __restrict__ W,
    u16* __restrict__ Wt, int K, int Nn, int roff) {
  __shared__ float t[32][33];
  int c0 = blockIdx.x * 32, r0 = blockIdx.y * 32;
  int tx = threadIdx.x & 31, ty = threadIdx.x >> 5;
  #pragma unroll
  for (int i = 0; i < 4; ++i) {
    int r = ty + i * 8;
    t[r][tx] = (c0 + tx < Nn) ? W[(size_t)(r0 + r) * Nn + c0 + tx] : 0.f;
  }
  __syncthreads();
  #pragma unroll
  for (int i = 0; i < 4; ++i) {
    int r = ty + i * 8;
    if (c0 + r < Nn)
      Wt[(size_t)(roff + c0 + r) * K + r0 + tx] = f2bf(t[tx][r]);
  }
}

// --------- bias concat: cb1 = [b_gate(16) | b_prune(80) | 0], cb2 = [b_g2(80)|0]
__global__ void bias_cat(const float* __restrict__ bg, const float* __restrict__ bp,
    const float* __restrict__ bg2, float* __restrict__ cb1, float* __restrict__ cb2) {
  int t = threadIdx.x;
  if (t < 128) cb1[t] = (t < 16) ? bg[t] : (t < 96 ? bp[t - 16] : 0.f);
  else { int c = t - 128; cb2[c] = (c < 80) ? bg2[c] : 0.f; }
}

// ---------------- bf16 MFMA GEMM: C = A(M,K) @ Bt(Nn,K)^T (+bias, +gelu) ------
// OBF=1: write bf16 (u16) output instead of fp32.
template<int ACT, int OBF>
__global__ __launch_bounds__(256) void gemm_mfma(const u16* __restrict__ A,
    const u16* __restrict__ Bt, const float* __restrict__ bias,
    float* __restrict__ Cout, int M, int Nn, int K, int Ns) {
  __shared__ __align__(16) u16 lA[128 * 32];
  __shared__ __align__(16) u16 lB[128 * 32];
  const int tid = threadIdx.x;
  const int lane = tid & 63, wid = tid >> 6;
  const int wr = wid >> 1, wc = wid & 1;
  const int r16 = lane & 15, kq = lane >> 4;
  const int row0 = blockIdx.y * 128, col0 = blockIdx.x * 128;
  const int c0 = wid * 2;
  const int srow = lane >> 2;
  const int skoff = (lane & 3) * 8;

  f32x4 acc[4][4] = {};
  for (int k0 = 0; k0 < K; k0 += 32) {
    #pragma unroll
    for (int s = 0; s < 2; ++s) {
      int c = c0 + s;
      int rt = c * 16 + srow;
      gload16(A  + (size_t)(row0 + rt) * K + k0 + skoff, &lA[c * 512]);
      gload16(Bt + (size_t)(col0 + rt) * K + k0 + skoff, &lB[c * 512]);
    }
    __syncthreads();
    bf16x8 af[4], bfv[4];
    #pragma unroll
    for (int m = 0; m < 4; ++m)
      af[m] = *(const bf16x8*)&lA[(wr * 64 + m * 16 + r16) * 32 + kq * 8];
    #pragma unroll
    for (int n = 0; n < 4; ++n)
      bfv[n] = *(const bf16x8*)&lB[(wc * 64 + n * 16 + r16) * 32 + kq * 8];
    #pragma unroll
    for (int m = 0; m < 4; ++m)
      #pragma unroll
      for (int n = 0; n < 4; ++n)
        acc[m][n] = __builtin_amdgcn_mfma_f32_16x16x32_bf16(af[m], bfv[n], acc[m][n], 0, 0, 0);
    __syncthreads();
  }
  #pragma unroll
  for (int n = 0; n < 4; ++n) {
    int col = col0 + wc * 64 + n * 16 + r16;
    if (col >= Ns) continue;
    float bs = bias ? bias[col] : 0.0f;
    #pragma unroll
    for (int m = 0; m < 4; ++m) {
      int rowb = row0 + wr * 64 + m * 16 + kq * 4;
      #pragma unroll
      for (int r = 0; r < 4; ++r) {
        float v = acc[m][n][r] + bs;
        if (ACT == 1) v = gelu_f(v);
        if (OBF) ((u16*)Cout)[(size_t)(rowb + r) * Ns + col] = f2bf(v);
        else     Cout[(size_t)(rowb + r) * Ns + col] = v;
      }
    }
  }
}

// ---------------- DeltaNet: per-chunk prep (normalize, M, register solves) ----
__global__ __launch_bounds__(256) void delta_prep(float* __restrict__ qkv,
    float* __restrict__ gW, float* __restrict__ gU) {
  const int bx = blockIdx.x;
  const int bh = bx >> 4, g = bx & 15;
  const int b = bh >> 4, h = bh & 15;
  const int n0 = g * 64;
  const int tid = threadIdx.x;
  __shared__ float sK[64][65];
  __shared__ float sV[64][65];
  __shared__ __align__(16) float sMT[64][68];  // M^T, upper (per-row) zeroed
  __shared__ float sPart[64][8];
  __shared__ float sBeta[64];

  const size_t rowbase = (size_t)b * N_ + n0;
  for (int i = 0; i < 16; ++i) {
    int idx = tid + i * 256; int r = idx >> 6, d = idx & 63;
    size_t off = (rowbase + r) * 3072 + h * 64 + d;
    sK[r][d] = qkv[off + 1024];
    sV[r][d] = qkv[off + 2048];
  }
  if (tid < 64) sBeta[tid] = 1.0f - 0.9f * (float)(n0 + tid) / 1023.0f;
  __syncthreads();

  // parallel norms: thread = (row rr_, quarter qd)
  const int rr_ = tid >> 2, qd = tid & 3;
  float ps = 0.f;
  #pragma unroll
  for (int j = 0; j < 16; ++j) { float v = sK[rr_][qd*16+j]; ps = fmaf(v, v, ps); }
  sPart[rr_][qd] = ps;
  const size_t qbase = (rowbase + rr_) * 3072 + h * 64 + qd * 16;
  float4 qv[4]; float qs = 0.f;
  #pragma unroll
  for (int j = 0; j < 4; ++j) {
    qv[j] = *(const float4*)(qkv + qbase + 4*j);
    qs += qv[j].x*qv[j].x + qv[j].y*qv[j].y + qv[j].z*qv[j].z + qv[j].w*qv[j].w;
  }
  sPart[rr_][4+qd] = qs;
  __syncthreads();
  const float ksc = rsqrtf(sPart[rr_][0]+sPart[rr_][1]+sPart[rr_][2]+sPart[rr_][3] + 1e-6f);
  const float qsc = rsqrtf(sPart[rr_][4]+sPart[rr_][5]+sPart[rr_][6]+sPart[rr_][7] + 1e-6f) * 0.125f;
  #pragma unroll
  for (int j = 0; j < 16; ++j) {
    float v = sK[rr_][qd*16+j] * ksc;
    sK[rr_][qd*16+j] = v;
    qkv[qbase + 1024 + j] = v;           // khat writeback
  }
  #pragma unroll
  for (int j = 0; j < 4; ++j) {
    float4 t = qv[j]; t.x *= qsc; t.y *= qsc; t.z *= qsc; t.w *= qsc;
    *(float4*)(qkv + qbase + 4*j) = t;   // qhat writeback
  }
  __syncthreads();

  // M^T[c][r] = (r>c) ? beta_r * khat_r . khat_c : 0   (microtile GEMM)
  {
    const int tx = tid & 15, ty = tid >> 4;
    const int r0 = ty * 4, cc0 = tx * 4;
    float acc[4][4] = {};
    #pragma unroll 4
    for (int d = 0; d < 64; ++d) {
      float a0[4], b0[4];
      #pragma unroll
      for (int i = 0; i < 4; ++i) a0[i] = sK[r0+i][d];
      #pragma unroll
      for (int j = 0; j < 4; ++j) b0[j] = sK[cc0+j][d];
      #pragma unroll
      for (int i = 0; i < 4; ++i)
        #pragma unroll
        for (int j = 0; j < 4; ++j) acc[i][j] = fmaf(a0[i], b0[j], acc[i][j]);
    }
    #pragma unroll
    for (int i = 0; i < 4; ++i)
      #pragma unroll
      for (int j = 0; j < 4; ++j) {
        int r = r0 + i, c = cc0 + j;
        sMT[c][r] = (r > c) ? sBeta[r] * acc[i][j] : 0.f;
      }
  }
  __syncthreads();

  // register-resident forward substitution; lanes 0-63: kb RHS, 64-127: v*beta RHS
  if (tid < 128) {
    const int c = tid & 63;
    float a[64];
    if (tid < 64) {
      #pragma unroll
      for (int i = 0; i < 64; ++i) a[i] = sBeta[i] * sK[i][c];
    } else {
      #pragma unroll
      for (int i = 0; i < 64; ++i) a[i] = sBeta[i] * sV[i][c];
    }
    #pragma unroll
    for (int i = 0; i < 64; ++i) {
      const float wi = a[i];
      #pragma unroll
      for (int j4 = 0; j4 < 16; ++j4) {
        const float4 m = *(const float4*)&sMT[i][j4 * 4];  // broadcast read
        a[j4*4+0] = fmaf(-m.x, wi, a[j4*4+0]);
        a[j4*4+1] = fmaf(-m.y, wi, a[j4*4+1]);
        a[j4*4+2] = fmaf(-m.z, wi, a[j4*4+2]);
        a[j4*4+3] = fmaf(-m.w, wi, a[j4*4+3]);
      }
    }
    float* dst = (tid < 64) ? gW : gU;
    const size_t obase = (size_t)(bh * 16 + g) * 4096;
    #pragma unroll
    for (int i = 0; i < 64; ++i) dst[obase + i * 64 + c] = a[i];
  }
}

// -------- DeltaNet: chunk scan, dv-sliced (4 slices of 16) --------------------
// grid = 64 bh * 4 slices; block computes recurrence for its 16 value-dims.
// Stores S_g (chunk-start) to gS and u_adj to gU (in place).
__global__ __launch_bounds__(256) void delta_scan(const float* __restrict__ qkv,
    const float* __restrict__ gW, float* __restrict__ gU,
    float* __restrict__ gS) {
  const int bx = blockIdx.x;
  const int bh = bx >> 2, sl = bx & 3;
  const int b = bh >> 4, h = bh & 15;
  const int c0 = sl * 16;
  const int tid = threadIdx.x;
  const int cc = tid & 15, r4 = tid >> 4;    // compute mapping: 4 rows x 1 col
  const int kr = tid >> 6, kd = tid & 63;    // K/W load mapping
  __shared__ float sK[64][65], sW[64][65];
  __shared__ float sU[64][17], sS[64][17];

  #pragma unroll
  for (int i = 0; i < 4; ++i) sS[r4 * 4 + i][cc] = 0.f;

  // prefetch chunk 0 into registers
  float pK[16], pW[16], pU[4];
  {
    const size_t ob0 = (size_t)(bh * 16) * 4096;
    #pragma unroll
    for (int i = 0; i < 16; ++i)
      pK[i] = qkv[((size_t)b * N_ + kr + 4 * i) * 3072 + 1024 + h * 64 + kd];
    #pragma unroll
    for (int i = 0; i < 16; ++i) pW[i] = gW[ob0 + (kr + 4 * i) * 64 + kd];
    #pragma unroll
    for (int i = 0; i < 4; ++i)  pU[i] = gU[ob0 + (r4 * 4 + i) * 64 + c0 + cc];
  }

  for (int g = 0; g < 16; ++g) {
    const size_t obase = (size_t)(bh * 16 + g) * 4096;
    __syncthreads();                       // prior-iter LDS reads done
    #pragma unroll
    for (int i = 0; i < 16; ++i) sK[kr + 4 * i][kd] = pK[i];
    #pragma unroll
    for (int i = 0; i < 16; ++i) sW[kr + 4 * i][kd] = pW[i];
    #pragma unroll
    for (int i = 0; i < 4; ++i)  sU[r4 * 4 + i][cc] = pU[i];
    __syncthreads();                       // LDS ready
    if (g < 15) {                          // prefetch next chunk (hidden)
      const size_t ob2 = obase + 4096;
      #pragma unroll
      for (int i = 0; i < 16; ++i)
        pK[i] = qkv[((size_t)b * N_ + (g + 1) * 64 + kr + 4 * i) * 3072 + 1024 + h * 64 + kd];
      #pragma unroll
      for (int i = 0; i < 16; ++i) pW[i] = gW[ob2 + (kr + 4 * i) * 64 + kd];
      #pragma unroll
      for (int i = 0; i < 4; ++i)  pU[i] = gU[ob2 + (r4 * 4 + i) * 64 + c0 + cc];
    }
    // store chunk-start S; u_adj = U - W @ S
    float uadj[4];
    #pragma unroll
    for (int i = 0; i < 4; ++i) {
      gS[obase + (size_t)(r4 * 4 + i) * 64 + c0 + cc] = sS[r4 * 4 + i][cc];
      uadj[i] = sU[r4 * 4 + i][cc];
    }
    #pragma unroll 4
    for (int kk = 0; kk < 64; ++kk) {
      const float sv = sS[kk][cc];
      #pragma unroll
      for (int i = 0; i < 4; ++i) uadj[i] = fmaf(-sW[r4 * 4 + i][kk], sv, uadj[i]);
    }
    __syncthreads();                       // all sS/sU reads done
    #pragma unroll
    for (int i = 0; i < 4; ++i) {
      sU[r4 * 4 + i][cc] = uadj[i];
      gU[obase + (size_t)(r4 * 4 + i) * 64 + c0 + cc] = uadj[i];
    }
    __syncthreads();                       // sU holds u_adj
    // S += K^T @ u_adj  (own elements only)
    float snew[4];
    #pragma unroll
    for (int i = 0; i < 4; ++i) snew[i] = sS[r4 * 4 + i][cc];
    #pragma unroll 4
    for (int cr = 0; cr < 64; ++cr) {
      const float uv = sU[cr][cc];
      #pragma unroll
      for (int i = 0; i < 4; ++i) snew[i] = fmaf(sK[cr][r4 * 4 + i], uv, snew[i]);
    }
    #pragma unroll
    for (int i = 0; i < 4; ++i) sS[r4 * 4 + i][cc] = snew[i];
  }
}

// ---- DeltaNet: per-chunk output o = q@S + tril(q k^T) @ u_adj (u_adj given) --
__global__ __launch_bounds__(256) void delta_outk(const float* __restrict__ qkv,
    const float* __restrict__ gUadj, const float* __restrict__ gS,
    float* __restrict__ dOut) {
  const int bx = blockIdx.x; const int bh = bx >> 4, g = bx & 15;
  const int b = bh >> 4, h = bh & 15;
  const int tid = threadIdx.x; const int tx = tid & 15, ty = tid >> 4;
  __shared__ float sQ[64][65], sKA[64][65], sU[64][65], sS[64][65];
  const size_t obase = (size_t)(bh * 16 + g) * 4096;
  for (int i = 0; i < 16; ++i) {
    int idx = tid + i * 256; int r = idx >> 6, d = idx & 63;
    size_t qoff = ((size_t)b * N_ + g * 64 + r) * 3072 + h * 64 + d;
    sQ[r][d]  = qkv[qoff];
    sKA[r][d] = qkv[qoff + 1024];
    sU[r][d]  = gUadj[obase + idx];
    sS[r][d]  = gS[obase + idx];
  }
  __syncthreads();
  const int r0 = ty * 4, cc0 = tx * 4;
  float at[4][4] = {}, oc[4][4] = {};
  #pragma unroll 4
  for (int d = 0; d < 64; ++d) {
    float a0[4], b0[4];
    #pragma unroll
    for (int i = 0; i < 4; ++i) a0[i] = sQ[r0+i][d];
    #pragma unroll
    for (int j = 0; j < 4; ++j) b0[j] = sKA[cc0+j][d];
    #pragma unroll
    for (int i = 0; i < 4; ++i)
      #pragma unroll
      for (int j = 0; j < 4; ++j) at[i][j] = fmaf(a0[i], b0[j], at[i][j]);
  }
  #pragma unroll 4
  for (int kk = 0; kk < 64; ++kk) {
    float a0[4], b0[4];
    #pragma unroll
    for (int i = 0; i < 4; ++i) a0[i] = sQ[r0+i][kk];
    #pragma unroll
    for (int j = 0; j < 4; ++j) b0[j] = sS[kk][cc0+j];
    #pragma unroll
    for (int i = 0; i < 4; ++i)
      #pragma unroll
      for (int j = 0; j < 4; ++j) oc[i][j] = fmaf(a0[i], b0[j], oc[i][j]);
  }
  __syncthreads();
  #pragma unroll
  for (int i = 0; i < 4; ++i)
    #pragma unroll
    for (int j = 0; j < 4; ++j) {
      int r = r0 + i, c = cc0 + j;
      sKA[r][c] = (r >= c) ? at[i][j] : 0.f;   // reuse K's LDS for attn
    }
  __syncthreads();
  #pragma unroll 4
  for (int kk = 0; kk < 64; ++kk) {
    float a0[4], b0[4];
    #pragma unroll
    for (int i = 0; i < 4; ++i) a0[i] = sKA[r0+i][kk];
    #pragma unroll
    for (int j = 0; j < 4; ++j) b0[j] = sU[kk][cc0+j];
    #pragma unroll
    for (int i = 0; i < 4; ++i)
      #pragma unroll
      for (int j = 0; j < 4; ++j) oc[i][j] = fmaf(a0[i], b0[j], oc[i][j]);
  }
  #pragma unroll
  for (int i = 0; i < 4; ++i)
    #pragma unroll
    for (int j = 0; j < 4; ++j) {
      int r = r0 + i, c = cc0 + j;
      dOut[(((size_t)b * N_ + g * 64 + r) * H_ + h) * 64 + c] = oc[i][j];
    }
}

// ---------------- fused FIR + cross-mix + gating + ctx (bf16 out) -------------
// gp: gate+prune logits, stride 96: [0:16]=gate, [16:96]=prune
__global__ __launch_bounds__(256) void paths_k(const float* __restrict__ qkv,
    const float* __restrict__ dOut, const float* __restrict__ idb,
    const float* __restrict__ gp, const float* __restrict__ g2L,
    const float* __restrict__ fir_s, const float* __restrict__ fir_l,
    const float* __restrict__ mix, const float* __restrict__ idlog,
    u16* __restrict__ ctxb, float* __restrict__ entAcc) {
  const int bn = blockIdx.x; const int b = bn >> 10, n = bn & 1023;
  const int tid = threadIdx.x;
  __shared__ float fS[16][64], fL[16][64];
  __shared__ float sMix[256];
  __shared__ float sWg[16][5], sIdg[16], sEnt[16];
  sMix[tid] = mix[tid];

  #pragma unroll
  for (int i = 0; i < 4; ++i) {
    int idx = tid + i * 256; int hh = idx >> 6, d = idx & 63;
    float accs = 0.f, accl = 0.f;
    #pragma unroll
    for (int j = 0; j < 7; ++j) {
      int t = n - 6 + j;
      float vv = (t >= 0) ? qkv[((size_t)b * 1024 + t) * 3072 + 2048 + idx] : 0.f;
      accl = fmaf(fir_l[(size_t)idx * 7 + j], vv, accl);
      if (j >= 4) accs = fmaf(fir_s[(size_t)idx * 3 + (j - 4)], vv, accs);
    }
    fS[hh][d] = accs; fL[hh][d] = accl;
  }
  __syncthreads();

  float fsm[4], flm[4];
  #pragma unroll
  for (int i = 0; i < 4; ++i) {
    int idx = tid + i * 256; int gg = idx >> 6, d = idx & 63;
    float as = fS[gg][d], al = fL[gg][d];
    #pragma unroll
    for (int hh = 0; hh < 16; ++hh) {
      float m = sMix[hh * 16 + gg];
      as = fmaf(fS[hh][d], m, as);
      al = fmaf(fL[hh][d], m, al);
    }
    fsm[i] = as; flm[i] = al;
  }

  if (tid < 16) {
    float pl[5], lp[5];
    #pragma unroll
    for (int p = 0; p < 5; ++p) pl[p] = gp[(size_t)bn * 96 + 16 + tid * 5 + p];
    float mx = pl[0];
    #pragma unroll
    for (int p = 1; p < 5; ++p) mx = fmaxf(mx, pl[p]);
    float s = 0.f;
    #pragma unroll
    for (int p = 0; p < 5; ++p) { pl[p] = expf(pl[p] - mx); s += pl[p]; }
    float inv = 1.f / s, e1 = 0.f;
    #pragma unroll
    for (int p = 0; p < 5; ++p) {
      float prob = pl[p] * inv;
      lp[p] = logf(prob + 1e-8f);
      e1 -= prob * lp[p];
    }
    float gl[5];
    #pragma unroll
    for (int p = 0; p < 5; ++p) gl[p] = g2L[(size_t)bn * 80 + tid * 5 + p] + lp[p];
    float mx2 = gl[0];
    #pragma unroll
    for (int p = 1; p < 5; ++p) mx2 = fmaxf(mx2, gl[p]);
    float s2 = 0.f;
    #pragma unroll
    for (int p = 0; p < 5; ++p) { gl[p] = expf(gl[p] - mx2); s2 += gl[p]; }
    float inv2 = 1.f / s2, e2 = 0.f;
    #pragma unroll
    for (int p = 0; p < 5; ++p) {
      float w = gl[p] * inv2;
      sWg[tid][p] = w;
      e2 -= w * logf(w + 1e-8f);
    }
    sEnt[tid] = e1 + e2;
    sIdg[tid] = sigmoid_f(gp[(size_t)bn * 96 + tid]) * sigmoid_f(idlog[tid]);
  }
  __syncthreads();

  #pragma unroll
  for (int i = 0; i < 4; ++i) {
    int idx = tid + i * 256; int hh = idx >> 6;
    float w0 = sWg[hh][0], w1 = sWg[hh][1], w2 = sWg[hh][2], w3 = sWg[hh][3], w4 = sWg[hh][4];
    float dv = dOut[(size_t)bn * 1024 + idx];
    float vv = qkv[(size_t)bn * 3072 + 2048 + idx];
    float iv = idb[(size_t)bn * 1024 + idx] * sIdg[hh];
    ctxb[(size_t)bn * 1024 + idx] = f2bf(w0*fsm[i] + w1*flm[i] + w2*dv + w3*vv + w4*iv);
  }
  if (tid == 0) {
    float s = 0.f;
    #pragma unroll
    for (int hh = 0; hh < 16; ++hh) s += sEnt[hh];
    atomicAdd(entAcc, s);
  }
}

__global__ void zero_ent(float* e) { e[0] = 0.f; }
__global__ void ent_fin(const float* __restrict__ e, float* __restrict__ dst) {
  dst[0] = e[0] * (1.0f / 65536.0f);
}

// ---------------- host launcher ----------------------------------------------
extern "C" void kernel_launch(void* const* d_in, const int* in_sizes, int n_in,
                              void* d_out, int out_size, void* d_ws, size_t ws_size,
                              hipStream_t stream) {
  (void)in_sizes; (void)n_in; (void)out_size; (void)ws_size;
  const float* x       = (const float*)d_in[0];
  const float* W_qkv   = (const float*)d_in[1];
  const float* W_id    = (const float*)d_in[2];
  const float* W_gate  = (const float*)d_in[3];
  const float* b_gate  = (const float*)d_in[4];
  const float* idlog   = (const float*)d_in[5];
  const float* fir_s   = (const float*)d_in[6];
  const float* fir_l   = (const float*)d_in[7];
  const float* mix     = (const float*)d_in[8];
  const float* W_prune = (const float*)d_in[9];
  const float* b_prune = (const float*)d_in[10];
  const float* W_g1    = (const float*)d_in[11];
  const float* b_g1    = (const float*)d_in[12];
  const float* W_g2    = (const float*)d_in[13];
  const float* b_g2    = (const float*)d_in[14];
  const float* W_proj  = (const float*)d_in[15];
  const float* b_proj  = (const float*)d_in[16];
  float* out = (float*)d_out;

  float* ws   = (float*)d_ws;
  float* qkv  = ws;                      // 4096 x 3072
  float* idb  = qkv + 12582912;          // 4096 x 1024
  float* gp   = idb + 4194304;           // 4096 x 96 (gate|prune logits)
  float* hbuf = gp + 393216;             // (unused fp32 slot)
  float* g2l  = hbuf + 4194304;          // 4096 x 80
  float* gW   = g2l + 327680;            // 64 bh x 16 g x 64 x 64
  float* gU   = gW + 4194304;            // u, overwritten with u_adj by scan
  float* gS   = gU + 4194304;
  float* dOut = gS + 4194304;            // (b,n,h,d)
  float* entA = dOut + 4194304;          // 1 float

  // bf16 scratch aliased into gW/gU (dead until delta_prep overwrites)
  u16* xb     = (u16*)gW;                          // 4096x1024 bf16
  u16* wqkvT  = (u16*)(gW + 2097152);              // 3072x1024 bf16
  u16* widT   = (u16*)gU;                          // 1024x1024 bf16
  u16* wg1T   = (u16*)(gU + 524288);               // 1024x1024 bf16
  u16* hb16   = (u16*)(gU + 1048576);              // 4096x1024 bf16 (gelu out)
  u16* catGP  = (u16*)(gU + 3145728);              // 128x1024 bf16
  u16* catG2  = (u16*)(gU + 3211264);              // 128x1024 bf16
  float* cb1  = gS;                                // 128 fl (dead before scan)
  float* cb2  = gS + 128;                          // 128 fl
  u16* ctxb   = (u16*)gW;                          // post-scan: 4096x1024 bf16
  u16* wprojT = (u16*)(gW + 2097152);              // post-scan: 1024x1024 bf16

  // casts + weight transposes
  conv_bf16<<<2048, 256, 0, stream>>>(x, xb, 524288);
  conv_wt<<<dim3(96, 32), 256, 0, stream>>>(W_qkv, wqkvT, 1024, 3072, 0);
  conv_wt<<<dim3(32, 32), 256, 0, stream>>>(W_id,  widT,  1024, 1024, 0);
  conv_wt<<<dim3(32, 32), 256, 0, stream>>>(W_g1,  wg1T,  1024, 1024, 0);
  conv_wt<<<dim3(1, 32),  256, 0, stream>>>(W_gate,  catGP, 1024, 16, 0);
  conv_wt<<<dim3(3, 32),  256, 0, stream>>>(W_prune, catGP, 1024, 80, 16);
  conv_wt<<<dim3(3, 32),  256, 0, stream>>>(W_g2,    catG2, 1024, 80, 0);
  hipMemsetAsync(catGP + 96 * 1024, 0, 32 * 1024 * sizeof(u16), stream);
  hipMemsetAsync(catG2 + 80 * 1024, 0, 48 * 1024 * sizeof(u16), stream);
  bias_cat<<<1, 256, 0, stream>>>(b_gate, b_prune, b_g2, cb1, cb2);

  // projections from x (bf16 MFMA)
  gemm_mfma<0,0><<<dim3(24, 32), 256, 0, stream>>>(xb, wqkvT, nullptr, qkv, BN_, 3072, 1024, 3072);
  gemm_mfma<0,0><<<dim3(8, 32), 256, 0, stream>>>(xb, widT, nullptr, idb, BN_, 1024, 1024, 1024);
  gemm_mfma<1,1><<<dim3(8, 32), 256, 0, stream>>>(xb, wg1T, b_g1, (float*)hb16, BN_, 1024, 1024, 1024);
  gemm_mfma<0,0><<<dim3(1, 32), 256, 0, stream>>>(xb, catGP, cb1, gp, BN_, 128, 1024, 96);
  gemm_mfma<0,0><<<dim3(1, 32), 256, 0, stream>>>(hb16, catG2, cb2, g2l, BN_, 128, 1024, 80);

  // delta rule (overwrites gW/gU — bf16 staging above is dead by now)
  delta_prep<<<1024, 256, 0, stream>>>(qkv, gW, gU);
  delta_scan<<<256, 256, 0, stream>>>(qkv, gW, gU, gS);
  delta_outk<<<1024, 256, 0, stream>>>(qkv, gU, gS, dOut);

  // fused paths + gating (writes bf16 ctx directly into gW region)
  zero_ent<<<1, 1, 0, stream>>>(entA);
  paths_k<<<BN_, 256, 0, stream>>>(qkv, dOut, idb, gp, g2l,
                                   fir_s, fir_l, mix, idlog, ctxb, entA);

  // output projection (bf16 MFMA) + entropy scalar
  conv_wt<<<dim3(32, 32), 256, 0, stream>>>(W_proj, wprojT, 1024, 1024, 0);
  gemm_mfma<0,0><<<dim3(8, 32), 256, 0, stream>>>(ctxb, wprojT, b_proj, out, BN_, 1024, 1024, 1024);
  ent_fin<<<1, 1, 0, stream>>>(entA, out + 4194304);
}

// Round 6
// 430.311 us; speedup vs baseline: 3.1728x; 1.0222x over previous
//
#include <hip/hip_runtime.h>
#include <math.h>

#define B_ 4
#define N_ 1024
#define C_ 1024
#define H_ 16
#define D_ 64
#define P_ 5
#define BN_ (B_*N_)

typedef unsigned int u32;
typedef unsigned short u16;
typedef __attribute__((ext_vector_type(8))) short bf16x8;
typedef __attribute__((ext_vector_type(4))) float f32x4;

__device__ __forceinline__ float gelu_f(float x){
  float x3 = x*x*x;
  return 0.5f*x*(1.0f + tanhf(0.7978845608028654f*(x + 0.044715f*x3)));
}
__device__ __forceinline__ float sigmoid_f(float x){ return 1.0f/(1.0f+expf(-x)); }

__device__ __forceinline__ u16 f2bf(float f) {
  u32 u = __float_as_uint(f);
  u32 r = u + 0x7fffu + ((u >> 16) & 1u);
  return (u16)(r >> 16);
}
__device__ __forceinline__ float bfu2f(u32 lo16){ return __uint_as_float(lo16 << 16); }

__device__ __forceinline__ void gload16(const void* g, void* l) {
  __builtin_amdgcn_global_load_lds((const __attribute__((address_space(1))) u32*)g,
                                   (__attribute__((address_space(3))) u32*)l, 16, 0, 0);
}

// ---------------- fp32 -> bf16 elementwise cast (8 elems/thread) --------------
__global__ __launch_bounds__(256) void conv_bf16(const float* __restrict__ in,
    u16* __restrict__ out, int n8) {
  int i = blockIdx.x * 256 + threadIdx.x;
  if (i >= n8) return;
  const float4* p = (const float4*)in + (size_t)i * 2;
  float4 a = p[0], b = p[1];
  uint4 o;
  o.x = (u32)f2bf(a.x) | ((u32)f2bf(a.y) << 16);
  o.y = (u32)f2bf(a.z) | ((u32)f2bf(a.w) << 16);
  o.z = (u32)f2bf(b.x) | ((u32)f2bf(b.y) << 16);
  o.w = (u32)f2bf(b.z) | ((u32)f2bf(b.w) << 16);
  *(uint4*)(out + (size_t)i * 8) = o;
}

// ------- fp32 [K][Nn] -> bf16 [Nn][K] transpose cast, guarded, with row offset
__global__ __launch_bounds__(256) void conv_wt(const float* __restrict__ W,
    u16* __restrict__ Wt, int K, int Nn, int roff) {
  __shared__ float t[32][33];
  int c0 = blockIdx.x * 32, r0 = blockIdx.y * 32;
  int tx = threadIdx.x & 31, ty = threadIdx.x >> 5;
  #pragma unroll
  for (int i = 0; i < 4; ++i) {
    int r = ty + i * 8;
    t[r][tx] = (c0 + tx < Nn) ? W[(size_t)(r0 + r) * Nn + c0 + tx] : 0.f;
  }
  __syncthreads();
  #pragma unroll
  for (int i = 0; i < 4; ++i) {
    int r = ty + i * 8;
    if (c0 + r < Nn)
      Wt[(size_t)(roff + c0 + r) * K + r0 + tx] = f2bf(t[tx][r]);
  }
}

// --------- bias concat: cb1 = [b_gate(16) | b_prune(80) | 0], cb2 = [b_g2(80)|0]
__global__ void bias_cat(const float* __restrict__ bg, const float* __restrict__ bp,
    const float* __restrict__ bg2, float* __restrict__ cb1, float* __restrict__ cb2) {
  int t = threadIdx.x;
  if (t < 128) cb1[t] = (t < 16) ? bg[t] : (t < 96 ? bp[t - 16] : 0.f);
  else { int c = t - 128; cb2[c] = (c < 80) ? bg2[c] : 0.f; }
}

// ---------------- bf16 MFMA GEMM: C = A(M,K) @ Bt(Nn,K)^T (+bias, +gelu) ------
// OBF=1: write bf16 (u16) output instead of fp32.
template<int ACT, int OBF>
__global__ __launch_bounds__(256) void gemm_mfma(const u16* __restrict__ A,
    const u16* __restrict__ Bt, const float* __restrict__ bias,
    float* __restrict__ Cout, int M, int Nn, int K, int Ns) {
  __shared__ __align__(16) u16 lA[128 * 32];
  __shared__ __align__(16) u16 lB[128 * 32];
  const int tid = threadIdx.x;
  const int lane = tid & 63, wid = tid >> 6;
  const int wr = wid >> 1, wc = wid & 1;
  const int r16 = lane & 15, kq = lane >> 4;
  const int row0 = blockIdx.y * 128, col0 = blockIdx.x * 128;
  const int c0 = wid * 2;
  const int srow = lane >> 2;
  const int skoff = (lane & 3) * 8;

  f32x4 acc[4][4] = {};
  for (int k0 = 0; k0 < K; k0 += 32) {
    #pragma unroll
    for (int s = 0; s < 2; ++s) {
      int c = c0 + s;
      int rt = c * 16 + srow;
      gload16(A  + (size_t)(row0 + rt) * K + k0 + skoff, &lA[c * 512]);
      gload16(Bt + (size_t)(col0 + rt) * K + k0 + skoff, &lB[c * 512]);
    }
    __syncthreads();
    bf16x8 af[4], bfv[4];
    #pragma unroll
    for (int m = 0; m < 4; ++m)
      af[m] = *(const bf16x8*)&lA[(wr * 64 + m * 16 + r16) * 32 + kq * 8];
    #pragma unroll
    for (int n = 0; n < 4; ++n)
      bfv[n] = *(const bf16x8*)&lB[(wc * 64 + n * 16 + r16) * 32 + kq * 8];
    #pragma unroll
    for (int m = 0; m < 4; ++m)
      #pragma unroll
      for (int n = 0; n < 4; ++n)
        acc[m][n] = __builtin_amdgcn_mfma_f32_16x16x32_bf16(af[m], bfv[n], acc[m][n], 0, 0, 0);
    __syncthreads();
  }
  #pragma unroll
  for (int n = 0; n < 4; ++n) {
    int col = col0 + wc * 64 + n * 16 + r16;
    if (col >= Ns) continue;
    float bs = bias ? bias[col] : 0.0f;
    #pragma unroll
    for (int m = 0; m < 4; ++m) {
      int rowb = row0 + wr * 64 + m * 16 + kq * 4;
      #pragma unroll
      for (int r = 0; r < 4; ++r) {
        float v = acc[m][n][r] + bs;
        if (ACT == 1) v = gelu_f(v);
        if (OBF) ((u16*)Cout)[(size_t)(rowb + r) * Ns + col] = f2bf(v);
        else     Cout[(size_t)(rowb + r) * Ns + col] = v;
      }
    }
  }
}

// ---------------- DeltaNet: per-chunk prep (normalize, M, register solves) ----
// qkv row stride 4096 (q|k|v|id). Writes khat fp32 back, khat bf16 -> kb,
// W bf16 -> wb, u fp32 -> gU.
__global__ __launch_bounds__(256) void delta_prep(float* __restrict__ qkv,
    float* __restrict__ gU, u16* __restrict__ kb, u16* __restrict__ wb) {
  const int bx = blockIdx.x;
  const int bh = bx >> 4, g = bx & 15;
  const int b = bh >> 4, h = bh & 15;
  const int n0 = g * 64;
  const int tid = threadIdx.x;
  __shared__ float sK[64][65];
  __shared__ float sV[64][65];
  __shared__ __align__(16) float sMT[64][68];  // M^T, upper (per-row) zeroed
  __shared__ float sPart[64][8];
  __shared__ float sBeta[64];

  const size_t rowbase = (size_t)b * N_ + n0;
  for (int i = 0; i < 16; ++i) {
    int idx = tid + i * 256; int r = idx >> 6, d = idx & 63;
    size_t off = (rowbase + r) * 4096 + h * 64 + d;
    sK[r][d] = qkv[off + 1024];
    sV[r][d] = qkv[off + 2048];
  }
  if (tid < 64) sBeta[tid] = 1.0f - 0.9f * (float)(n0 + tid) / 1023.0f;
  __syncthreads();

  // parallel norms: thread = (row rr_, quarter qd)
  const int rr_ = tid >> 2, qd = tid & 3;
  float ps = 0.f;
  #pragma unroll
  for (int j = 0; j < 16; ++j) { float v = sK[rr_][qd*16+j]; ps = fmaf(v, v, ps); }
  sPart[rr_][qd] = ps;
  const size_t qbase = (rowbase + rr_) * 4096 + h * 64 + qd * 16;
  float4 qv[4]; float qs = 0.f;
  #pragma unroll
  for (int j = 0; j < 4; ++j) {
    qv[j] = *(const float4*)(qkv + qbase + 4*j);
    qs += qv[j].x*qv[j].x + qv[j].y*qv[j].y + qv[j].z*qv[j].z + qv[j].w*qv[j].w;
  }
  sPart[rr_][4+qd] = qs;
  __syncthreads();
  const float ksc = rsqrtf(sPart[rr_][0]+sPart[rr_][1]+sPart[rr_][2]+sPart[rr_][3] + 1e-6f);
  const float qsc = rsqrtf(sPart[rr_][4]+sPart[rr_][5]+sPart[rr_][6]+sPart[rr_][7] + 1e-6f) * 0.125f;
  const size_t cbase = (size_t)bx * 4096 + rr_ * 64 + qd * 16;
  #pragma unroll
  for (int j = 0; j < 16; ++j) {
    float v = sK[rr_][qd*16+j] * ksc;
    sK[rr_][qd*16+j] = v;
    qkv[qbase + 1024 + j] = v;           // khat fp32 writeback (outk)
    kb[cbase + j] = f2bf(v);             // khat bf16 (scan)
  }
  #pragma unroll
  for (int j = 0; j < 4; ++j) {
    float4 t = qv[j]; t.x *= qsc; t.y *= qsc; t.z *= qsc; t.w *= qsc;
    *(float4*)(qkv + qbase + 4*j) = t;   // qhat writeback
  }
  __syncthreads();

  // M^T[c][r] = (r>c) ? beta_r * khat_r . khat_c : 0   (microtile GEMM)
  {
    const int tx = tid & 15, ty = tid >> 4;
    const int r0 = ty * 4, cc0 = tx * 4;
    float acc[4][4] = {};
    #pragma unroll 4
    for (int d = 0; d < 64; ++d) {
      float a0[4], b0[4];
      #pragma unroll
      for (int i = 0; i < 4; ++i) a0[i] = sK[r0+i][d];
      #pragma unroll
      for (int j = 0; j < 4; ++j) b0[j] = sK[cc0+j][d];
      #pragma unroll
      for (int i = 0; i < 4; ++i)
        #pragma unroll
        for (int j = 0; j < 4; ++j) acc[i][j] = fmaf(a0[i], b0[j], acc[i][j]);
    }
    #pragma unroll
    for (int i = 0; i < 4; ++i)
      #pragma unroll
      for (int j = 0; j < 4; ++j) {
        int r = r0 + i, c = cc0 + j;
        sMT[c][r] = (r > c) ? sBeta[r] * acc[i][j] : 0.f;
      }
  }
  __syncthreads();

  // register-resident forward substitution; lanes 0-63: kb RHS, 64-127: v*beta RHS
  if (tid < 128) {
    const int c = tid & 63;
    float a[64];
    if (tid < 64) {
      #pragma unroll
      for (int i = 0; i < 64; ++i) a[i] = sBeta[i] * sK[i][c];
    } else {
      #pragma unroll
      for (int i = 0; i < 64; ++i) a[i] = sBeta[i] * sV[i][c];
    }
    #pragma unroll
    for (int i = 0; i < 64; ++i) {
      const float wi = a[i];
      #pragma unroll
      for (int j4 = 0; j4 < 16; ++j4) {
        const float4 m = *(const float4*)&sMT[i][j4 * 4];  // broadcast read
        a[j4*4+0] = fmaf(-m.x, wi, a[j4*4+0]);
        a[j4*4+1] = fmaf(-m.y, wi, a[j4*4+1]);
        a[j4*4+2] = fmaf(-m.z, wi, a[j4*4+2]);
        a[j4*4+3] = fmaf(-m.w, wi, a[j4*4+3]);
      }
    }
    const size_t obase = (size_t)bx * 4096;
    if (tid < 64) {   // W -> bf16 only (scan consumes bf16)
      #pragma unroll
      for (int i = 0; i < 64; ++i) wb[obase + i * 64 + c] = f2bf(a[i]);
    } else {          // u -> fp32 (scan RHS accuracy)
      #pragma unroll
      for (int i = 0; i < 64; ++i) gU[obase + i * 64 + c] = a[i];
    }
  }
}

#define PUT8(arr,row,base,v0) { \
  arr[row][(base)+0]=bfu2f((v0).x&0xffffu); arr[row][(base)+1]=bfu2f((v0).x>>16); \
  arr[row][(base)+2]=bfu2f((v0).y&0xffffu); arr[row][(base)+3]=bfu2f((v0).y>>16); \
  arr[row][(base)+4]=bfu2f((v0).z&0xffffu); arr[row][(base)+5]=bfu2f((v0).z>>16); \
  arr[row][(base)+6]=bfu2f((v0).w&0xffffu); arr[row][(base)+7]=bfu2f((v0).w>>16); }

// -------- DeltaNet: chunk scan, dv-sliced (8 slices of 8), bf16 K/W -----------
// grid = 64 bh * 8 slices. Stores S_g (chunk-start) to gS, u_adj to gU in place.
__global__ __launch_bounds__(256) void delta_scan(const u16* __restrict__ kb,
    const u16* __restrict__ wb, float* __restrict__ gU, float* __restrict__ gS) {
  const int bx = blockIdx.x;
  const int bh = bx >> 3, sl = bx & 7;
  const int c0 = sl * 8;
  const int tid = threadIdx.x;
  const int cc = tid & 7, rr = tid >> 3;        // own rows rr, rr+32; col c0+cc
  const int lrow = tid >> 2, ld0 = (tid & 3) * 16;  // K/W fill mapping
  __shared__ float sK[64][65], sW[64][65];
  __shared__ float sU[64][9], sS[64][9];
  sS[rr][cc] = 0.f; sS[rr + 32][cc] = 0.f;

  // prefetch chunk 0
  uint4 pK0, pK1, pW0, pW1; float pU0, pU1;
  {
    const size_t ob0 = (size_t)(bh * 16) * 4096;
    pK0 = *(const uint4*)(kb + ob0 + tid * 16);
    pK1 = *(const uint4*)(kb + ob0 + tid * 16 + 8);
    pW0 = *(const uint4*)(wb + ob0 + tid * 16);
    pW1 = *(const uint4*)(wb + ob0 + tid * 16 + 8);
    pU0 = gU[ob0 + rr * 64 + c0 + cc];
    pU1 = gU[ob0 + (rr + 32) * 64 + c0 + cc];
  }

  for (int g = 0; g < 16; ++g) {
    const size_t obase = (size_t)(bh * 16 + g) * 4096;
    __syncthreads();                       // prior-iter LDS reads done
    PUT8(sK, lrow, ld0, pK0); PUT8(sK, lrow, ld0 + 8, pK1);
    PUT8(sW, lrow, ld0, pW0); PUT8(sW, lrow, ld0 + 8, pW1);
    sU[rr][cc] = pU0; sU[rr + 32][cc] = pU1;
    __syncthreads();                       // LDS ready
    if (g < 15) {                          // prefetch next chunk (hidden)
      const size_t ob2 = obase + 4096;
      pK0 = *(const uint4*)(kb + ob2 + tid * 16);
      pK1 = *(const uint4*)(kb + ob2 + tid * 16 + 8);
      pW0 = *(const uint4*)(wb + ob2 + tid * 16);
      pW1 = *(const uint4*)(wb + ob2 + tid * 16 + 8);
      pU0 = gU[ob2 + rr * 64 + c0 + cc];
      pU1 = gU[ob2 + (rr + 32) * 64 + c0 + cc];
    }
    // store chunk-start S; u_adj = U - W @ S
    float u0 = sU[rr][cc], u1 = sU[rr + 32][cc];
    gS[obase + rr * 64 + c0 + cc]        = sS[rr][cc];
    gS[obase + (rr + 32) * 64 + c0 + cc] = sS[rr + 32][cc];
    #pragma unroll 16
    for (int k = 0; k < 64; ++k) {
      const float sv = sS[k][cc];
      u0 = fmaf(-sW[rr][k],      sv, u0);
      u1 = fmaf(-sW[rr + 32][k], sv, u1);
    }
    __syncthreads();                       // all sS/sU reads done
    sU[rr][cc] = u0; sU[rr + 32][cc] = u1;
    gU[obase + rr * 64 + c0 + cc]        = u0;
    gU[obase + (rr + 32) * 64 + c0 + cc] = u1;
    __syncthreads();                       // sU holds u_adj
    // S += K^T @ u_adj (own elements)
    float s0 = sS[rr][cc], s1 = sS[rr + 32][cc];
    #pragma unroll 16
    for (int cr = 0; cr < 64; ++cr) {
      const float uv = sU[cr][cc];
      s0 = fmaf(sK[cr][rr],      uv, s0);
      s1 = fmaf(sK[cr][rr + 32], uv, s1);
    }
    sS[rr][cc] = s0; sS[rr + 32][cc] = s1;
  }
}

// ---- DeltaNet: per-chunk output o = q@S + tril(q k^T) @ u_adj (u_adj given) --
__global__ __launch_bounds__(256) void delta_outk(const float* __restrict__ qkv,
    const float* __restrict__ gUadj, const float* __restrict__ gS,
    float* __restrict__ dOut) {
  const int bx = blockIdx.x; const int bh = bx >> 4, g = bx & 15;
  const int b = bh >> 4, h = bh & 15;
  const int tid = threadIdx.x; const int tx = tid & 15, ty = tid >> 4;
  __shared__ float sQ[64][65], sKA[64][65], sU[64][65], sS[64][65];
  const size_t obase = (size_t)(bh * 16 + g) * 4096;
  for (int i = 0; i < 16; ++i) {
    int idx = tid + i * 256; int r = idx >> 6, d = idx & 63;
    size_t qoff = ((size_t)b * N_ + g * 64 + r) * 4096 + h * 64 + d;
    sQ[r][d]  = qkv[qoff];
    sKA[r][d] = qkv[qoff + 1024];
    sU[r][d]  = gUadj[obase + idx];
    sS[r][d]  = gS[obase + idx];
  }
  __syncthreads();
  const int r0 = ty * 4, cc0 = tx * 4;
  float at[4][4] = {}, oc[4][4] = {};
  #pragma unroll 4
  for (int d = 0; d < 64; ++d) {
    float a0[4], b0[4];
    #pragma unroll
    for (int i = 0; i < 4; ++i) a0[i] = sQ[r0+i][d];
    #pragma unroll
    for (int j = 0; j < 4; ++j) b0[j] = sKA[cc0+j][d];
    #pragma unroll
    for (int i = 0; i < 4; ++i)
      #pragma unroll
      for (int j = 0; j < 4; ++j) at[i][j] = fmaf(a0[i], b0[j], at[i][j]);
  }
  #pragma unroll 4
  for (int kk = 0; kk < 64; ++kk) {
    float a0[4], b0[4];
    #pragma unroll
    for (int i = 0; i < 4; ++i) a0[i] = sQ[r0+i][kk];
    #pragma unroll
    for (int j = 0; j < 4; ++j) b0[j] = sS[kk][cc0+j];
    #pragma unroll
    for (int i = 0; i < 4; ++i)
      #pragma unroll
      for (int j = 0; j < 4; ++j) oc[i][j] = fmaf(a0[i], b0[j], oc[i][j]);
  }
  __syncthreads();
  #pragma unroll
  for (int i = 0; i < 4; ++i)
    #pragma unroll
    for (int j = 0; j < 4; ++j) {
      int r = r0 + i, c = cc0 + j;
      sKA[r][c] = (r >= c) ? at[i][j] : 0.f;   // reuse K's LDS for attn
    }
  __syncthreads();
  #pragma unroll 4
  for (int kk = 0; kk < 64; ++kk) {
    float a0[4], b0[4];
    #pragma unroll
    for (int i = 0; i < 4; ++i) a0[i] = sKA[r0+i][kk];
    #pragma unroll
    for (int j = 0; j < 4; ++j) b0[j] = sU[kk][cc0+j];
    #pragma unroll
    for (int i = 0; i < 4; ++i)
      #pragma unroll
      for (int j = 0; j < 4; ++j) oc[i][j] = fmaf(a0[i], b0[j], oc[i][j]);
  }
  #pragma unroll
  for (int i = 0; i < 4; ++i)
    #pragma unroll
    for (int j = 0; j < 4; ++j) {
      int r = r0 + i, c = cc0 + j;
      dOut[(((size_t)b * N_ + g * 64 + r) * H_ + h) * 64 + c] = oc[i][j];
    }
}

// ---------------- fused FIR + cross-mix + gating + ctx (bf16 out) -------------
// qkv row stride 4096 (q|k|v|id); gp stride 96: [0:16]=gate, [16:96]=prune
__global__ __launch_bounds__(256) void paths_k(const float* __restrict__ qkv,
    const float* __restrict__ dOut, const float* __restrict__ gp,
    const float* __restrict__ g2L, const float* __restrict__ fir_s,
    const float* __restrict__ fir_l, const float* __restrict__ mix,
    const float* __restrict__ idlog, u16* __restrict__ ctxb,
    float* __restrict__ entAcc) {
  const int bn = blockIdx.x; const int b = bn >> 10, n = bn & 1023;
  const int tid = threadIdx.x;
  __shared__ float fS[16][64], fL[16][64];
  __shared__ float sMix[256];
  __shared__ float sWg[16][5], sIdg[16], sEnt[16];
  sMix[tid] = mix[tid];

  #pragma unroll
  for (int i = 0; i < 4; ++i) {
    int idx = tid + i * 256; int hh = idx >> 6, d = idx & 63;
    float accs = 0.f, accl = 0.f;
    #pragma unroll
    for (int j = 0; j < 7; ++j) {
      int t = n - 6 + j;
      float vv = (t >= 0) ? qkv[((size_t)b * 1024 + t) * 4096 + 2048 + idx] : 0.f;
      accl = fmaf(fir_l[(size_t)idx * 7 + j], vv, accl);
      if (j >= 4) accs = fmaf(fir_s[(size_t)idx * 3 + (j - 4)], vv, accs);
    }
    fS[hh][d] = accs; fL[hh][d] = accl;
  }
  __syncthreads();

  float fsm[4], flm[4];
  #pragma unroll
  for (int i = 0; i < 4; ++i) {
    int idx = tid + i * 256; int gg = idx >> 6, d = idx & 63;
    float as = fS[gg][d], al = fL[gg][d];
    #pragma unroll
    for (int hh = 0; hh < 16; ++hh) {
      float m = sMix[hh * 16 + gg];
      as = fmaf(fS[hh][d], m, as);
      al = fmaf(fL[hh][d], m, al);
    }
    fsm[i] = as; flm[i] = al;
  }

  if (tid < 16) {
    float pl[5], lp[5];
    #pragma unroll
    for (int p = 0; p < 5; ++p) pl[p] = gp[(size_t)bn * 96 + 16 + tid * 5 + p];
    float mx = pl[0];
    #pragma unroll
    for (int p = 1; p < 5; ++p) mx = fmaxf(mx, pl[p]);
    float s = 0.f;
    #pragma unroll
    for (int p = 0; p < 5; ++p) { pl[p] = expf(pl[p] - mx); s += pl[p]; }
    float inv = 1.f / s, e1 = 0.f;
    #pragma unroll
    for (int p = 0; p < 5; ++p) {
      float prob = pl[p] * inv;
      lp[p] = logf(prob + 1e-8f);
      e1 -= prob * lp[p];
    }
    float gl[5];
    #pragma unroll
    for (int p = 0; p < 5; ++p) gl[p] = g2L[(size_t)bn * 80 + tid * 5 + p] + lp[p];
    float mx2 = gl[0];
    #pragma unroll
    for (int p = 1; p < 5; ++p) mx2 = fmaxf(mx2, gl[p]);
    float s2 = 0.f;
    #pragma unroll
    for (int p = 0; p < 5; ++p) { gl[p] = expf(gl[p] - mx2); s2 += gl[p]; }
    float inv2 = 1.f / s2, e2 = 0.f;
    #pragma unroll
    for (int p = 0; p < 5; ++p) {
      float w = gl[p] * inv2;
      sWg[tid][p] = w;
      e2 -= w * logf(w + 1e-8f);
    }
    sEnt[tid] = e1 + e2;
    sIdg[tid] = sigmoid_f(gp[(size_t)bn * 96 + tid]) * sigmoid_f(idlog[tid]);
  }
  __syncthreads();

  #pragma unroll
  for (int i = 0; i < 4; ++i) {
    int idx = tid + i * 256; int hh = idx >> 6;
    float w0 = sWg[hh][0], w1 = sWg[hh][1], w2 = sWg[hh][2], w3 = sWg[hh][3], w4 = sWg[hh][4];
    float dv = dOut[(size_t)bn * 1024 + idx];
    float vv = qkv[(size_t)bn * 4096 + 2048 + idx];
    float iv = qkv[(size_t)bn * 4096 + 3072 + idx] * sIdg[hh];
    ctxb[(size_t)bn * 1024 + idx] = f2bf(w0*fsm[i] + w1*flm[i] + w2*dv + w3*vv + w4*iv);
  }
  if (tid == 0) {
    float s = 0.f;
    #pragma unroll
    for (int hh = 0; hh < 16; ++hh) s += sEnt[hh];
    atomicAdd(entAcc, s);
  }
}

__global__ void zero_ent(float* e) { e[0] = 0.f; }
__global__ void ent_fin(const float* __restrict__ e, float* __restrict__ dst) {
  dst[0] = e[0] * (1.0f / 65536.0f);
}

// ---------------- host launcher ----------------------------------------------
extern "C" void kernel_launch(void* const* d_in, const int* in_sizes, int n_in,
                              void* d_out, int out_size, void* d_ws, size_t ws_size,
                              hipStream_t stream) {
  (void)in_sizes; (void)n_in; (void)out_size; (void)ws_size;
  const float* x       = (const float*)d_in[0];
  const float* W_qkv   = (const float*)d_in[1];
  const float* W_id    = (const float*)d_in[2];
  const float* W_gate  = (const float*)d_in[3];
  const float* b_gate  = (const float*)d_in[4];
  const float* idlog   = (const float*)d_in[5];
  const float* fir_s   = (const float*)d_in[6];
  const float* fir_l   = (const float*)d_in[7];
  const float* mix     = (const float*)d_in[8];
  const float* W_prune = (const float*)d_in[9];
  const float* b_prune = (const float*)d_in[10];
  const float* W_g1    = (const float*)d_in[11];
  const float* b_g1    = (const float*)d_in[12];
  const float* W_g2    = (const float*)d_in[13];
  const float* b_g2    = (const float*)d_in[14];
  const float* W_proj  = (const float*)d_in[15];
  const float* b_proj  = (const float*)d_in[16];
  float* out = (float*)d_out;

  float* ws   = (float*)d_ws;
  float* qkv4 = ws;                      // 4096 x 4096 (q|k|v|id)
  float* gp   = qkv4 + 16777216;         // 4096 x 96 (gate|prune logits)
  float* hbuf = gp + 393216;             // holds kb16 + gWb16 (bf16)
  float* g2l  = hbuf + 4194304;          // 4096 x 80
  float* gW   = g2l + 327680;            // bf16 staging / ctxb region
  float* gU   = gW + 4194304;            // u, overwritten with u_adj by scan
  float* gS   = gU + 4194304;
  float* dOut = gS + 4194304;            // (b,n,h,d)
  float* entA = dOut + 4194304;          // 1 float

  // delta bf16 operand buffers (hbuf region, exactly 4.19M fl = 8.39M u16 x2)
  u16* kb16   = (u16*)hbuf;                        // [bh*16+g][4096] khat bf16
  u16* gWb16  = kb16 + 4194304;                    // [bh*16+g][4096] W bf16

  // bf16 staging aliased into gW/gU (dead once delta_prep runs)
  u16* xb     = (u16*)gW;                          // 4096x1024 bf16
  u16* wqT    = (u16*)(gW + 2097152);              // 4096x1024 bf16 (qkv|id ^T)
  u16* wg1T   = (u16*)gU;                          // 1024x1024 bf16
  u16* hb16   = (u16*)(gU + 524288);               // 4096x1024 bf16 (gelu out)
  u16* catGP  = (u16*)(gU + 2621440);              // 128x1024 bf16
  u16* catG2  = (u16*)(gU + 2686976);              // 128x1024 bf16
  float* cb1  = gS;                                // 128 fl (dead before scan)
  float* cb2  = gS + 128;                          // 128 fl
  u16* ctxb   = (u16*)gW;                          // post-delta: 4096x1024 bf16
  u16* wprojT = (u16*)(gW + 2097152);              // post-delta: 1024x1024 bf16

  // casts + weight transposes
  conv_bf16<<<2048, 256, 0, stream>>>(x, xb, 524288);
  conv_wt<<<dim3(96, 32), 256, 0, stream>>>(W_qkv, wqT, 1024, 3072, 0);
  conv_wt<<<dim3(32, 32), 256, 0, stream>>>(W_id,  wqT, 1024, 1024, 3072);
  conv_wt<<<dim3(32, 32), 256, 0, stream>>>(W_g1,  wg1T, 1024, 1024, 0);
  conv_wt<<<dim3(1, 32),  256, 0, stream>>>(W_gate,  catGP, 1024, 16, 0);
  conv_wt<<<dim3(3, 32),  256, 0, stream>>>(W_prune, catGP, 1024, 80, 16);
  conv_wt<<<dim3(3, 32),  256, 0, stream>>>(W_g2,    catG2, 1024, 80, 0);
  hipMemsetAsync(catGP + 96 * 1024, 0, 32 * 1024 * sizeof(u16), stream);
  hipMemsetAsync(catG2 + 80 * 1024, 0, 48 * 1024 * sizeof(u16), stream);
  bias_cat<<<1, 256, 0, stream>>>(b_gate, b_prune, b_g2, cb1, cb2);

  // fused qkv+id projection, g1, skinny gates (bf16 MFMA)
  gemm_mfma<0,0><<<dim3(32, 32), 256, 0, stream>>>(xb, wqT, nullptr, qkv4, BN_, 4096, 1024, 4096);
  gemm_mfma<1,1><<<dim3(8, 32), 256, 0, stream>>>(xb, wg1T, b_g1, (float*)hb16, BN_, 1024, 1024, 1024);
  gemm_mfma<0,0><<<dim3(1, 32), 256, 0, stream>>>(xb, catGP, cb1, gp, BN_, 128, 1024, 96);
  gemm_mfma<0,0><<<dim3(1, 32), 256, 0, stream>>>(hb16, catG2, cb2, g2l, BN_, 128, 1024, 80);

  // delta rule
  delta_prep<<<1024, 256, 0, stream>>>(qkv4, gU, kb16, gWb16);
  delta_scan<<<512, 256, 0, stream>>>(kb16, gWb16, gU, gS);
  delta_outk<<<1024, 256, 0, stream>>>(qkv4, gU, gS, dOut);

  // fused paths + gating (writes bf16 ctx directly into gW region)
  zero_ent<<<1, 1, 0, stream>>>(entA);
  paths_k<<<BN_, 256, 0, stream>>>(qkv4, dOut, gp, g2l,
                                   fir_s, fir_l, mix, idlog, ctxb, entA);

  // output projection (bf16 MFMA) + entropy scalar
  conv_wt<<<dim3(32, 32), 256, 0, stream>>>(W_proj, wprojT, 1024, 1024, 0);
  gemm_mfma<0,0><<<dim3(8, 32), 256, 0, stream>>>(ctxb, wprojT, b_proj, out, BN_, 1024, 1024, 1024);
  ent_fin<<<1, 1, 0, stream>>>(entA, out + 4194304);
}

// Round 7
// 358.828 us; speedup vs baseline: 3.8049x; 1.1992x over previous
//
#include <hip/hip_runtime.h>
#include <math.h>

#define B_ 4
#define N_ 1024
#define C_ 1024
#define H_ 16
#define D_ 64
#define P_ 5
#define BN_ (B_*N_)

typedef unsigned int u32;
typedef unsigned short u16;
typedef __attribute__((ext_vector_type(8))) short bf16x8;
typedef __attribute__((ext_vector_type(4))) float f32x4;

__device__ __forceinline__ float gelu_f(float x){
  float x3 = x*x*x;
  return 0.5f*x*(1.0f + tanhf(0.7978845608028654f*(x + 0.044715f*x3)));
}
__device__ __forceinline__ float sigmoid_f(float x){ return 1.0f/(1.0f+expf(-x)); }

__device__ __forceinline__ u16 f2bf(float f) {
  u32 u = __float_as_uint(f);
  u32 r = u + 0x7fffu + ((u >> 16) & 1u);
  return (u16)(r >> 16);
}

__device__ __forceinline__ void gload16(const void* g, void* l) {
  __builtin_amdgcn_global_load_lds((const __attribute__((address_space(1))) u32*)g,
                                   (__attribute__((address_space(3))) u32*)l, 16, 0, 0);
}

// ---------------- fp32 -> bf16 elementwise cast (8 elems/thread) --------------
__global__ __launch_bounds__(256) void conv_bf16(const float* __restrict__ in,
    u16* __restrict__ out, int n8) {
  int i = blockIdx.x * 256 + threadIdx.x;
  if (i >= n8) return;
  const float4* p = (const float4*)in + (size_t)i * 2;
  float4 a = p[0], b = p[1];
  uint4 o;
  o.x = (u32)f2bf(a.x) | ((u32)f2bf(a.y) << 16);
  o.y = (u32)f2bf(a.z) | ((u32)f2bf(a.w) << 16);
  o.z = (u32)f2bf(b.x) | ((u32)f2bf(b.y) << 16);
  o.w = (u32)f2bf(b.z) | ((u32)f2bf(b.w) << 16);
  *(uint4*)(out + (size_t)i * 8) = o;
}

// ------- fp32 [K][Nn] -> bf16 [Nn][K] transpose cast, guarded, with row offset
__global__ __launch_bounds__(256) void conv_wt(const float* __restrict__ W,
    u16* __restrict__ Wt, int K, int Nn, int roff) {
  __shared__ float t[32][33];
  int c0 = blockIdx.x * 32, r0 = blockIdx.y * 32;
  int tx = threadIdx.x & 31, ty = threadIdx.x >> 5;
  #pragma unroll
  for (int i = 0; i < 4; ++i) {
    int r = ty + i * 8;
    t[r][tx] = (c0 + tx < Nn) ? W[(size_t)(r0 + r) * Nn + c0 + tx] : 0.f;
  }
  __syncthreads();
  #pragma unroll
  for (int i = 0; i < 4; ++i) {
    int r = ty + i * 8;
    if (c0 + r < Nn)
      Wt[(size_t)(roff + c0 + r) * K + r0 + tx] = f2bf(t[tx][r]);
  }
}

// --------- bias concat: cb1 = [b_gate(16) | b_prune(80) | 0], cb2 = [b_g2(80)|0]
__global__ void bias_cat(const float* __restrict__ bg, const float* __restrict__ bp,
    const float* __restrict__ bg2, float* __restrict__ cb1, float* __restrict__ cb2) {
  int t = threadIdx.x;
  if (t < 128) cb1[t] = (t < 16) ? bg[t] : (t < 96 ? bp[t - 16] : 0.f);
  else { int c = t - 128; cb2[c] = (c < 80) ? bg2[c] : 0.f; }
}

// ---------------- bf16 MFMA GEMM: C = A(M,K) @ Bt(Nn,K)^T (+bias, +gelu) ------
template<int ACT, int OBF>
__global__ __launch_bounds__(256) void gemm_mfma(const u16* __restrict__ A,
    const u16* __restrict__ Bt, const float* __restrict__ bias,
    float* __restrict__ Cout, int M, int Nn, int K, int Ns) {
  __shared__ __align__(16) u16 lA[128 * 32];
  __shared__ __align__(16) u16 lB[128 * 32];
  const int tid = threadIdx.x;
  const int lane = tid & 63, wid = tid >> 6;
  const int wr = wid >> 1, wc = wid & 1;
  const int r16 = lane & 15, kq = lane >> 4;
  const int row0 = blockIdx.y * 128, col0 = blockIdx.x * 128;
  const int c0 = wid * 2;
  const int srow = lane >> 2;
  const int skoff = (lane & 3) * 8;

  f32x4 acc[4][4] = {};
  for (int k0 = 0; k0 < K; k0 += 32) {
    #pragma unroll
    for (int s = 0; s < 2; ++s) {
      int c = c0 + s;
      int rt = c * 16 + srow;
      gload16(A  + (size_t)(row0 + rt) * K + k0 + skoff, &lA[c * 512]);
      gload16(Bt + (size_t)(col0 + rt) * K + k0 + skoff, &lB[c * 512]);
    }
    __syncthreads();
    bf16x8 af[4], bfv[4];
    #pragma unroll
    for (int m = 0; m < 4; ++m)
      af[m] = *(const bf16x8*)&lA[(wr * 64 + m * 16 + r16) * 32 + kq * 8];
    #pragma unroll
    for (int n = 0; n < 4; ++n)
      bfv[n] = *(const bf16x8*)&lB[(wc * 64 + n * 16 + r16) * 32 + kq * 8];
    #pragma unroll
    for (int m = 0; m < 4; ++m)
      #pragma unroll
      for (int n = 0; n < 4; ++n)
        acc[m][n] = __builtin_amdgcn_mfma_f32_16x16x32_bf16(af[m], bfv[n], acc[m][n], 0, 0, 0);
    __syncthreads();
  }
  #pragma unroll
  for (int n = 0; n < 4; ++n) {
    int col = col0 + wc * 64 + n * 16 + r16;
    if (col >= Ns) continue;
    float bs = bias ? bias[col] : 0.0f;
    #pragma unroll
    for (int m = 0; m < 4; ++m) {
      int rowb = row0 + wr * 64 + m * 16 + kq * 4;
      #pragma unroll
      for (int r = 0; r < 4; ++r) {
        float v = acc[m][n][r] + bs;
        if (ACT == 1) v = gelu_f(v);
        if (OBF) ((u16*)Cout)[(size_t)(rowb + r) * Ns + col] = f2bf(v);
        else     Cout[(size_t)(rowb + r) * Ns + col] = v;
      }
    }
  }
}

// ---------------- DeltaNet: per-chunk prep (normalize, M, register solves) ----
// qkv row stride 4096 (q|k|v|id). Emits: qb/kb/wb bf16 (chunk-major [bx][r][e]),
// u fp32 -> gU. No fp32 q/k writeback.
__global__ __launch_bounds__(256) void delta_prep(const float* __restrict__ qkv,
    float* __restrict__ gU, u16* __restrict__ kb, u16* __restrict__ wb,
    u16* __restrict__ qb) {
  const int bx = blockIdx.x;
  const int bh = bx >> 4, g = bx & 15;
  const int b = bh >> 4, h = bh & 15;
  const int n0 = g * 64;
  const int tid = threadIdx.x;
  __shared__ float sK[64][65];
  __shared__ float sV[64][65];
  __shared__ __align__(16) float sMT[64][68];  // M^T, upper (per-row) zeroed
  __shared__ float sPart[64][8];
  __shared__ float sBeta[64];

  const size_t rowbase = (size_t)b * N_ + n0;
  for (int i = 0; i < 16; ++i) {
    int idx = tid + i * 256; int r = idx >> 6, d = idx & 63;
    size_t off = (rowbase + r) * 4096 + h * 64 + d;
    sK[r][d] = qkv[off + 1024];
    sV[r][d] = qkv[off + 2048];
  }
  if (tid < 64) sBeta[tid] = 1.0f - 0.9f * (float)(n0 + tid) / 1023.0f;
  __syncthreads();

  // parallel norms: thread = (row rr_, quarter qd)
  const int rr_ = tid >> 2, qd = tid & 3;
  float ps = 0.f;
  #pragma unroll
  for (int j = 0; j < 16; ++j) { float v = sK[rr_][qd*16+j]; ps = fmaf(v, v, ps); }
  sPart[rr_][qd] = ps;
  const size_t qbase = (rowbase + rr_) * 4096 + h * 64 + qd * 16;
  float4 qv[4]; float qs = 0.f;
  #pragma unroll
  for (int j = 0; j < 4; ++j) {
    qv[j] = *(const float4*)(qkv + qbase + 4*j);
    qs += qv[j].x*qv[j].x + qv[j].y*qv[j].y + qv[j].z*qv[j].z + qv[j].w*qv[j].w;
  }
  sPart[rr_][4+qd] = qs;
  __syncthreads();
  const float ksc = rsqrtf(sPart[rr_][0]+sPart[rr_][1]+sPart[rr_][2]+sPart[rr_][3] + 1e-6f);
  const float qsc = rsqrtf(sPart[rr_][4]+sPart[rr_][5]+sPart[rr_][6]+sPart[rr_][7] + 1e-6f) * 0.125f;
  const size_t cbase = (size_t)bx * 4096 + rr_ * 64 + qd * 16;
  #pragma unroll
  for (int j = 0; j < 16; ++j) {
    float v = sK[rr_][qd*16+j] * ksc;
    sK[rr_][qd*16+j] = v;
    kb[cbase + j] = f2bf(v);             // khat bf16
  }
  #pragma unroll
  for (int j = 0; j < 4; ++j) {
    float4 t = qv[j];
    u32 lo = (u32)f2bf(t.x * qsc) | ((u32)f2bf(t.y * qsc) << 16);
    u32 hi = (u32)f2bf(t.z * qsc) | ((u32)f2bf(t.w * qsc) << 16);
    *(u32*)(qb + cbase + j*4)     = lo;  // qhat bf16
    *(u32*)(qb + cbase + j*4 + 2) = hi;
  }
  __syncthreads();

  // M^T[c][r] = (r>c) ? beta_r * khat_r . khat_c : 0   (microtile GEMM)
  {
    const int tx = tid & 15, ty = tid >> 4;
    const int r0 = ty * 4, cc0 = tx * 4;
    float acc[4][4] = {};
    #pragma unroll 4
    for (int d = 0; d < 64; ++d) {
      float a0[4], b0[4];
      #pragma unroll
      for (int i = 0; i < 4; ++i) a0[i] = sK[r0+i][d];
      #pragma unroll
      for (int j = 0; j < 4; ++j) b0[j] = sK[cc0+j][d];
      #pragma unroll
      for (int i = 0; i < 4; ++i)
        #pragma unroll
        for (int j = 0; j < 4; ++j) acc[i][j] = fmaf(a0[i], b0[j], acc[i][j]);
    }
    #pragma unroll
    for (int i = 0; i < 4; ++i)
      #pragma unroll
      for (int j = 0; j < 4; ++j) {
        int r = r0 + i, c = cc0 + j;
        sMT[c][r] = (r > c) ? sBeta[r] * acc[i][j] : 0.f;
      }
  }
  __syncthreads();

  // register-resident forward substitution; lanes 0-63: kb RHS, 64-127: v*beta RHS
  if (tid < 128) {
    const int c = tid & 63;
    float a[64];
    if (tid < 64) {
      #pragma unroll
      for (int i = 0; i < 64; ++i) a[i] = sBeta[i] * sK[i][c];
    } else {
      #pragma unroll
      for (int i = 0; i < 64; ++i) a[i] = sBeta[i] * sV[i][c];
    }
    #pragma unroll
    for (int i = 0; i < 64; ++i) {
      const float wi = a[i];
      #pragma unroll
      for (int j4 = 0; j4 < 16; ++j4) {
        const float4 m = *(const float4*)&sMT[i][j4 * 4];  // broadcast read
        a[j4*4+0] = fmaf(-m.x, wi, a[j4*4+0]);
        a[j4*4+1] = fmaf(-m.y, wi, a[j4*4+1]);
        a[j4*4+2] = fmaf(-m.z, wi, a[j4*4+2]);
        a[j4*4+3] = fmaf(-m.w, wi, a[j4*4+3]);
      }
    }
    const size_t obase = (size_t)bx * 4096;
    if (tid < 64) {   // W -> bf16
      #pragma unroll
      for (int i = 0; i < 64; ++i) wb[obase + i * 64 + c] = f2bf(a[i]);
    } else {          // u -> fp32
      #pragma unroll
      for (int i = 0; i < 64; ++i) gU[obase + i * 64 + c] = a[i];
    }
  }
}

// -------- DeltaNet fused scan+output: one block per (b,h), S in MFMA accs -----
// Per chunk: attn=tril(q k^T); WS=W@S; u_adj=U-WS; o=q@S+attn@u_adj;
// S += K^T@u_adj.  All matmuls MFMA 16x16x32 bf16 (fp32 acc).
__global__ __launch_bounds__(256, 1) void delta_fused(const u16* __restrict__ kb,
    const u16* __restrict__ wb, const u16* __restrict__ qb,
    const float* __restrict__ gU, float* __restrict__ dOut) {
  const int bh = blockIdx.x;
  const int b = bh >> 4, h = bh & 15;
  const int tid = threadIdx.x;
  const int lane = tid & 63, wv = tid >> 6;      // wave id 0..3 (owns rows 16wv..)
  const int l15 = lane & 15, l4 = lane >> 4;
  const int fr = tid >> 2, fe0 = (tid & 3) * 16; // fill mapping (16 elems/thread)

  __shared__ __align__(16) u16 sK [64][72];   // k_hat   [c][e]
  __shared__ __align__(16) u16 sKT[64][72];   // k_hat^T [e][c]
  __shared__ __align__(16) u16 sW [64][72];   // W       [c][e]
  __shared__ __align__(16) u16 sQ [64][72];   // q_hat   [r][e]
  __shared__ __align__(16) u16 sSt[64][72];   // S^T     [d][e]
  __shared__ __align__(16) u16 sUt[64][72];   // u_adj^T [d][c]
  __shared__ __align__(16) u16 sA [64][72];   // attn    [r][c]
  __shared__ __align__(16) float sU[64][68];  // u       [c][d] fp32

  f32x4 Sacc[4] = {};   // S[e=16wv+l4*4+j][d=dt*16+l15]

  // prologue: prefetch chunk 0
  uint4 pk0, pk1, pw0, pw1, pq0, pq1, pu0, pu1, pu2, pu3;
  {
    const size_t bs = (size_t)(bh * 16) * 4096;
    pk0 = *(const uint4*)(kb + bs + tid*16); pk1 = *(const uint4*)(kb + bs + tid*16 + 8);
    pw0 = *(const uint4*)(wb + bs + tid*16); pw1 = *(const uint4*)(wb + bs + tid*16 + 8);
    pq0 = *(const uint4*)(qb + bs + tid*16); pq1 = *(const uint4*)(qb + bs + tid*16 + 8);
    pu0 = *(const uint4*)(gU + bs + tid*16);     pu1 = *(const uint4*)(gU + bs + tid*16 + 4);
    pu2 = *(const uint4*)(gU + bs + tid*16 + 8); pu3 = *(const uint4*)(gU + bs + tid*16 + 12);
  }

  for (int g = 0; g < 16; ++g) {
    __syncthreads();                           // BAR_A: prev phase B reads done
    // fills from prefetch regs
    *(uint4*)&sK[fr][fe0] = pk0; *(uint4*)&sK[fr][fe0+8] = pk1;
    *(uint4*)&sW[fr][fe0] = pw0; *(uint4*)&sW[fr][fe0+8] = pw1;
    *(uint4*)&sQ[fr][fe0] = pq0; *(uint4*)&sQ[fr][fe0+8] = pq1;
    {
      u32 kk[8] = {pk0.x, pk0.y, pk0.z, pk0.w, pk1.x, pk1.y, pk1.z, pk1.w};
      #pragma unroll
      for (int i = 0; i < 8; ++i) {
        sKT[fe0 + 2*i][fr]     = (u16)kk[i];
        sKT[fe0 + 2*i + 1][fr] = (u16)(kk[i] >> 16);
      }
    }
    *(uint4*)&sU[fr][fe0]    = pu0; *(uint4*)&sU[fr][fe0+4]  = pu1;
    *(uint4*)&sU[fr][fe0+8]  = pu2; *(uint4*)&sU[fr][fe0+12] = pu3;
    // S^T (chunk-start S) from accumulators, bf16
    #pragma unroll
    for (int dt = 0; dt < 4; ++dt) {
      u32 lo = (u32)f2bf(Sacc[dt][0]) | ((u32)f2bf(Sacc[dt][1]) << 16);
      u32 hi = (u32)f2bf(Sacc[dt][2]) | ((u32)f2bf(Sacc[dt][3]) << 16);
      *(u32*)&sSt[dt*16 + l15][16*wv + l4*4]     = lo;
      *(u32*)&sSt[dt*16 + l15][16*wv + l4*4 + 2] = hi;
    }
    __syncthreads();                           // BAR_B: LDS ready
    if (g < 15) {                              // prefetch next chunk
      const size_t bs = (size_t)(bh * 16 + g + 1) * 4096;
      pk0 = *(const uint4*)(kb + bs + tid*16); pk1 = *(const uint4*)(kb + bs + tid*16 + 8);
      pw0 = *(const uint4*)(wb + bs + tid*16); pw1 = *(const uint4*)(wb + bs + tid*16 + 8);
      pq0 = *(const uint4*)(qb + bs + tid*16); pq1 = *(const uint4*)(qb + bs + tid*16 + 8);
      pu0 = *(const uint4*)(gU + bs + tid*16);     pu1 = *(const uint4*)(gU + bs + tid*16 + 4);
      pu2 = *(const uint4*)(gU + bs + tid*16 + 8); pu3 = *(const uint4*)(gU + bs + tid*16 + 12);
    }
    // ---- phase A: attn = q k^T ; WS = W @ S ; o = q @ S ----
    bf16x8 qf0 = *(const bf16x8*)&sQ[16*wv + l15][l4*8];
    bf16x8 qf1 = *(const bf16x8*)&sQ[16*wv + l15][32 + l4*8];
    bf16x8 wf0 = *(const bf16x8*)&sW[16*wv + l15][l4*8];
    bf16x8 wf1 = *(const bf16x8*)&sW[16*wv + l15][32 + l4*8];
    f32x4 aacc[4] = {}, wsacc[4] = {}, oacc[4] = {};
    #pragma unroll
    for (int ct = 0; ct < 4; ++ct) {
      bf16x8 k0 = *(const bf16x8*)&sK[ct*16 + l15][l4*8];
      bf16x8 k1 = *(const bf16x8*)&sK[ct*16 + l15][32 + l4*8];
      aacc[ct] = __builtin_amdgcn_mfma_f32_16x16x32_bf16(qf0, k0, aacc[ct], 0, 0, 0);
      aacc[ct] = __builtin_amdgcn_mfma_f32_16x16x32_bf16(qf1, k1, aacc[ct], 0, 0, 0);
    }
    #pragma unroll
    for (int dt = 0; dt < 4; ++dt) {
      bf16x8 s0 = *(const bf16x8*)&sSt[dt*16 + l15][l4*8];
      bf16x8 s1 = *(const bf16x8*)&sSt[dt*16 + l15][32 + l4*8];
      wsacc[dt] = __builtin_amdgcn_mfma_f32_16x16x32_bf16(wf0, s0, wsacc[dt], 0, 0, 0);
      wsacc[dt] = __builtin_amdgcn_mfma_f32_16x16x32_bf16(wf1, s1, wsacc[dt], 0, 0, 0);
      oacc[dt]  = __builtin_amdgcn_mfma_f32_16x16x32_bf16(qf0, s0, oacc[dt], 0, 0, 0);
      oacc[dt]  = __builtin_amdgcn_mfma_f32_16x16x32_bf16(qf1, s1, oacc[dt], 0, 0, 0);
    }
    // u_adj = U - WS -> sUt (bf16, transposed); attn -> sA (tril, bf16)
    #pragma unroll
    for (int dt = 0; dt < 4; ++dt) {
      float u0 = sU[16*wv + l4*4 + 0][dt*16 + l15] - wsacc[dt][0];
      float u1 = sU[16*wv + l4*4 + 1][dt*16 + l15] - wsacc[dt][1];
      float u2 = sU[16*wv + l4*4 + 2][dt*16 + l15] - wsacc[dt][2];
      float u3 = sU[16*wv + l4*4 + 3][dt*16 + l15] - wsacc[dt][3];
      u32 lo = (u32)f2bf(u0) | ((u32)f2bf(u1) << 16);
      u32 hi = (u32)f2bf(u2) | ((u32)f2bf(u3) << 16);
      *(u32*)&sUt[dt*16 + l15][16*wv + l4*4]     = lo;
      *(u32*)&sUt[dt*16 + l15][16*wv + l4*4 + 2] = hi;
    }
    #pragma unroll
    for (int ct = 0; ct < 4; ++ct)
      #pragma unroll
      for (int j = 0; j < 4; ++j) {
        int r = 16*wv + l4*4 + j, c = ct*16 + l15;
        sA[r][c] = f2bf((r >= c) ? aacc[ct][j] : 0.f);
      }
    __syncthreads();                           // BAR_C: sA/sUt visible
    // ---- phase B: o += attn @ u_adj ; S += K^T @ u_adj ----
    bf16x8 af0 = *(const bf16x8*)&sA[16*wv + l15][l4*8];
    bf16x8 af1 = *(const bf16x8*)&sA[16*wv + l15][32 + l4*8];
    bf16x8 kt0 = *(const bf16x8*)&sKT[16*wv + l15][l4*8];
    bf16x8 kt1 = *(const bf16x8*)&sKT[16*wv + l15][32 + l4*8];
    #pragma unroll
    for (int dt = 0; dt < 4; ++dt) {
      bf16x8 u0 = *(const bf16x8*)&sUt[dt*16 + l15][l4*8];
      bf16x8 u1 = *(const bf16x8*)&sUt[dt*16 + l15][32 + l4*8];
      oacc[dt] = __builtin_amdgcn_mfma_f32_16x16x32_bf16(af0, u0, oacc[dt], 0, 0, 0);
      oacc[dt] = __builtin_amdgcn_mfma_f32_16x16x32_bf16(af1, u1, oacc[dt], 0, 0, 0);
      Sacc[dt] = __builtin_amdgcn_mfma_f32_16x16x32_bf16(kt0, u0, Sacc[dt], 0, 0, 0);
      Sacc[dt] = __builtin_amdgcn_mfma_f32_16x16x32_bf16(kt1, u1, Sacc[dt], 0, 0, 0);
    }
    // store o -> dOut (b,n,h,d)
    #pragma unroll
    for (int dt = 0; dt < 4; ++dt)
      #pragma unroll
      for (int j = 0; j < 4; ++j) {
        int r = 16*wv + l4*4 + j;
        dOut[((size_t)(b * 1024 + g * 64 + r)) * 1024 + h * 64 + dt*16 + l15] = oacc[dt][j];
      }
  }
}

// ---------------- fused FIR + cross-mix + gating + ctx (bf16 out) -------------
__global__ __launch_bounds__(256) void paths_k(const float* __restrict__ qkv,
    const float* __restrict__ dOut, const float* __restrict__ gp,
    const float* __restrict__ g2L, const float* __restrict__ fir_s,
    const float* __restrict__ fir_l, const float* __restrict__ mix,
    const float* __restrict__ idlog, u16* __restrict__ ctxb,
    float* __restrict__ entAcc) {
  const int bn = blockIdx.x; const int b = bn >> 10, n = bn & 1023;
  const int tid = threadIdx.x;
  __shared__ float fS[16][64], fL[16][64];
  __shared__ float sMix[256];
  __shared__ float sWg[16][5], sIdg[16], sEnt[16];
  sMix[tid] = mix[tid];

  #pragma unroll
  for (int i = 0; i < 4; ++i) {
    int idx = tid + i * 256; int hh = idx >> 6, d = idx & 63;
    float accs = 0.f, accl = 0.f;
    #pragma unroll
    for (int j = 0; j < 7; ++j) {
      int t = n - 6 + j;
      float vv = (t >= 0) ? qkv[((size_t)b * 1024 + t) * 4096 + 2048 + idx] : 0.f;
      accl = fmaf(fir_l[(size_t)idx * 7 + j], vv, accl);
      if (j >= 4) accs = fmaf(fir_s[(size_t)idx * 3 + (j - 4)], vv, accs);
    }
    fS[hh][d] = accs; fL[hh][d] = accl;
  }
  __syncthreads();

  float fsm[4], flm[4];
  #pragma unroll
  for (int i = 0; i < 4; ++i) {
    int idx = tid + i * 256; int gg = idx >> 6, d = idx & 63;
    float as = fS[gg][d], al = fL[gg][d];
    #pragma unroll
    for (int hh = 0; hh < 16; ++hh) {
      float m = sMix[hh * 16 + gg];
      as = fmaf(fS[hh][d], m, as);
      al = fmaf(fL[hh][d], m, al);
    }
    fsm[i] = as; flm[i] = al;
  }

  if (tid < 16) {
    float pl[5], lp[5];
    #pragma unroll
    for (int p = 0; p < 5; ++p) pl[p] = gp[(size_t)bn * 96 + 16 + tid * 5 + p];
    float mx = pl[0];
    #pragma unroll
    for (int p = 1; p < 5; ++p) mx = fmaxf(mx, pl[p]);
    float s = 0.f;
    #pragma unroll
    for (int p = 0; p < 5; ++p) { pl[p] = expf(pl[p] - mx); s += pl[p]; }
    float inv = 1.f / s, e1 = 0.f;
    #pragma unroll
    for (int p = 0; p < 5; ++p) {
      float prob = pl[p] * inv;
      lp[p] = logf(prob + 1e-8f);
      e1 -= prob * lp[p];
    }
    float gl[5];
    #pragma unroll
    for (int p = 0; p < 5; ++p) gl[p] = g2L[(size_t)bn * 80 + tid * 5 + p] + lp[p];
    float mx2 = gl[0];
    #pragma unroll
    for (int p = 1; p < 5; ++p) mx2 = fmaxf(mx2, gl[p]);
    float s2 = 0.f;
    #pragma unroll
    for (int p = 0; p < 5; ++p) { gl[p] = expf(gl[p] - mx2); s2 += gl[p]; }
    float inv2 = 1.f / s2, e2 = 0.f;
    #pragma unroll
    for (int p = 0; p < 5; ++p) {
      float w = gl[p] * inv2;
      sWg[tid][p] = w;
      e2 -= w * logf(w + 1e-8f);
    }
    sEnt[tid] = e1 + e2;
    sIdg[tid] = sigmoid_f(gp[(size_t)bn * 96 + tid]) * sigmoid_f(idlog[tid]);
  }
  __syncthreads();

  #pragma unroll
  for (int i = 0; i < 4; ++i) {
    int idx = tid + i * 256; int hh = idx >> 6;
    float w0 = sWg[hh][0], w1 = sWg[hh][1], w2 = sWg[hh][2], w3 = sWg[hh][3], w4 = sWg[hh][4];
    float dv = dOut[(size_t)bn * 1024 + idx];
    float vv = qkv[(size_t)bn * 4096 + 2048 + idx];
    float iv = qkv[(size_t)bn * 4096 + 3072 + idx] * sIdg[hh];
    ctxb[(size_t)bn * 1024 + idx] = f2bf(w0*fsm[i] + w1*flm[i] + w2*dv + w3*vv + w4*iv);
  }
  if (tid == 0) {
    float s = 0.f;
    #pragma unroll
    for (int hh = 0; hh < 16; ++hh) s += sEnt[hh];
    atomicAdd(entAcc, s);
  }
}

__global__ void zero_ent(float* e) { e[0] = 0.f; }
__global__ void ent_fin(const float* __restrict__ e, float* __restrict__ dst) {
  dst[0] = e[0] * (1.0f / 65536.0f);
}

// ---------------- host launcher ----------------------------------------------
extern "C" void kernel_launch(void* const* d_in, const int* in_sizes, int n_in,
                              void* d_out, int out_size, void* d_ws, size_t ws_size,
                              hipStream_t stream) {
  (void)in_sizes; (void)n_in; (void)out_size; (void)ws_size;
  const float* x       = (const float*)d_in[0];
  const float* W_qkv   = (const float*)d_in[1];
  const float* W_id    = (const float*)d_in[2];
  const float* W_gate  = (const float*)d_in[3];
  const float* b_gate  = (const float*)d_in[4];
  const float* idlog   = (const float*)d_in[5];
  const float* fir_s   = (const float*)d_in[6];
  const float* fir_l   = (const float*)d_in[7];
  const float* mix     = (const float*)d_in[8];
  const float* W_prune = (const float*)d_in[9];
  const float* b_prune = (const float*)d_in[10];
  const float* W_g1    = (const float*)d_in[11];
  const float* b_g1    = (const float*)d_in[12];
  const float* W_g2    = (const float*)d_in[13];
  const float* b_g2    = (const float*)d_in[14];
  const float* W_proj  = (const float*)d_in[15];
  const float* b_proj  = (const float*)d_in[16];
  float* out = (float*)d_out;

  float* ws   = (float*)d_ws;
  float* qkv4 = ws;                      // 4096 x 4096 (q|k|v|id)
  float* gp   = qkv4 + 16777216;         // 4096 x 96
  float* g2l  = gp + 393216;             // 4096 x 80
  float* kqwB = g2l + 327680;            // 6,291,456 fl = 3 bf16 arrays of 8MB
  float* gU   = kqwB + 6291456;          // 4,194,304 fl
  float* dOut = gU + 4194304;            // 4,194,304 fl
  float* entA = dOut + 4194304;          // 1 fl

  // delta bf16 operand buffers (chunk-major [bx][r][e], bx = bh*16+g)
  u16* kb16 = (u16*)kqwB;                // 4,194,304 u16
  u16* wb16 = kb16 + 4194304;
  u16* qb16 = wb16 + 4194304;

  // pre-delta bf16 staging (aliased; dead before delta_prep writes kb/wb/qb/gU)
  u16* xb     = (u16*)kqwB;                        // = kb region (4.19M u16)
  u16* wqT    = wb16;                              // 4096x1024 bf16
  u16* wg1T   = qb16;                              // 1024x1024 bf16
  u16* hb16   = (u16*)gU;                          // 4096x1024 bf16 (gelu out)
  u16* catGP  = (u16*)(gU + 2097152);              // 128x1024 bf16
  u16* catG2  = (u16*)(gU + 2162688);              // 128x1024 bf16
  float* cb1  = dOut;                              // 128 fl (dead before fused)
  float* cb2  = dOut + 128;
  // post-delta aliases
  u16* ctxb   = (u16*)kqwB;                        // kb region dead after fused
  u16* wprojT = wb16;                              // wb region dead after fused

  // casts + weight transposes
  conv_bf16<<<2048, 256, 0, stream>>>(x, xb, 524288);
  conv_wt<<<dim3(96, 32), 256, 0, stream>>>(W_qkv, wqT, 1024, 3072, 0);
  conv_wt<<<dim3(32, 32), 256, 0, stream>>>(W_id,  wqT, 1024, 1024, 3072);
  conv_wt<<<dim3(32, 32), 256, 0, stream>>>(W_g1,  wg1T, 1024, 1024, 0);
  conv_wt<<<dim3(1, 32),  256, 0, stream>>>(W_gate,  catGP, 1024, 16, 0);
  conv_wt<<<dim3(3, 32),  256, 0, stream>>>(W_prune, catGP, 1024, 80, 16);
  conv_wt<<<dim3(3, 32),  256, 0, stream>>>(W_g2,    catG2, 1024, 80, 0);
  hipMemsetAsync(catGP + 96 * 1024, 0, 32 * 1024 * sizeof(u16), stream);
  hipMemsetAsync(catG2 + 80 * 1024, 0, 48 * 1024 * sizeof(u16), stream);
  bias_cat<<<1, 256, 0, stream>>>(b_gate, b_prune, b_g2, cb1, cb2);

  // fused qkv+id projection, g1, skinny gates (bf16 MFMA)
  gemm_mfma<0,0><<<dim3(32, 32), 256, 0, stream>>>(xb, wqT, nullptr, qkv4, BN_, 4096, 1024, 4096);
  gemm_mfma<1,1><<<dim3(8, 32), 256, 0, stream>>>(xb, wg1T, b_g1, (float*)hb16, BN_, 1024, 1024, 1024);
  gemm_mfma<0,0><<<dim3(1, 32), 256, 0, stream>>>(xb, catGP, cb1, gp, BN_, 128, 1024, 96);
  gemm_mfma<0,0><<<dim3(1, 32), 256, 0, stream>>>(hb16, catG2, cb2, g2l, BN_, 128, 1024, 80);

  // delta rule: prep (parallel) then fused MFMA scan+output (64 blocks)
  delta_prep<<<1024, 256, 0, stream>>>(qkv4, gU, kb16, wb16, qb16);
  delta_fused<<<64, 256, 0, stream>>>(kb16, wb16, qb16, gU, dOut);

  // fused paths + gating (writes bf16 ctx into kb region)
  zero_ent<<<1, 1, 0, stream>>>(entA);
  paths_k<<<BN_, 256, 0, stream>>>(qkv4, dOut, gp, g2l,
                                   fir_s, fir_l, mix, idlog, ctxb, entA);

  // output projection (bf16 MFMA) + entropy scalar
  conv_wt<<<dim3(32, 32), 256, 0, stream>>>(W_proj, wprojT, 1024, 1024, 0);
  gemm_mfma<0,0><<<dim3(8, 32), 256, 0, stream>>>(ctxb, wprojT, b_proj, out, BN_, 1024, 1024, 1024);
  ent_fin<<<1, 1, 0, stream>>>(entA, out + 4194304);
}

// Round 8
// 336.615 us; speedup vs baseline: 4.0560x; 1.0660x over previous
//
#include <hip/hip_runtime.h>
#include <math.h>

#define B_ 4
#define N_ 1024
#define C_ 1024
#define H_ 16
#define D_ 64
#define P_ 5
#define BN_ (B_*N_)
#define TOK 8

typedef unsigned int u32;
typedef unsigned short u16;
typedef __attribute__((ext_vector_type(8))) short bf16x8;
typedef __attribute__((ext_vector_type(4))) float f32x4;

__device__ __forceinline__ float gelu_f(float x){
  float x3 = x*x*x;
  return 0.5f*x*(1.0f + tanhf(0.7978845608028654f*(x + 0.044715f*x3)));
}
__device__ __forceinline__ float sigmoid_f(float x){ return 1.0f/(1.0f+expf(-x)); }

__device__ __forceinline__ u16 f2bf(float f) {
  u32 u = __float_as_uint(f);
  u32 r = u + 0x7fffu + ((u >> 16) & 1u);
  return (u16)(r >> 16);
}
__device__ __forceinline__ float bf2f(u16 v){ return __uint_as_float(((u32)v) << 16); }

__device__ __forceinline__ void gload16(const void* g, void* l) {
  __builtin_amdgcn_global_load_lds((const __attribute__((address_space(1))) u32*)g,
                                   (__attribute__((address_space(3))) u32*)l, 16, 0, 0);
}

// ---------------- fp32 -> bf16 elementwise cast (8 elems/thread) --------------
__global__ __launch_bounds__(256) void conv_bf16(const float* __restrict__ in,
    u16* __restrict__ out, int n8) {
  int i = blockIdx.x * 256 + threadIdx.x;
  if (i >= n8) return;
  const float4* p = (const float4*)in + (size_t)i * 2;
  float4 a = p[0], b = p[1];
  uint4 o;
  o.x = (u32)f2bf(a.x) | ((u32)f2bf(a.y) << 16);
  o.y = (u32)f2bf(a.z) | ((u32)f2bf(a.w) << 16);
  o.z = (u32)f2bf(b.x) | ((u32)f2bf(b.y) << 16);
  o.w = (u32)f2bf(b.z) | ((u32)f2bf(b.w) << 16);
  *(uint4*)(out + (size_t)i * 8) = o;
}

// ------- fp32 [K][Nn] -> bf16 [Nn][K] transpose cast, guarded, with row offset
__global__ __launch_bounds__(256) void conv_wt(const float* __restrict__ W,
    u16* __restrict__ Wt, int K, int Nn, int roff) {
  __shared__ float t[32][33];
  int c0 = blockIdx.x * 32, r0 = blockIdx.y * 32;
  int tx = threadIdx.x & 31, ty = threadIdx.x >> 5;
  #pragma unroll
  for (int i = 0; i < 4; ++i) {
    int r = ty + i * 8;
    t[r][tx] = (c0 + tx < Nn) ? W[(size_t)(r0 + r) * Nn + c0 + tx] : 0.f;
  }
  __syncthreads();
  #pragma unroll
  for (int i = 0; i < 4; ++i) {
    int r = ty + i * 8;
    if (c0 + r < Nn)
      Wt[(size_t)(roff + c0 + r) * K + r0 + tx] = f2bf(t[tx][r]);
  }
}

// --------- bias concat: cb1 = [b_gate(16) | b_prune(80) | 0], cb2 = [b_g2(80)|0]
__global__ void bias_cat(const float* __restrict__ bg, const float* __restrict__ bp,
    const float* __restrict__ bg2, float* __restrict__ cb1, float* __restrict__ cb2) {
  int t = threadIdx.x;
  if (t < 128) cb1[t] = (t < 16) ? bg[t] : (t < 96 ? bp[t - 16] : 0.f);
  else { int c = t - 128; cb2[c] = (c < 80) ? bg2[c] : 0.f; }
}

// ---------------- bf16 MFMA GEMM: C = A(M,K) @ Bt(Nn,K)^T (+bias, +gelu) ------
template<int ACT, int OBF>
__global__ __launch_bounds__(256) void gemm_mfma(const u16* __restrict__ A,
    const u16* __restrict__ Bt, const float* __restrict__ bias,
    float* __restrict__ Cout, int M, int Nn, int K, int Ns) {
  __shared__ __align__(16) u16 lA[128 * 32];
  __shared__ __align__(16) u16 lB[128 * 32];
  const int tid = threadIdx.x;
  const int lane = tid & 63, wid = tid >> 6;
  const int wr = wid >> 1, wc = wid & 1;
  const int r16 = lane & 15, kq = lane >> 4;
  const int row0 = blockIdx.y * 128, col0 = blockIdx.x * 128;
  const int c0 = wid * 2;
  const int srow = lane >> 2;
  const int skoff = (lane & 3) * 8;

  f32x4 acc[4][4] = {};
  for (int k0 = 0; k0 < K; k0 += 32) {
    #pragma unroll
    for (int s = 0; s < 2; ++s) {
      int c = c0 + s;
      int rt = c * 16 + srow;
      gload16(A  + (size_t)(row0 + rt) * K + k0 + skoff, &lA[c * 512]);
      gload16(Bt + (size_t)(col0 + rt) * K + k0 + skoff, &lB[c * 512]);
    }
    __syncthreads();
    bf16x8 af[4], bfv[4];
    #pragma unroll
    for (int m = 0; m < 4; ++m)
      af[m] = *(const bf16x8*)&lA[(wr * 64 + m * 16 + r16) * 32 + kq * 8];
    #pragma unroll
    for (int n = 0; n < 4; ++n)
      bfv[n] = *(const bf16x8*)&lB[(wc * 64 + n * 16 + r16) * 32 + kq * 8];
    #pragma unroll
    for (int m = 0; m < 4; ++m)
      #pragma unroll
      for (int n = 0; n < 4; ++n)
        acc[m][n] = __builtin_amdgcn_mfma_f32_16x16x32_bf16(af[m], bfv[n], acc[m][n], 0, 0, 0);
    __syncthreads();
  }
  #pragma unroll
  for (int n = 0; n < 4; ++n) {
    int col = col0 + wc * 64 + n * 16 + r16;
    if (col >= Ns) continue;
    float bs = bias ? bias[col] : 0.0f;
    #pragma unroll
    for (int m = 0; m < 4; ++m) {
      int rowb = row0 + wr * 64 + m * 16 + kq * 4;
      #pragma unroll
      for (int r = 0; r < 4; ++r) {
        float v = acc[m][n][r] + bs;
        if (ACT == 1) v = gelu_f(v);
        if (OBF) ((u16*)Cout)[(size_t)(rowb + r) * Ns + col] = f2bf(v);
        else     Cout[(size_t)(rowb + r) * Ns + col] = v;
      }
    }
  }
}

// ---------------- DeltaNet: per-chunk prep (normalize, M, register solves) ----
// qkv row stride 3072 (q|k|v). Emits qb/kb/wb bf16 (chunk-major), u fp32 -> gU.
__global__ __launch_bounds__(256) void delta_prep(const float* __restrict__ qkv,
    float* __restrict__ gU, u16* __restrict__ kb, u16* __restrict__ wb,
    u16* __restrict__ qb) {
  const int bx = blockIdx.x;
  const int bh = bx >> 4, g = bx & 15;
  const int b = bh >> 4, h = bh & 15;
  const int n0 = g * 64;
  const int tid = threadIdx.x;
  __shared__ float sK[64][65];
  __shared__ float sV[64][65];
  __shared__ __align__(16) float sMT[64][68];
  __shared__ float sPart[64][8];
  __shared__ float sBeta[64];

  const size_t rowbase = (size_t)b * N_ + n0;
  for (int i = 0; i < 16; ++i) {
    int idx = tid + i * 256; int r = idx >> 6, d = idx & 63;
    size_t off = (rowbase + r) * 3072 + h * 64 + d;
    sK[r][d] = qkv[off + 1024];
    sV[r][d] = qkv[off + 2048];
  }
  if (tid < 64) sBeta[tid] = 1.0f - 0.9f * (float)(n0 + tid) / 1023.0f;
  __syncthreads();

  const int rr_ = tid >> 2, qd = tid & 3;
  float ps = 0.f;
  #pragma unroll
  for (int j = 0; j < 16; ++j) { float v = sK[rr_][qd*16+j]; ps = fmaf(v, v, ps); }
  sPart[rr_][qd] = ps;
  const size_t qbase = (rowbase + rr_) * 3072 + h * 64 + qd * 16;
  float4 qv[4]; float qs = 0.f;
  #pragma unroll
  for (int j = 0; j < 4; ++j) {
    qv[j] = *(const float4*)(qkv + qbase + 4*j);
    qs += qv[j].x*qv[j].x + qv[j].y*qv[j].y + qv[j].z*qv[j].z + qv[j].w*qv[j].w;
  }
  sPart[rr_][4+qd] = qs;
  __syncthreads();
  const float ksc = rsqrtf(sPart[rr_][0]+sPart[rr_][1]+sPart[rr_][2]+sPart[rr_][3] + 1e-6f);
  const float qsc = rsqrtf(sPart[rr_][4]+sPart[rr_][5]+sPart[rr_][6]+sPart[rr_][7] + 1e-6f) * 0.125f;
  const size_t cbase = (size_t)bx * 4096 + rr_ * 64 + qd * 16;
  #pragma unroll
  for (int j = 0; j < 16; ++j) {
    float v = sK[rr_][qd*16+j] * ksc;
    sK[rr_][qd*16+j] = v;
    kb[cbase + j] = f2bf(v);
  }
  #pragma unroll
  for (int j = 0; j < 4; ++j) {
    float4 t = qv[j];
    u32 lo = (u32)f2bf(t.x * qsc) | ((u32)f2bf(t.y * qsc) << 16);
    u32 hi = (u32)f2bf(t.z * qsc) | ((u32)f2bf(t.w * qsc) << 16);
    *(u32*)(qb + cbase + j*4)     = lo;
    *(u32*)(qb + cbase + j*4 + 2) = hi;
  }
  __syncthreads();

  {
    const int tx = tid & 15, ty = tid >> 4;
    const int r0 = ty * 4, cc0 = tx * 4;
    float acc[4][4] = {};
    #pragma unroll 4
    for (int d = 0; d < 64; ++d) {
      float a0[4], b0[4];
      #pragma unroll
      for (int i = 0; i < 4; ++i) a0[i] = sK[r0+i][d];
      #pragma unroll
      for (int j = 0; j < 4; ++j) b0[j] = sK[cc0+j][d];
      #pragma unroll
      for (int i = 0; i < 4; ++i)
        #pragma unroll
        for (int j = 0; j < 4; ++j) acc[i][j] = fmaf(a0[i], b0[j], acc[i][j]);
    }
    #pragma unroll
    for (int i = 0; i < 4; ++i)
      #pragma unroll
      for (int j = 0; j < 4; ++j) {
        int r = r0 + i, c = cc0 + j;
        sMT[c][r] = (r > c) ? sBeta[r] * acc[i][j] : 0.f;
      }
  }
  __syncthreads();

  if (tid < 128) {
    const int c = tid & 63;
    float a[64];
    if (tid < 64) {
      #pragma unroll
      for (int i = 0; i < 64; ++i) a[i] = sBeta[i] * sK[i][c];
    } else {
      #pragma unroll
      for (int i = 0; i < 64; ++i) a[i] = sBeta[i] * sV[i][c];
    }
    #pragma unroll
    for (int i = 0; i < 64; ++i) {
      const float wi = a[i];
      #pragma unroll
      for (int j4 = 0; j4 < 16; ++j4) {
        const float4 m = *(const float4*)&sMT[i][j4 * 4];
        a[j4*4+0] = fmaf(-m.x, wi, a[j4*4+0]);
        a[j4*4+1] = fmaf(-m.y, wi, a[j4*4+1]);
        a[j4*4+2] = fmaf(-m.z, wi, a[j4*4+2]);
        a[j4*4+3] = fmaf(-m.w, wi, a[j4*4+3]);
      }
    }
    const size_t obase = (size_t)bx * 4096;
    if (tid < 64) {
      #pragma unroll
      for (int i = 0; i < 64; ++i) wb[obase + i * 64 + c] = f2bf(a[i]);
    } else {
      #pragma unroll
      for (int i = 0; i < 64; ++i) gU[obase + i * 64 + c] = a[i];
    }
  }
}

// -------- DeltaNet fused scan+output: one block per (b,h), S in MFMA accs -----
__global__ __launch_bounds__(256, 1) void delta_fused(const u16* __restrict__ kb,
    const u16* __restrict__ wb, const u16* __restrict__ qb,
    const float* __restrict__ gU, u16* __restrict__ dOutb) {
  const int bh = blockIdx.x;
  const int b = bh >> 4, h = bh & 15;
  const int tid = threadIdx.x;
  const int lane = tid & 63, wv = tid >> 6;
  const int l15 = lane & 15, l4 = lane >> 4;
  const int fr = tid >> 2, fe0 = (tid & 3) * 16;

  __shared__ __align__(16) u16 sK [64][72];
  __shared__ __align__(16) u16 sKT[64][72];
  __shared__ __align__(16) u16 sW [64][72];
  __shared__ __align__(16) u16 sQ [64][72];
  __shared__ __align__(16) u16 sSt[64][72];
  __shared__ __align__(16) u16 sUt[64][72];
  __shared__ __align__(16) u16 sA [64][72];
  __shared__ __align__(16) float sU[64][68];

  f32x4 Sacc[4] = {};

  uint4 pk0, pk1, pw0, pw1, pq0, pq1, pu0, pu1, pu2, pu3;
  {
    const size_t bs = (size_t)(bh * 16) * 4096;
    pk0 = *(const uint4*)(kb + bs + tid*16); pk1 = *(const uint4*)(kb + bs + tid*16 + 8);
    pw0 = *(const uint4*)(wb + bs + tid*16); pw1 = *(const uint4*)(wb + bs + tid*16 + 8);
    pq0 = *(const uint4*)(qb + bs + tid*16); pq1 = *(const uint4*)(qb + bs + tid*16 + 8);
    pu0 = *(const uint4*)(gU + bs + tid*16);     pu1 = *(const uint4*)(gU + bs + tid*16 + 4);
    pu2 = *(const uint4*)(gU + bs + tid*16 + 8); pu3 = *(const uint4*)(gU + bs + tid*16 + 12);
  }

  for (int g = 0; g < 16; ++g) {
    __syncthreads();
    *(uint4*)&sK[fr][fe0] = pk0; *(uint4*)&sK[fr][fe0+8] = pk1;
    *(uint4*)&sW[fr][fe0] = pw0; *(uint4*)&sW[fr][fe0+8] = pw1;
    *(uint4*)&sQ[fr][fe0] = pq0; *(uint4*)&sQ[fr][fe0+8] = pq1;
    {
      u32 kk[8] = {pk0.x, pk0.y, pk0.z, pk0.w, pk1.x, pk1.y, pk1.z, pk1.w};
      #pragma unroll
      for (int i = 0; i < 8; ++i) {
        sKT[fe0 + 2*i][fr]     = (u16)kk[i];
        sKT[fe0 + 2*i + 1][fr] = (u16)(kk[i] >> 16);
      }
    }
    *(uint4*)&sU[fr][fe0]    = pu0; *(uint4*)&sU[fr][fe0+4]  = pu1;
    *(uint4*)&sU[fr][fe0+8]  = pu2; *(uint4*)&sU[fr][fe0+12] = pu3;
    #pragma unroll
    for (int dt = 0; dt < 4; ++dt) {
      u32 lo = (u32)f2bf(Sacc[dt][0]) | ((u32)f2bf(Sacc[dt][1]) << 16);
      u32 hi = (u32)f2bf(Sacc[dt][2]) | ((u32)f2bf(Sacc[dt][3]) << 16);
      *(u32*)&sSt[dt*16 + l15][16*wv + l4*4]     = lo;
      *(u32*)&sSt[dt*16 + l15][16*wv + l4*4 + 2] = hi;
    }
    __syncthreads();
    if (g < 15) {
      const size_t bs = (size_t)(bh * 16 + g + 1) * 4096;
      pk0 = *(const uint4*)(kb + bs + tid*16); pk1 = *(const uint4*)(kb + bs + tid*16 + 8);
      pw0 = *(const uint4*)(wb + bs + tid*16); pw1 = *(const uint4*)(wb + bs + tid*16 + 8);
      pq0 = *(const uint4*)(qb + bs + tid*16); pq1 = *(const uint4*)(qb + bs + tid*16 + 8);
      pu0 = *(const uint4*)(gU + bs + tid*16);     pu1 = *(const uint4*)(gU + bs + tid*16 + 4);
      pu2 = *(const uint4*)(gU + bs + tid*16 + 8); pu3 = *(const uint4*)(gU + bs + tid*16 + 12);
    }
    bf16x8 qf0 = *(const bf16x8*)&sQ[16*wv + l15][l4*8];
    bf16x8 qf1 = *(const bf16x8*)&sQ[16*wv + l15][32 + l4*8];
    bf16x8 wf0 = *(const bf16x8*)&sW[16*wv + l15][l4*8];
    bf16x8 wf1 = *(const bf16x8*)&sW[16*wv + l15][32 + l4*8];
    f32x4 aacc[4] = {}, wsacc[4] = {}, oacc[4] = {};
    #pragma unroll
    for (int ct = 0; ct < 4; ++ct) {
      bf16x8 k0 = *(const bf16x8*)&sK[ct*16 + l15][l4*8];
      bf16x8 k1 = *(const bf16x8*)&sK[ct*16 + l15][32 + l4*8];
      aacc[ct] = __builtin_amdgcn_mfma_f32_16x16x32_bf16(qf0, k0, aacc[ct], 0, 0, 0);
      aacc[ct] = __builtin_amdgcn_mfma_f32_16x16x32_bf16(qf1, k1, aacc[ct], 0, 0, 0);
    }
    #pragma unroll
    for (int dt = 0; dt < 4; ++dt) {
      bf16x8 s0 = *(const bf16x8*)&sSt[dt*16 + l15][l4*8];
      bf16x8 s1 = *(const bf16x8*)&sSt[dt*16 + l15][32 + l4*8];
      wsacc[dt] = __builtin_amdgcn_mfma_f32_16x16x32_bf16(wf0, s0, wsacc[dt], 0, 0, 0);
      wsacc[dt] = __builtin_amdgcn_mfma_f32_16x16x32_bf16(wf1, s1, wsacc[dt], 0, 0, 0);
      oacc[dt]  = __builtin_amdgcn_mfma_f32_16x16x32_bf16(qf0, s0, oacc[dt], 0, 0, 0);
      oacc[dt]  = __builtin_amdgcn_mfma_f32_16x16x32_bf16(qf1, s1, oacc[dt], 0, 0, 0);
    }
    #pragma unroll
    for (int dt = 0; dt < 4; ++dt) {
      float u0 = sU[16*wv + l4*4 + 0][dt*16 + l15] - wsacc[dt][0];
      float u1 = sU[16*wv + l4*4 + 1][dt*16 + l15] - wsacc[dt][1];
      float u2 = sU[16*wv + l4*4 + 2][dt*16 + l15] - wsacc[dt][2];
      float u3 = sU[16*wv + l4*4 + 3][dt*16 + l15] - wsacc[dt][3];
      u32 lo = (u32)f2bf(u0) | ((u32)f2bf(u1) << 16);
      u32 hi = (u32)f2bf(u2) | ((u32)f2bf(u3) << 16);
      *(u32*)&sUt[dt*16 + l15][16*wv + l4*4]     = lo;
      *(u32*)&sUt[dt*16 + l15][16*wv + l4*4 + 2] = hi;
    }
    #pragma unroll
    for (int ct = 0; ct < 4; ++ct)
      #pragma unroll
      for (int j = 0; j < 4; ++j) {
        int r = 16*wv + l4*4 + j, c = ct*16 + l15;
        sA[r][c] = f2bf((r >= c) ? aacc[ct][j] : 0.f);
      }
    __syncthreads();
    bf16x8 af0 = *(const bf16x8*)&sA[16*wv + l15][l4*8];
    bf16x8 af1 = *(const bf16x8*)&sA[16*wv + l15][32 + l4*8];
    bf16x8 kt0 = *(const bf16x8*)&sKT[16*wv + l15][l4*8];
    bf16x8 kt1 = *(const bf16x8*)&sKT[16*wv + l15][32 + l4*8];
    #pragma unroll
    for (int dt = 0; dt < 4; ++dt) {
      bf16x8 u0 = *(const bf16x8*)&sUt[dt*16 + l15][l4*8];
      bf16x8 u1 = *(const bf16x8*)&sUt[dt*16 + l15][32 + l4*8];
      oacc[dt] = __builtin_amdgcn_mfma_f32_16x16x32_bf16(af0, u0, oacc[dt], 0, 0, 0);
      oacc[dt] = __builtin_amdgcn_mfma_f32_16x16x32_bf16(af1, u1, oacc[dt], 0, 0, 0);
      Sacc[dt] = __builtin_amdgcn_mfma_f32_16x16x32_bf16(kt0, u0, Sacc[dt], 0, 0, 0);
      Sacc[dt] = __builtin_amdgcn_mfma_f32_16x16x32_bf16(kt1, u1, Sacc[dt], 0, 0, 0);
    }
    #pragma unroll
    for (int dt = 0; dt < 4; ++dt)
      #pragma unroll
      for (int j = 0; j < 4; ++j) {
        int r = 16*wv + l4*4 + j;
        dOutb[((size_t)(b * 1024 + g * 64 + r)) * 1024 + h * 64 + dt*16 + l15] = f2bf(oacc[dt][j]);
      }
  }
}

// ------- fused FIR + mix + gating + ctx, 8 tokens/block, V staged in LDS ------
__global__ __launch_bounds__(256) void paths2(const float* __restrict__ qkv,
    const u16* __restrict__ dOutb, const u16* __restrict__ idb,
    const float* __restrict__ gp, const float* __restrict__ g2L,
    const float* __restrict__ fir_s, const float* __restrict__ fir_l,
    const float* __restrict__ mix, const float* __restrict__ idlog,
    u16* __restrict__ ctxb, float* __restrict__ entAcc) {
  const int bid = ((blockIdx.x & 7) << 6) | (blockIdx.x >> 3);  // XCD-contiguous
  const int b = bid >> 7, n0 = (bid & 127) * TOK;
  const int tid = threadIdx.x;
  __shared__ u16 sV[TOK + 6][1024];
  __shared__ u16 sFS[TOK][1024], sFL[TOK][1024];
  __shared__ float sMix[256];
  __shared__ float sWg[TOK][16][5];
  __shared__ float sIdg[TOK][16];
  __shared__ float sEnt[128];
  sMix[tid] = mix[tid];

  // stage V rows n0-6 .. n0+TOK-1 (bf16)
  #pragma unroll
  for (int r = 0; r < TOK + 6; ++r) {
    int t = n0 - 6 + r;
    u32 lo = 0, hi = 0;
    if (t >= 0) {
      float4 v = *(const float4*)(qkv + ((size_t)b * 1024 + t) * 3072 + 2048 + tid * 4);
      lo = (u32)f2bf(v.x) | ((u32)f2bf(v.y) << 16);
      hi = (u32)f2bf(v.z) | ((u32)f2bf(v.w) << 16);
    }
    *(u32*)&sV[r][tid * 4]     = lo;
    *(u32*)&sV[r][tid * 4 + 2] = hi;
  }

  // per-(token,head) softmaxes + entropy + id gate: threads 0..127
  if (tid < 128) {
    const int tok = tid >> 4, hh = tid & 15;
    const size_t bn = (size_t)b * 1024 + n0 + tok;
    float pl[5], lp[5];
    #pragma unroll
    for (int p = 0; p < 5; ++p) pl[p] = gp[bn * 96 + 16 + hh * 5 + p];
    float mx = pl[0];
    #pragma unroll
    for (int p = 1; p < 5; ++p) mx = fmaxf(mx, pl[p]);
    float s = 0.f;
    #pragma unroll
    for (int p = 0; p < 5; ++p) { pl[p] = expf(pl[p] - mx); s += pl[p]; }
    float inv = 1.f / s, e1 = 0.f;
    #pragma unroll
    for (int p = 0; p < 5; ++p) {
      float prob = pl[p] * inv;
      lp[p] = logf(prob + 1e-8f);
      e1 -= prob * lp[p];
    }
    float gl[5];
    #pragma unroll
    for (int p = 0; p < 5; ++p) gl[p] = g2L[bn * 80 + hh * 5 + p] + lp[p];
    float mx2 = gl[0];
    #pragma unroll
    for (int p = 1; p < 5; ++p) mx2 = fmaxf(mx2, gl[p]);
    float s2 = 0.f;
    #pragma unroll
    for (int p = 0; p < 5; ++p) { gl[p] = expf(gl[p] - mx2); s2 += gl[p]; }
    float inv2 = 1.f / s2, e2 = 0.f;
    #pragma unroll
    for (int p = 0; p < 5; ++p) {
      float w = gl[p] * inv2;
      sWg[tok][hh][p] = w;
      e2 -= w * logf(w + 1e-8f);
    }
    sEnt[tid] = e1 + e2;
    sIdg[tok][hh] = sigmoid_f(gp[bn * 96 + hh]) * sigmoid_f(idlog[hh]);
  }
  __syncthreads();

  // FIR from LDS V (coefs hoisted per dim)
  #pragma unroll
  for (int i = 0; i < 4; ++i) {
    const int idx = tid + i * 256;
    float fl7[7], fs3[3];
    #pragma unroll
    for (int j = 0; j < 7; ++j) fl7[j] = fir_l[(size_t)idx * 7 + j];
    #pragma unroll
    for (int j = 0; j < 3; ++j) fs3[j] = fir_s[(size_t)idx * 3 + j];
    #pragma unroll
    for (int tok = 0; tok < TOK; ++tok) {
      float accs = 0.f, accl = 0.f;
      #pragma unroll
      for (int j = 0; j < 7; ++j) {
        float vv = bf2f(sV[tok + j][idx]);
        accl = fmaf(fl7[j], vv, accl);
        if (j >= 4) accs = fmaf(fs3[j - 4], vv, accs);
      }
      sFS[tok][idx] = f2bf(accs);
      sFL[tok][idx] = f2bf(accl);
    }
  }
  __syncthreads();

  // cross-head mix + combine + ctx write
  #pragma unroll
  for (int i = 0; i < 4; ++i) {
    const int idx = tid + i * 256;
    const int gg = idx >> 6, d = idx & 63;
    #pragma unroll
    for (int tok = 0; tok < TOK; ++tok) {
      float as = bf2f(sFS[tok][idx]), al = bf2f(sFL[tok][idx]);
      #pragma unroll
      for (int hh = 0; hh < 16; ++hh) {
        float m = sMix[hh * 16 + gg];
        as = fmaf(bf2f(sFS[tok][hh * 64 + d]), m, as);
        al = fmaf(bf2f(sFL[tok][hh * 64 + d]), m, al);
      }
      const size_t bn = (size_t)b * 1024 + n0 + tok;
      float w0 = sWg[tok][gg][0], w1 = sWg[tok][gg][1], w2 = sWg[tok][gg][2];
      float w3 = sWg[tok][gg][3], w4 = sWg[tok][gg][4];
      float dv = bf2f(dOutb[bn * 1024 + idx]);
      float vv = bf2f(sV[tok + 6][idx]);
      float iv = bf2f(idb[bn * 1024 + idx]) * sIdg[tok][gg];
      ctxb[bn * 1024 + idx] = f2bf(w0*as + w1*al + w2*dv + w3*vv + w4*iv);
    }
  }
  if (tid == 0) {
    float s = 0.f;
    #pragma unroll
    for (int i = 0; i < 128; ++i) s += sEnt[i];
    atomicAdd(entAcc, s);
  }
}

__global__ void zero_ent(float* e) { e[0] = 0.f; }
__global__ void ent_fin(const float* __restrict__ e, float* __restrict__ dst) {
  dst[0] = e[0] * (1.0f / 65536.0f);
}

// ---------------- host launcher ----------------------------------------------
extern "C" void kernel_launch(void* const* d_in, const int* in_sizes, int n_in,
                              void* d_out, int out_size, void* d_ws, size_t ws_size,
                              hipStream_t stream) {
  (void)in_sizes; (void)n_in; (void)out_size; (void)ws_size;
  const float* x       = (const float*)d_in[0];
  const float* W_qkv   = (const float*)d_in[1];
  const float* W_id    = (const float*)d_in[2];
  const float* W_gate  = (const float*)d_in[3];
  const float* b_gate  = (const float*)d_in[4];
  const float* idlog   = (const float*)d_in[5];
  const float* fir_s   = (const float*)d_in[6];
  const float* fir_l   = (const float*)d_in[7];
  const float* mix     = (const float*)d_in[8];
  const float* W_prune = (const float*)d_in[9];
  const float* b_prune = (const float*)d_in[10];
  const float* W_g1    = (const float*)d_in[11];
  const float* b_g1    = (const float*)d_in[12];
  const float* W_g2    = (const float*)d_in[13];
  const float* b_g2    = (const float*)d_in[14];
  const float* W_proj  = (const float*)d_in[15];
  const float* b_proj  = (const float*)d_in[16];
  float* out = (float*)d_out;

  float* ws    = (float*)d_ws;
  float* qkv3  = ws;                       // 4096 x 3072
  float* gp    = qkv3 + 12582912;          // 4096 x 96
  float* g2l   = gp + 393216;              // 4096 x 80
  float* kqwB  = g2l + 327680;             // 3 bf16 chunk-major buffers
  float* gU    = kqwB + 6291456;           // 4096 x 1024 fp32
  float* dOb   = gU + 4194304;             // bf16 4096x1024 (2,097,152 fl)
  float* idbF  = dOb + 2097152;            // bf16 4096x1024
  float* entA  = idbF + 2097152;           // 1 fl

  u16* kb16 = (u16*)kqwB;
  u16* wb16 = kb16 + 4194304;
  u16* qb16 = wb16 + 4194304;
  u16* dOutb = (u16*)dOb;
  u16* idb   = (u16*)idbF;

  // pre-delta staging aliases (dead before their regions are overwritten)
  u16* xb     = (u16*)kqwB;                    // kb region
  u16* wqT    = wb16;                          // 3072x1024 bf16
  u16* wg1T   = qb16;                          // 1024x1024 bf16
  u16* widT   = qb16 + 1048576;                // 1024x1024 bf16
  u16* hb16   = (u16*)gU;                      // 4096x1024 bf16 (gelu out)
  u16* catGP  = (u16*)(gU + 2097152);          // 128x1024 bf16
  u16* catG2  = (u16*)(gU + 2162688);          // 128x1024 bf16
  float* cb1  = dOb;                           // 128 fl (dead before delta_fused)
  float* cb2  = dOb + 128;
  u16* ctxb   = (u16*)kqwB;                    // post-delta
  u16* wprojT = wb16;                          // post-delta

  // casts + weight transposes
  conv_bf16<<<2048, 256, 0, stream>>>(x, xb, 524288);
  conv_wt<<<dim3(96, 32), 256, 0, stream>>>(W_qkv, wqT, 1024, 3072, 0);
  conv_wt<<<dim3(32, 32), 256, 0, stream>>>(W_id,  widT, 1024, 1024, 0);
  conv_wt<<<dim3(32, 32), 256, 0, stream>>>(W_g1,  wg1T, 1024, 1024, 0);
  conv_wt<<<dim3(1, 32),  256, 0, stream>>>(W_gate,  catGP, 1024, 16, 0);
  conv_wt<<<dim3(3, 32),  256, 0, stream>>>(W_prune, catGP, 1024, 80, 16);
  conv_wt<<<dim3(3, 32),  256, 0, stream>>>(W_g2,    catG2, 1024, 80, 0);
  hipMemsetAsync(catGP + 96 * 1024, 0, 32 * 1024 * sizeof(u16), stream);
  hipMemsetAsync(catG2 + 80 * 1024, 0, 48 * 1024 * sizeof(u16), stream);
  bias_cat<<<1, 256, 0, stream>>>(b_gate, b_prune, b_g2, cb1, cb2);

  // projections (bf16 MFMA); id emitted bf16
  gemm_mfma<0,0><<<dim3(24, 32), 256, 0, stream>>>(xb, wqT, nullptr, qkv3, BN_, 3072, 1024, 3072);
  gemm_mfma<0,1><<<dim3(8, 32), 256, 0, stream>>>(xb, widT, nullptr, (float*)idb, BN_, 1024, 1024, 1024);
  gemm_mfma<1,1><<<dim3(8, 32), 256, 0, stream>>>(xb, wg1T, b_g1, (float*)hb16, BN_, 1024, 1024, 1024);
  gemm_mfma<0,0><<<dim3(1, 32), 256, 0, stream>>>(xb, catGP, cb1, gp, BN_, 128, 1024, 96);
  gemm_mfma<0,0><<<dim3(1, 32), 256, 0, stream>>>(hb16, catG2, cb2, g2l, BN_, 128, 1024, 80);

  // delta rule
  delta_prep<<<1024, 256, 0, stream>>>(qkv3, gU, kb16, wb16, qb16);
  delta_fused<<<64, 256, 0, stream>>>(kb16, wb16, qb16, gU, dOutb);

  // fused paths + gating (8 tokens/block)
  zero_ent<<<1, 1, 0, stream>>>(entA);
  paths2<<<512, 256, 0, stream>>>(qkv3, dOutb, idb, gp, g2l,
                                  fir_s, fir_l, mix, idlog, ctxb, entA);

  // output projection + entropy scalar
  conv_wt<<<dim3(32, 32), 256, 0, stream>>>(W_proj, wprojT, 1024, 1024, 0);
  gemm_mfma<0,0><<<dim3(8, 32), 256, 0, stream>>>(ctxb, wprojT, b_proj, out, BN_, 1024, 1024, 1024);
  ent_fin<<<1, 1, 0, stream>>>(entA, out + 4194304);
}

// Round 9
// 332.116 us; speedup vs baseline: 4.1109x; 1.0135x over previous
//
#include <hip/hip_runtime.h>
#include <math.h>

#define B_ 4
#define N_ 1024
#define C_ 1024
#define H_ 16
#define D_ 64
#define P_ 5
#define BN_ (B_*N_)
#define TOK 8

typedef unsigned int u32;
typedef unsigned short u16;
typedef __attribute__((ext_vector_type(8))) short bf16x8;
typedef __attribute__((ext_vector_type(4))) float f32x4;

__device__ __forceinline__ float gelu_f(float x){
  float x3 = x*x*x;
  return 0.5f*x*(1.0f + tanhf(0.7978845608028654f*(x + 0.044715f*x3)));
}
__device__ __forceinline__ float sigmoid_f(float x){ return 1.0f/(1.0f+expf(-x)); }

__device__ __forceinline__ u16 f2bf(float f) {
  u32 u = __float_as_uint(f);
  u32 r = u + 0x7fffu + ((u >> 16) & 1u);
  return (u16)(r >> 16);
}
__device__ __forceinline__ float bf2f(u16 v){ return __uint_as_float(((u32)v) << 16); }

__device__ __forceinline__ void gload16(const void* g, void* l) {
  __builtin_amdgcn_global_load_lds((const __attribute__((address_space(1))) u32*)g,
                                   (__attribute__((address_space(3))) u32*)l, 16, 0, 0);
}

// ---------------- fp32 -> bf16 elementwise cast (8 elems/thread) --------------
__global__ __launch_bounds__(256) void conv_bf16(const float* __restrict__ in,
    u16* __restrict__ out, int n8) {
  int i = blockIdx.x * 256 + threadIdx.x;
  if (i >= n8) return;
  const float4* p = (const float4*)in + (size_t)i * 2;
  float4 a = p[0], b = p[1];
  uint4 o;
  o.x = (u32)f2bf(a.x) | ((u32)f2bf(a.y) << 16);
  o.y = (u32)f2bf(a.z) | ((u32)f2bf(a.w) << 16);
  o.z = (u32)f2bf(b.x) | ((u32)f2bf(b.y) << 16);
  o.w = (u32)f2bf(b.z) | ((u32)f2bf(b.w) << 16);
  *(uint4*)(out + (size_t)i * 8) = o;
}

// ------- fp32 [K][Nn] -> bf16 [Nn][K] transpose cast, guarded, with row offset
__global__ __launch_bounds__(256) void conv_wt(const float* __restrict__ W,
    u16* __restrict__ Wt, int K, int Nn, int roff) {
  __shared__ float t[32][33];
  int c0 = blockIdx.x * 32, r0 = blockIdx.y * 32;
  int tx = threadIdx.x & 31, ty = threadIdx.x >> 5;
  #pragma unroll
  for (int i = 0; i < 4; ++i) {
    int r = ty + i * 8;
    t[r][tx] = (c0 + tx < Nn) ? W[(size_t)(r0 + r) * Nn + c0 + tx] : 0.f;
  }
  __syncthreads();
  #pragma unroll
  for (int i = 0; i < 4; ++i) {
    int r = ty + i * 8;
    if (c0 + r < Nn)
      Wt[(size_t)(roff + c0 + r) * K + r0 + tx] = f2bf(t[tx][r]);
  }
}

// --------- bias concat: cb1 = [b_gate(16) | b_prune(80) | 0], cb2 = [b_g2(80)|0]
__global__ void bias_cat(const float* __restrict__ bg, const float* __restrict__ bp,
    const float* __restrict__ bg2, float* __restrict__ cb1, float* __restrict__ cb2) {
  int t = threadIdx.x;
  if (t < 128) cb1[t] = (t < 16) ? bg[t] : (t < 96 ? bp[t - 16] : 0.f);
  else { int c = t - 128; cb2[c] = (c < 80) ? bg2[c] : 0.f; }
}

// ---------------- bf16 MFMA GEMM: C = A(M,K) @ Bt(Nn,K)^T (+bias, +gelu) ------
template<int ACT, int OBF>
__global__ __launch_bounds__(256) void gemm_mfma(const u16* __restrict__ A,
    const u16* __restrict__ Bt, const float* __restrict__ bias,
    float* __restrict__ Cout, int M, int Nn, int K, int Ns) {
  __shared__ __align__(16) u16 lA[128 * 32];
  __shared__ __align__(16) u16 lB[128 * 32];
  const int tid = threadIdx.x;
  const int lane = tid & 63, wid = tid >> 6;
  const int wr = wid >> 1, wc = wid & 1;
  const int r16 = lane & 15, kq = lane >> 4;
  const int row0 = blockIdx.y * 128, col0 = blockIdx.x * 128;
  const int c0 = wid * 2;
  const int srow = lane >> 2;
  const int skoff = (lane & 3) * 8;

  f32x4 acc[4][4] = {};
  for (int k0 = 0; k0 < K; k0 += 32) {
    #pragma unroll
    for (int s = 0; s < 2; ++s) {
      int c = c0 + s;
      int rt = c * 16 + srow;
      gload16(A  + (size_t)(row0 + rt) * K + k0 + skoff, &lA[c * 512]);
      gload16(Bt + (size_t)(col0 + rt) * K + k0 + skoff, &lB[c * 512]);
    }
    __syncthreads();
    bf16x8 af[4], bfv[4];
    #pragma unroll
    for (int m = 0; m < 4; ++m)
      af[m] = *(const bf16x8*)&lA[(wr * 64 + m * 16 + r16) * 32 + kq * 8];
    #pragma unroll
    for (int n = 0; n < 4; ++n)
      bfv[n] = *(const bf16x8*)&lB[(wc * 64 + n * 16 + r16) * 32 + kq * 8];
    #pragma unroll
    for (int m = 0; m < 4; ++m)
      #pragma unroll
      for (int n = 0; n < 4; ++n)
        acc[m][n] = __builtin_amdgcn_mfma_f32_16x16x32_bf16(af[m], bfv[n], acc[m][n], 0, 0, 0);
    __syncthreads();
  }
  #pragma unroll
  for (int n = 0; n < 4; ++n) {
    int col = col0 + wc * 64 + n * 16 + r16;
    if (col >= Ns) continue;
    float bs = bias ? bias[col] : 0.0f;
    #pragma unroll
    for (int m = 0; m < 4; ++m) {
      int rowb = row0 + wr * 64 + m * 16 + kq * 4;
      #pragma unroll
      for (int r = 0; r < 4; ++r) {
        float v = acc[m][n][r] + bs;
        if (ACT == 1) v = gelu_f(v);
        if (OBF) ((u16*)Cout)[(size_t)(rowb + r) * Ns + col] = f2bf(v);
        else     Cout[(size_t)(rowb + r) * Ns + col] = v;
      }
    }
  }
}

// ---------------- DeltaNet prep: normalize, M via MFMA, T' inverse ------------
// qkv row stride 3072 (q|k|v). Emits kb/qb/vb bf16 (chunk-major [bx][r][e]) and
// tb = T' = M^{-1} diag(beta) bf16.
__global__ __launch_bounds__(256) void delta_prep(const float* __restrict__ qkv,
    u16* __restrict__ kb, u16* __restrict__ tb, u16* __restrict__ qb,
    u16* __restrict__ vb) {
  const int bx = blockIdx.x;
  const int bh = bx >> 4, g = bx & 15;
  const int b = bh >> 4, h = bh & 15;
  const int n0 = g * 16 * 4;  // g*64
  const int tid = threadIdx.x;
  __shared__ float sK[64][65];
  __shared__ __align__(16) u16 sKb[64][72];
  __shared__ __align__(16) float sMT[64][68];  // M^T fp32, [c][r], upper zeroed
  __shared__ float sPart[64][8];
  __shared__ float sBeta[64];

  const size_t rowbase = (size_t)b * N_ + n0;
  // load K to LDS; V: straight bf16 cast to global (no beta)
  for (int i = 0; i < 16; ++i) {
    int idx = tid + i * 256; int r = idx >> 6, d = idx & 63;
    size_t off = (rowbase + r) * 3072 + h * 64 + d;
    sK[r][d] = qkv[off + 1024];
    vb[(size_t)bx * 4096 + idx] = f2bf(qkv[off + 2048]);
  }
  if (tid < 64) sBeta[tid] = 1.0f - 0.9f * (float)(n0 + tid) / 1023.0f;
  __syncthreads();

  // parallel norms: thread = (row rr_, quarter qd)
  const int rr_ = tid >> 2, qd = tid & 3;
  float ps = 0.f;
  #pragma unroll
  for (int j = 0; j < 16; ++j) { float v = sK[rr_][qd*16+j]; ps = fmaf(v, v, ps); }
  sPart[rr_][qd] = ps;
  const size_t qbase = (rowbase + rr_) * 3072 + h * 64 + qd * 16;
  float4 qv[4]; float qs = 0.f;
  #pragma unroll
  for (int j = 0; j < 4; ++j) {
    qv[j] = *(const float4*)(qkv + qbase + 4*j);
    qs += qv[j].x*qv[j].x + qv[j].y*qv[j].y + qv[j].z*qv[j].z + qv[j].w*qv[j].w;
  }
  sPart[rr_][4+qd] = qs;
  __syncthreads();
  const float ksc = rsqrtf(sPart[rr_][0]+sPart[rr_][1]+sPart[rr_][2]+sPart[rr_][3] + 1e-6f);
  const float qsc = rsqrtf(sPart[rr_][4]+sPart[rr_][5]+sPart[rr_][6]+sPart[rr_][7] + 1e-6f) * 0.125f;
  const size_t cbase = (size_t)bx * 4096 + rr_ * 64 + qd * 16;
  #pragma unroll
  for (int j = 0; j < 16; ++j) {
    u16 vb16v = f2bf(sK[rr_][qd*16+j] * ksc);
    kb[cbase + j] = vb16v;
    sKb[rr_][qd*16+j] = vb16v;
  }
  #pragma unroll
  for (int j = 0; j < 4; ++j) {
    float4 t = qv[j];
    u32 lo = (u32)f2bf(t.x * qsc) | ((u32)f2bf(t.y * qsc) << 16);
    u32 hi = (u32)f2bf(t.z * qsc) | ((u32)f2bf(t.w * qsc) << 16);
    *(u32*)(qb + cbase + j*4)     = lo;
    *(u32*)(qb + cbase + j*4 + 2) = hi;
  }
  __syncthreads();

  // M^T via MFMA: M[r][c] = beta_r * khat_r . khat_c (r>c else 0), store [c][r]
  {
    const int lane = tid & 63, wv = tid >> 6;
    const int l15 = lane & 15, l4 = lane >> 4;
    bf16x8 ka0 = *(const bf16x8*)&sKb[16*wv + l15][l4*8];
    bf16x8 ka1 = *(const bf16x8*)&sKb[16*wv + l15][32 + l4*8];
    #pragma unroll
    for (int ct = 0; ct < 4; ++ct) {
      bf16x8 kc0 = *(const bf16x8*)&sKb[ct*16 + l15][l4*8];
      bf16x8 kc1 = *(const bf16x8*)&sKb[ct*16 + l15][32 + l4*8];
      f32x4 m = {};
      m = __builtin_amdgcn_mfma_f32_16x16x32_bf16(ka0, kc0, m, 0, 0, 0);
      m = __builtin_amdgcn_mfma_f32_16x16x32_bf16(ka1, kc1, m, 0, 0, 0);
      const int c = ct*16 + l15, rbase = 16*wv + l4*4;
      float4 o;
      o.x = (rbase+0 > c) ? sBeta[rbase+0] * m[0] : 0.f;
      o.y = (rbase+1 > c) ? sBeta[rbase+1] * m[1] : 0.f;
      o.z = (rbase+2 > c) ? sBeta[rbase+2] * m[2] : 0.f;
      o.w = (rbase+3 > c) ? sBeta[rbase+3] * m[3] : 0.f;
      *(float4*)&sMT[c][rbase] = o;
    }
  }
  __syncthreads();

  // T' solve: thread c in [0,64): forward-substitute e_c, triangular-blocked
  if (tid < 64) {
    const int c = tid;
    float a[64];
    #pragma unroll
    for (int i = 0; i < 64; ++i) a[i] = (i == c) ? 1.f : 0.f;
    #pragma unroll
    for (int ib = 0; ib < 4; ++ib) {
      #pragma unroll
      for (int i2 = 0; i2 < 16; ++i2) {
        const int i = ib * 16 + i2;
        const float wi = a[i];
        #pragma unroll
        for (int j4 = ib * 4; j4 < 16; ++j4) {
          const float4 m = *(const float4*)&sMT[i][j4 * 4];  // broadcast read
          a[j4*4+0] = fmaf(-m.x, wi, a[j4*4+0]);
          a[j4*4+1] = fmaf(-m.y, wi, a[j4*4+1]);
          a[j4*4+2] = fmaf(-m.z, wi, a[j4*4+2]);
          a[j4*4+3] = fmaf(-m.w, wi, a[j4*4+3]);
        }
      }
    }
    const float bc = sBeta[c];
    const size_t obase = (size_t)bx * 4096;
    #pragma unroll
    for (int i = 0; i < 64; ++i) tb[obase + i * 64 + c] = f2bf(a[i] * bc);
  }
}

// -------- DeltaNet fused scan+output: one block per (b,h), S in MFMA accs -----
// Per chunk: attn=tril(q k^T); Y = v - khat@S; u_adj = T'@Y;
// o = q@S + attn@u_adj; S += khat^T@u_adj.
__global__ __launch_bounds__(256, 1) void delta_fused(const u16* __restrict__ kb,
    const u16* __restrict__ tb, const u16* __restrict__ qb,
    const u16* __restrict__ vb, u16* __restrict__ dOutb) {
  const int bh = blockIdx.x;
  const int b = bh >> 4, h = bh & 15;
  const int tid = threadIdx.x;
  const int lane = tid & 63, wv = tid >> 6;
  const int l15 = lane & 15, l4 = lane >> 4;
  const int fr = tid >> 2, fe0 = (tid & 3) * 16;

  __shared__ __align__(16) u16 sK [64][72];   // khat   [c][dk]
  __shared__ __align__(16) u16 sKT[64][72];   // khat^T [dk][c]
  __shared__ __align__(16) u16 sT [64][72];   // T'     [c][j]
  __shared__ __align__(16) u16 sQ [64][72];   // qhat   [r][dk]
  __shared__ __align__(16) u16 sV [64][72];   // v      [c][dv]
  __shared__ __align__(16) u16 sSt[64][72];   // S^T    [dv][dk]
  __shared__ __align__(16) u16 sYt[64][72];   // Y^T    [dv][c]
  __shared__ __align__(16) u16 sUt[64][72];   // u_adj^T[dv][c]
  __shared__ __align__(16) u16 sA [64][72];   // attn   [r][c]

  f32x4 Sacc[4] = {};   // S[dk = 16wv+l4*4+j][dv = dt*16+l15]

  uint4 pk0, pk1, pt0, pt1, pq0, pq1, pv0, pv1;
  {
    const size_t bs = (size_t)(bh * 16) * 4096;
    pk0 = *(const uint4*)(kb + bs + tid*16); pk1 = *(const uint4*)(kb + bs + tid*16 + 8);
    pt0 = *(const uint4*)(tb + bs + tid*16); pt1 = *(const uint4*)(tb + bs + tid*16 + 8);
    pq0 = *(const uint4*)(qb + bs + tid*16); pq1 = *(const uint4*)(qb + bs + tid*16 + 8);
    pv0 = *(const uint4*)(vb + bs + tid*16); pv1 = *(const uint4*)(vb + bs + tid*16 + 8);
  }

  for (int g = 0; g < 16; ++g) {
    __syncthreads();                           // BAR_A: prev phase reads done
    *(uint4*)&sK[fr][fe0] = pk0; *(uint4*)&sK[fr][fe0+8] = pk1;
    *(uint4*)&sT[fr][fe0] = pt0; *(uint4*)&sT[fr][fe0+8] = pt1;
    *(uint4*)&sQ[fr][fe0] = pq0; *(uint4*)&sQ[fr][fe0+8] = pq1;
    *(uint4*)&sV[fr][fe0] = pv0; *(uint4*)&sV[fr][fe0+8] = pv1;
    {
      u32 kk[8] = {pk0.x, pk0.y, pk0.z, pk0.w, pk1.x, pk1.y, pk1.z, pk1.w};
      #pragma unroll
      for (int i = 0; i < 8; ++i) {
        sKT[fe0 + 2*i][fr]     = (u16)kk[i];
        sKT[fe0 + 2*i + 1][fr] = (u16)(kk[i] >> 16);
      }
    }
    #pragma unroll
    for (int dt = 0; dt < 4; ++dt) {
      u32 lo = (u32)f2bf(Sacc[dt][0]) | ((u32)f2bf(Sacc[dt][1]) << 16);
      u32 hi = (u32)f2bf(Sacc[dt][2]) | ((u32)f2bf(Sacc[dt][3]) << 16);
      *(u32*)&sSt[dt*16 + l15][16*wv + l4*4]     = lo;
      *(u32*)&sSt[dt*16 + l15][16*wv + l4*4 + 2] = hi;
    }
    __syncthreads();                           // BAR_B: LDS ready
    if (g < 15) {
      const size_t bs = (size_t)(bh * 16 + g + 1) * 4096;
      pk0 = *(const uint4*)(kb + bs + tid*16); pk1 = *(const uint4*)(kb + bs + tid*16 + 8);
      pt0 = *(const uint4*)(tb + bs + tid*16); pt1 = *(const uint4*)(tb + bs + tid*16 + 8);
      pq0 = *(const uint4*)(qb + bs + tid*16); pq1 = *(const uint4*)(qb + bs + tid*16 + 8);
      pv0 = *(const uint4*)(vb + bs + tid*16); pv1 = *(const uint4*)(vb + bs + tid*16 + 8);
    }
    // ---- phase A: attn = q k^T ; Y = khat@S ; o1 = q@S ----
    bf16x8 qf0 = *(const bf16x8*)&sQ[16*wv + l15][l4*8];
    bf16x8 qf1 = *(const bf16x8*)&sQ[16*wv + l15][32 + l4*8];
    bf16x8 kr0 = *(const bf16x8*)&sK[16*wv + l15][l4*8];
    bf16x8 kr1 = *(const bf16x8*)&sK[16*wv + l15][32 + l4*8];
    f32x4 aacc[4] = {}, yacc[4] = {}, oacc[4] = {};
    #pragma unroll
    for (int ct = 0; ct < 4; ++ct) {
      bf16x8 kc0 = *(const bf16x8*)&sK[ct*16 + l15][l4*8];
      bf16x8 kc1 = *(const bf16x8*)&sK[ct*16 + l15][32 + l4*8];
      aacc[ct] = __builtin_amdgcn_mfma_f32_16x16x32_bf16(qf0, kc0, aacc[ct], 0, 0, 0);
      aacc[ct] = __builtin_amdgcn_mfma_f32_16x16x32_bf16(qf1, kc1, aacc[ct], 0, 0, 0);
    }
    #pragma unroll
    for (int dt = 0; dt < 4; ++dt) {
      bf16x8 s0 = *(const bf16x8*)&sSt[dt*16 + l15][l4*8];
      bf16x8 s1 = *(const bf16x8*)&sSt[dt*16 + l15][32 + l4*8];
      yacc[dt] = __builtin_amdgcn_mfma_f32_16x16x32_bf16(kr0, s0, yacc[dt], 0, 0, 0);
      yacc[dt] = __builtin_amdgcn_mfma_f32_16x16x32_bf16(kr1, s1, yacc[dt], 0, 0, 0);
      oacc[dt] = __builtin_amdgcn_mfma_f32_16x16x32_bf16(qf0, s0, oacc[dt], 0, 0, 0);
      oacc[dt] = __builtin_amdgcn_mfma_f32_16x16x32_bf16(qf1, s1, oacc[dt], 0, 0, 0);
    }
    // Y^T = (v - khat@S)^T -> sYt bf16 ; attn -> sA (tril)
    #pragma unroll
    for (int dt = 0; dt < 4; ++dt) {
      float y0 = bf2f(sV[16*wv + l4*4 + 0][dt*16 + l15]) - yacc[dt][0];
      float y1 = bf2f(sV[16*wv + l4*4 + 1][dt*16 + l15]) - yacc[dt][1];
      float y2 = bf2f(sV[16*wv + l4*4 + 2][dt*16 + l15]) - yacc[dt][2];
      float y3 = bf2f(sV[16*wv + l4*4 + 3][dt*16 + l15]) - yacc[dt][3];
      u32 lo = (u32)f2bf(y0) | ((u32)f2bf(y1) << 16);
      u32 hi = (u32)f2bf(y2) | ((u32)f2bf(y3) << 16);
      *(u32*)&sYt[dt*16 + l15][16*wv + l4*4]     = lo;
      *(u32*)&sYt[dt*16 + l15][16*wv + l4*4 + 2] = hi;
    }
    #pragma unroll
    for (int ct = 0; ct < 4; ++ct)
      #pragma unroll
      for (int j = 0; j < 4; ++j) {
        int r = 16*wv + l4*4 + j, c = ct*16 + l15;
        sA[r][c] = f2bf((r >= c) ? aacc[ct][j] : 0.f);
      }
    __syncthreads();                           // BAR_C: sYt/sA visible
    // ---- phase B1: u_adj = T' @ Y ----
    bf16x8 tf0 = *(const bf16x8*)&sT[16*wv + l15][l4*8];
    bf16x8 tf1 = *(const bf16x8*)&sT[16*wv + l15][32 + l4*8];
    f32x4 uacc[4] = {};
    #pragma unroll
    for (int dt = 0; dt < 4; ++dt) {
      bf16x8 y0 = *(const bf16x8*)&sYt[dt*16 + l15][l4*8];
      bf16x8 y1 = *(const bf16x8*)&sYt[dt*16 + l15][32 + l4*8];
      uacc[dt] = __builtin_amdgcn_mfma_f32_16x16x32_bf16(tf0, y0, uacc[dt], 0, 0, 0);
      uacc[dt] = __builtin_amdgcn_mfma_f32_16x16x32_bf16(tf1, y1, uacc[dt], 0, 0, 0);
    }
    #pragma unroll
    for (int dt = 0; dt < 4; ++dt) {
      u32 lo = (u32)f2bf(uacc[dt][0]) | ((u32)f2bf(uacc[dt][1]) << 16);
      u32 hi = (u32)f2bf(uacc[dt][2]) | ((u32)f2bf(uacc[dt][3]) << 16);
      *(u32*)&sUt[dt*16 + l15][16*wv + l4*4]     = lo;
      *(u32*)&sUt[dt*16 + l15][16*wv + l4*4 + 2] = hi;
    }
    __syncthreads();                           // BAR_D: sUt visible
    // ---- phase B2: o += attn@u_adj ; S += khat^T@u_adj ----
    bf16x8 af0 = *(const bf16x8*)&sA[16*wv + l15][l4*8];
    bf16x8 af1 = *(const bf16x8*)&sA[16*wv + l15][32 + l4*8];
    bf16x8 kt0 = *(const bf16x8*)&sKT[16*wv + l15][l4*8];
    bf16x8 kt1 = *(const bf16x8*)&sKT[16*wv + l15][32 + l4*8];
    #pragma unroll
    for (int dt = 0; dt < 4; ++dt) {
      bf16x8 u0 = *(const bf16x8*)&sUt[dt*16 + l15][l4*8];
      bf16x8 u1 = *(const bf16x8*)&sUt[dt*16 + l15][32 + l4*8];
      oacc[dt] = __builtin_amdgcn_mfma_f32_16x16x32_bf16(af0, u0, oacc[dt], 0, 0, 0);
      oacc[dt] = __builtin_amdgcn_mfma_f32_16x16x32_bf16(af1, u1, oacc[dt], 0, 0, 0);
      Sacc[dt] = __builtin_amdgcn_mfma_f32_16x16x32_bf16(kt0, u0, Sacc[dt], 0, 0, 0);
      Sacc[dt] = __builtin_amdgcn_mfma_f32_16x16x32_bf16(kt1, u1, Sacc[dt], 0, 0, 0);
    }
    #pragma unroll
    for (int dt = 0; dt < 4; ++dt)
      #pragma unroll
      for (int j = 0; j < 4; ++j) {
        int r = 16*wv + l4*4 + j;
        dOutb[((size_t)(b * 1024 + g * 64 + r)) * 1024 + h * 64 + dt*16 + l15] = f2bf(oacc[dt][j]);
      }
  }
}

// ------- fused FIR + mix + gating + ctx, 8 tokens/block, V staged in LDS ------
__global__ __launch_bounds__(256) void paths2(const float* __restrict__ qkv,
    const u16* __restrict__ dOutb, const u16* __restrict__ idb,
    const float* __restrict__ gp, const float* __restrict__ g2L,
    const float* __restrict__ fir_s, const float* __restrict__ fir_l,
    const float* __restrict__ mix, const float* __restrict__ idlog,
    u16* __restrict__ ctxb, float* __restrict__ entAcc) {
  const int bid = ((blockIdx.x & 7) << 6) | (blockIdx.x >> 3);  // XCD-contiguous
  const int b = bid >> 7, n0 = (bid & 127) * TOK;
  const int tid = threadIdx.x;
  __shared__ u16 sV[TOK + 6][1024];
  __shared__ u16 sFS[TOK][1024], sFL[TOK][1024];
  __shared__ float sMix[256];
  __shared__ float sWg[TOK][16][5];
  __shared__ float sIdg[TOK][16];
  __shared__ float sEnt[128];
  sMix[tid] = mix[tid];

  #pragma unroll
  for (int r = 0; r < TOK + 6; ++r) {
    int t = n0 - 6 + r;
    u32 lo = 0, hi = 0;
    if (t >= 0) {
      float4 v = *(const float4*)(qkv + ((size_t)b * 1024 + t) * 3072 + 2048 + tid * 4);
      lo = (u32)f2bf(v.x) | ((u32)f2bf(v.y) << 16);
      hi = (u32)f2bf(v.z) | ((u32)f2bf(v.w) << 16);
    }
    *(u32*)&sV[r][tid * 4]     = lo;
    *(u32*)&sV[r][tid * 4 + 2] = hi;
  }

  if (tid < 128) {
    const int tok = tid >> 4, hh = tid & 15;
    const size_t bn = (size_t)b * 1024 + n0 + tok;
    float pl[5], lp[5];
    #pragma unroll
    for (int p = 0; p < 5; ++p) pl[p] = gp[bn * 96 + 16 + hh * 5 + p];
    float mx = pl[0];
    #pragma unroll
    for (int p = 1; p < 5; ++p) mx = fmaxf(mx, pl[p]);
    float s = 0.f;
    #pragma unroll
    for (int p = 0; p < 5; ++p) { pl[p] = expf(pl[p] - mx); s += pl[p]; }
    float inv = 1.f / s, e1 = 0.f;
    #pragma unroll
    for (int p = 0; p < 5; ++p) {
      float prob = pl[p] * inv;
      lp[p] = logf(prob + 1e-8f);
      e1 -= prob * lp[p];
    }
    float gl[5];
    #pragma unroll
    for (int p = 0; p < 5; ++p) gl[p] = g2L[bn * 80 + hh * 5 + p] + lp[p];
    float mx2 = gl[0];
    #pragma unroll
    for (int p = 1; p < 5; ++p) mx2 = fmaxf(mx2, gl[p]);
    float s2 = 0.f;
    #pragma unroll
    for (int p = 0; p < 5; ++p) { gl[p] = expf(gl[p] - mx2); s2 += gl[p]; }
    float inv2 = 1.f / s2, e2 = 0.f;
    #pragma unroll
    for (int p = 0; p < 5; ++p) {
      float w = gl[p] * inv2;
      sWg[tok][hh][p] = w;
      e2 -= w * logf(w + 1e-8f);
    }
    sEnt[tid] = e1 + e2;
    sIdg[tok][hh] = sigmoid_f(gp[bn * 96 + hh]) * sigmoid_f(idlog[hh]);
  }
  __syncthreads();

  #pragma unroll
  for (int i = 0; i < 4; ++i) {
    const int idx = tid + i * 256;
    float fl7[7], fs3[3];
    #pragma unroll
    for (int j = 0; j < 7; ++j) fl7[j] = fir_l[(size_t)idx * 7 + j];
    #pragma unroll
    for (int j = 0; j < 3; ++j) fs3[j] = fir_s[(size_t)idx * 3 + j];
    #pragma unroll
    for (int tok = 0; tok < TOK; ++tok) {
      float accs = 0.f, accl = 0.f;
      #pragma unroll
      for (int j = 0; j < 7; ++j) {
        float vv = bf2f(sV[tok + j][idx]);
        accl = fmaf(fl7[j], vv, accl);
        if (j >= 4) accs = fmaf(fs3[j - 4], vv, accs);
      }
      sFS[tok][idx] = f2bf(accs);
      sFL[tok][idx] = f2bf(accl);
    }
  }
  __syncthreads();

  #pragma unroll
  for (int i = 0; i < 4; ++i) {
    const int idx = tid + i * 256;
    const int gg = idx >> 6, d = idx & 63;
    #pragma unroll
    for (int tok = 0; tok < TOK; ++tok) {
      float as = bf2f(sFS[tok][idx]), al = bf2f(sFL[tok][idx]);
      #pragma unroll
      for (int hh = 0; hh < 16; ++hh) {
        float m = sMix[hh * 16 + gg];
        as = fmaf(bf2f(sFS[tok][hh * 64 + d]), m, as);
        al = fmaf(bf2f(sFL[tok][hh * 64 + d]), m, al);
      }
      const size_t bn = (size_t)b * 1024 + n0 + tok;
      float w0 = sWg[tok][gg][0], w1 = sWg[tok][gg][1], w2 = sWg[tok][gg][2];
      float w3 = sWg[tok][gg][3], w4 = sWg[tok][gg][4];
      float dv = bf2f(dOutb[bn * 1024 + idx]);
      float vv = bf2f(sV[tok + 6][idx]);
      float iv = bf2f(idb[bn * 1024 + idx]) * sIdg[tok][gg];
      ctxb[bn * 1024 + idx] = f2bf(w0*as + w1*al + w2*dv + w3*vv + w4*iv);
    }
  }
  if (tid == 0) {
    float s = 0.f;
    #pragma unroll
    for (int i = 0; i < 128; ++i) s += sEnt[i];
    atomicAdd(entAcc, s);
  }
}

__global__ void zero_ent(float* e) { e[0] = 0.f; }
__global__ void ent_fin(const float* __restrict__ e, float* __restrict__ dst) {
  dst[0] = e[0] * (1.0f / 65536.0f);
}

// ---------------- host launcher ----------------------------------------------
extern "C" void kernel_launch(void* const* d_in, const int* in_sizes, int n_in,
                              void* d_out, int out_size, void* d_ws, size_t ws_size,
                              hipStream_t stream) {
  (void)in_sizes; (void)n_in; (void)out_size; (void)ws_size;
  const float* x       = (const float*)d_in[0];
  const float* W_qkv   = (const float*)d_in[1];
  const float* W_id    = (const float*)d_in[2];
  const float* W_gate  = (const float*)d_in[3];
  const float* b_gate  = (const float*)d_in[4];
  const float* idlog   = (const float*)d_in[5];
  const float* fir_s   = (const float*)d_in[6];
  const float* fir_l   = (const float*)d_in[7];
  const float* mix     = (const float*)d_in[8];
  const float* W_prune = (const float*)d_in[9];
  const float* b_prune = (const float*)d_in[10];
  const float* W_g1    = (const float*)d_in[11];
  const float* b_g1    = (const float*)d_in[12];
  const float* W_g2    = (const float*)d_in[13];
  const float* b_g2    = (const float*)d_in[14];
  const float* W_proj  = (const float*)d_in[15];
  const float* b_proj  = (const float*)d_in[16];
  float* out = (float*)d_out;

  float* ws    = (float*)d_ws;
  float* qkv3  = ws;                       // 4096 x 3072 fp32
  float* gp    = qkv3 + 12582912;          // 4096 x 96
  float* g2l   = gp + 393216;              // 4096 x 80
  float* dB    = g2l + 327680;             // 4 bf16 chunk-major buffers (8.39M fl)
  float* dOb   = dB + 8388608;             // bf16 4096x1024 (2,097,152 fl)
  float* idbF  = dOb + 2097152;            // bf16 4096x1024
  float* entA  = idbF + 2097152;           // 1 fl

  u16* kb16 = (u16*)dB;                    // 4,194,304 u16 each
  u16* tb16 = kb16 + 4194304;
  u16* qb16 = kb16 + 8388608;
  u16* vb16 = kb16 + 12582912;
  u16* dOutb = (u16*)dOb;
  u16* idb   = (u16*)idbF;

  // pre-delta staging aliases (dead before their regions are overwritten)
  u16* xb     = kb16;                      // 4096x1024 bf16 (exact fit)
  u16* wqT    = tb16;                      // 3072x1024 bf16
  u16* widT   = qb16;                      // 1024x1024 bf16
  u16* wg1T   = qb16 + 1048576;            // 1024x1024 bf16
  u16* catGP  = qb16 + 2097152;            // 128x1024 bf16
  u16* catG2  = qb16 + 2228224;            // 128x1024 bf16
  u16* hb16   = vb16;                      // 4096x1024 bf16 (gelu out)
  float* cb1  = dOb;                       // 128 fl (dead before delta_fused)
  float* cb2  = dOb + 128;
  // post-delta aliases
  u16* ctxb   = kb16;                      // kb dead after delta_fused
  u16* wprojT = tb16;                      // tb dead after delta_fused

  // casts + weight transposes
  conv_bf16<<<2048, 256, 0, stream>>>(x, xb, 524288);
  conv_wt<<<dim3(96, 32), 256, 0, stream>>>(W_qkv, wqT, 1024, 3072, 0);
  conv_wt<<<dim3(32, 32), 256, 0, stream>>>(W_id,  widT, 1024, 1024, 0);
  conv_wt<<<dim3(32, 32), 256, 0, stream>>>(W_g1,  wg1T, 1024, 1024, 0);
  conv_wt<<<dim3(1, 32),  256, 0, stream>>>(W_gate,  catGP, 1024, 16, 0);
  conv_wt<<<dim3(3, 32),  256, 0, stream>>>(W_prune, catGP, 1024, 80, 16);
  conv_wt<<<dim3(3, 32),  256, 0, stream>>>(W_g2,    catG2, 1024, 80, 0);
  hipMemsetAsync(catGP + 96 * 1024, 0, 32 * 1024 * sizeof(u16), stream);
  hipMemsetAsync(catG2 + 80 * 1024, 0, 48 * 1024 * sizeof(u16), stream);
  bias_cat<<<1, 256, 0, stream>>>(b_gate, b_prune, b_g2, cb1, cb2);

  // projections (bf16 MFMA); id + gelu(g1) emitted bf16
  gemm_mfma<0,0><<<dim3(24, 32), 256, 0, stream>>>(xb, wqT, nullptr, qkv3, BN_, 3072, 1024, 3072);
  gemm_mfma<0,1><<<dim3(8, 32), 256, 0, stream>>>(xb, widT, nullptr, (float*)idb, BN_, 1024, 1024, 1024);
  gemm_mfma<1,1><<<dim3(8, 32), 256, 0, stream>>>(xb, wg1T, b_g1, (float*)hb16, BN_, 1024, 1024, 1024);
  gemm_mfma<0,0><<<dim3(1, 32), 256, 0, stream>>>(xb, catGP, cb1, gp, BN_, 128, 1024, 96);
  gemm_mfma<0,0><<<dim3(1, 32), 256, 0, stream>>>(hb16, catG2, cb2, g2l, BN_, 128, 1024, 80);

  // delta rule
  delta_prep<<<1024, 256, 0, stream>>>(qkv3, kb16, tb16, qb16, vb16);
  delta_fused<<<64, 256, 0, stream>>>(kb16, tb16, qb16, vb16, dOutb);

  // fused paths + gating (8 tokens/block)
  zero_ent<<<1, 1, 0, stream>>>(entA);
  paths2<<<512, 256, 0, stream>>>(qkv3, dOutb, idb, gp, g2l,
                                  fir_s, fir_l, mix, idlog, ctxb, entA);

  // output projection + entropy scalar
  conv_wt<<<dim3(32, 32), 256, 0, stream>>>(W_proj, wprojT, 1024, 1024, 0);
  gemm_mfma<0,0><<<dim3(8, 32), 256, 0, stream>>>(ctxb, wprojT, b_proj, out, BN_, 1024, 1024, 1024);
  ent_fin<<<1, 1, 0, stream>>>(entA, out + 4194304);
}

// Round 10
// 302.883 us; speedup vs baseline: 4.5077x; 1.0965x over previous
//
#include <hip/hip_runtime.h>
#include <math.h>

#define B_ 4
#define N_ 1024
#define C_ 1024
#define H_ 16
#define D_ 64
#define P_ 5
#define BN_ (B_*N_)
#define TOK 8

typedef unsigned int u32;
typedef unsigned short u16;
typedef __attribute__((ext_vector_type(8))) short bf16x8;
typedef __attribute__((ext_vector_type(4))) float f32x4;

__device__ __forceinline__ float gelu_f(float x){
  float x3 = x*x*x;
  return 0.5f*x*(1.0f + tanhf(0.7978845608028654f*(x + 0.044715f*x3)));
}
__device__ __forceinline__ float sigmoid_f(float x){ return 1.0f/(1.0f+expf(-x)); }

__device__ __forceinline__ u16 f2bf(float f) {
  u32 u = __float_as_uint(f);
  u32 r = u + 0x7fffu + ((u >> 16) & 1u);
  return (u16)(r >> 16);
}
__device__ __forceinline__ float bf2f(u16 v){ return __uint_as_float(((u32)v) << 16); }

__device__ __forceinline__ void unpack8(uint4 v, float* f) {
  f[0]=bf2f((u16)v.x); f[1]=bf2f((u16)(v.x>>16));
  f[2]=bf2f((u16)v.y); f[3]=bf2f((u16)(v.y>>16));
  f[4]=bf2f((u16)v.z); f[5]=bf2f((u16)(v.z>>16));
  f[6]=bf2f((u16)v.w); f[7]=bf2f((u16)(v.w>>16));
}

__device__ __forceinline__ void gload16(const void* g, void* l) {
  __builtin_amdgcn_global_load_lds((const __attribute__((address_space(1))) u32*)g,
                                   (__attribute__((address_space(3))) u32*)l, 16, 0, 0);
}

// ---------------- fp32 -> bf16 elementwise cast (8 elems/thread) --------------
__global__ __launch_bounds__(256) void conv_bf16(const float* __restrict__ in,
    u16* __restrict__ out, int n8) {
  int i = blockIdx.x * 256 + threadIdx.x;
  if (i >= n8) return;
  const float4* p = (const float4*)in + (size_t)i * 2;
  float4 a = p[0], b = p[1];
  uint4 o;
  o.x = (u32)f2bf(a.x) | ((u32)f2bf(a.y) << 16);
  o.y = (u32)f2bf(a.z) | ((u32)f2bf(a.w) << 16);
  o.z = (u32)f2bf(b.x) | ((u32)f2bf(b.y) << 16);
  o.w = (u32)f2bf(b.z) | ((u32)f2bf(b.w) << 16);
  *(uint4*)(out + (size_t)i * 8) = o;
}

// ------- fp32 [K][Nn] -> bf16 [Nn][K] transpose cast, guarded, with row offset
__global__ __launch_bounds__(256) void conv_wt(const float* __restrict__ W,
    u16* __restrict__ Wt, int K, int Nn, int roff) {
  __shared__ float t[32][33];
  int c0 = blockIdx.x * 32, r0 = blockIdx.y * 32;
  int tx = threadIdx.x & 31, ty = threadIdx.x >> 5;
  #pragma unroll
  for (int i = 0; i < 4; ++i) {
    int r = ty + i * 8;
    t[r][tx] = (c0 + tx < Nn) ? W[(size_t)(r0 + r) * Nn + c0 + tx] : 0.f;
  }
  __syncthreads();
  #pragma unroll
  for (int i = 0; i < 4; ++i) {
    int r = ty + i * 8;
    if (c0 + r < Nn)
      Wt[(size_t)(roff + c0 + r) * K + r0 + tx] = f2bf(t[tx][r]);
  }
}

// --------- bias concat: cb1 = [b_gate(16) | b_prune(80) | 0], cb2 = [b_g2(80)|0]
__global__ void bias_cat(const float* __restrict__ bg, const float* __restrict__ bp,
    const float* __restrict__ bg2, float* __restrict__ cb1, float* __restrict__ cb2) {
  int t = threadIdx.x;
  if (t < 128) cb1[t] = (t < 16) ? bg[t] : (t < 96 ? bp[t - 16] : 0.f);
  else { int c = t - 128; cb2[c] = (c < 80) ? bg2[c] : 0.f; }
}

// ---------------- bf16 MFMA GEMM: C = A(M,K) @ Bt(Nn,K)^T (+bias, +gelu) ------
template<int ACT, int OBF>
__global__ __launch_bounds__(256) void gemm_mfma(const u16* __restrict__ A,
    const u16* __restrict__ Bt, const float* __restrict__ bias,
    float* __restrict__ Cout, int M, int Nn, int K, int Ns) {
  __shared__ __align__(16) u16 lA[128 * 32];
  __shared__ __align__(16) u16 lB[128 * 32];
  const int tid = threadIdx.x;
  const int lane = tid & 63, wid = tid >> 6;
  const int wr = wid >> 1, wc = wid & 1;
  const int r16 = lane & 15, kq = lane >> 4;
  const int row0 = blockIdx.y * 128, col0 = blockIdx.x * 128;
  const int c0 = wid * 2;
  const int srow = lane >> 2;
  const int skoff = (lane & 3) * 8;

  f32x4 acc[4][4] = {};
  for (int k0 = 0; k0 < K; k0 += 32) {
    #pragma unroll
    for (int s = 0; s < 2; ++s) {
      int c = c0 + s;
      int rt = c * 16 + srow;
      gload16(A  + (size_t)(row0 + rt) * K + k0 + skoff, &lA[c * 512]);
      gload16(Bt + (size_t)(col0 + rt) * K + k0 + skoff, &lB[c * 512]);
    }
    __syncthreads();
    bf16x8 af[4], bfv[4];
    #pragma unroll
    for (int m = 0; m < 4; ++m)
      af[m] = *(const bf16x8*)&lA[(wr * 64 + m * 16 + r16) * 32 + kq * 8];
    #pragma unroll
    for (int n = 0; n < 4; ++n)
      bfv[n] = *(const bf16x8*)&lB[(wc * 64 + n * 16 + r16) * 32 + kq * 8];
    #pragma unroll
    for (int m = 0; m < 4; ++m)
      #pragma unroll
      for (int n = 0; n < 4; ++n)
        acc[m][n] = __builtin_amdgcn_mfma_f32_16x16x32_bf16(af[m], bfv[n], acc[m][n], 0, 0, 0);
    __syncthreads();
  }
  #pragma unroll
  for (int n = 0; n < 4; ++n) {
    int col = col0 + wc * 64 + n * 16 + r16;
    if (col >= Ns) continue;
    float bs = bias ? bias[col] : 0.0f;
    #pragma unroll
    for (int m = 0; m < 4; ++m) {
      int rowb = row0 + wr * 64 + m * 16 + kq * 4;
      #pragma unroll
      for (int r = 0; r < 4; ++r) {
        float v = acc[m][n][r] + bs;
        if (ACT == 1) v = gelu_f(v);
        if (OBF) ((u16*)Cout)[(size_t)(rowb + r) * Ns + col] = f2bf(v);
        else     Cout[(size_t)(rowb + r) * Ns + col] = v;
      }
    }
  }
}

// ---------------- DeltaNet prep: norms from bf16 qkvi, M via MFMA, T' ---------
// qkvi row stride 4096 bf16 (q|k|v|id). Emits kb/qb (chunk-major bf16) and
// tb = T' = M^{-1} diag(beta) bf16.
__global__ __launch_bounds__(256) void delta_prep(const u16* __restrict__ qkvi,
    u16* __restrict__ kb, u16* __restrict__ tb, u16* __restrict__ qb) {
  const int bx = blockIdx.x;
  const int bh = bx >> 4, g = bx & 15;
  const int b = bh >> 4, h = bh & 15;
  const int n0 = g * 64;
  const int tid = threadIdx.x;
  __shared__ __align__(16) u16 sKb[64][72];
  __shared__ __align__(16) float sMT[64][68];  // M^T fp32, [c][r], upper zeroed
  __shared__ float sPart[64][8];
  __shared__ float sBeta[64];

  if (tid < 64) sBeta[tid] = 1.0f - 0.9f * (float)(n0 + tid) / 1023.0f;

  // thread = (row rr_, quarter qd): load 16 bf16 of q and k, norms in fp32
  const int rr_ = tid >> 2, qd = tid & 3;
  const size_t rowoff = ((size_t)b * N_ + n0 + rr_) * 4096 + h * 64 + qd * 16;
  uint4 k0 = *(const uint4*)(qkvi + rowoff + 1024);
  uint4 k1 = *(const uint4*)(qkvi + rowoff + 1024 + 8);
  uint4 q0 = *(const uint4*)(qkvi + rowoff);
  uint4 q1 = *(const uint4*)(qkvi + rowoff + 8);
  float kv[16], qv[16];
  unpack8(k0, kv); unpack8(k1, kv + 8);
  unpack8(q0, qv); unpack8(q1, qv + 8);
  float ks = 0.f, qs = 0.f;
  #pragma unroll
  for (int j = 0; j < 16; ++j) {
    ks = fmaf(kv[j], kv[j], ks);
    qs = fmaf(qv[j], qv[j], qs);
  }
  sPart[rr_][qd] = ks; sPart[rr_][4 + qd] = qs;
  __syncthreads();
  const float ksc = rsqrtf(sPart[rr_][0]+sPart[rr_][1]+sPart[rr_][2]+sPart[rr_][3] + 1e-6f);
  const float qsc = rsqrtf(sPart[rr_][4]+sPart[rr_][5]+sPart[rr_][6]+sPart[rr_][7] + 1e-6f) * 0.125f;
  const size_t cbase = (size_t)bx * 4096 + rr_ * 64 + qd * 16;
  uint4 ko0, ko1, qo0, qo1;
  u32 kw[8], qw[8];
  #pragma unroll
  for (int j2 = 0; j2 < 8; ++j2) {
    kw[j2] = (u32)f2bf(kv[2*j2] * ksc) | ((u32)f2bf(kv[2*j2+1] * ksc) << 16);
    qw[j2] = (u32)f2bf(qv[2*j2] * qsc) | ((u32)f2bf(qv[2*j2+1] * qsc) << 16);
  }
  ko0 = make_uint4(kw[0], kw[1], kw[2], kw[3]); ko1 = make_uint4(kw[4], kw[5], kw[6], kw[7]);
  qo0 = make_uint4(qw[0], qw[1], qw[2], qw[3]); qo1 = make_uint4(qw[4], qw[5], qw[6], qw[7]);
  *(uint4*)(kb + cbase) = ko0; *(uint4*)(kb + cbase + 8) = ko1;
  *(uint4*)(qb + cbase) = qo0; *(uint4*)(qb + cbase + 8) = qo1;
  *(uint4*)&sKb[rr_][qd * 16] = ko0; *(uint4*)&sKb[rr_][qd * 16 + 8] = ko1;
  __syncthreads();

  // M^T via MFMA: M[r][c] = beta_r * khat_r . khat_c (r>c else 0), store [c][r]
  {
    const int lane = tid & 63, wv = tid >> 6;
    const int l15 = lane & 15, l4 = lane >> 4;
    bf16x8 ka0 = *(const bf16x8*)&sKb[16*wv + l15][l4*8];
    bf16x8 ka1 = *(const bf16x8*)&sKb[16*wv + l15][32 + l4*8];
    #pragma unroll
    for (int ct = 0; ct < 4; ++ct) {
      bf16x8 kc0 = *(const bf16x8*)&sKb[ct*16 + l15][l4*8];
      bf16x8 kc1 = *(const bf16x8*)&sKb[ct*16 + l15][32 + l4*8];
      f32x4 m = {};
      m = __builtin_amdgcn_mfma_f32_16x16x32_bf16(ka0, kc0, m, 0, 0, 0);
      m = __builtin_amdgcn_mfma_f32_16x16x32_bf16(ka1, kc1, m, 0, 0, 0);
      const int c = ct*16 + l15, rbase = 16*wv + l4*4;
      float4 o;
      o.x = (rbase+0 > c) ? sBeta[rbase+0] * m[0] : 0.f;
      o.y = (rbase+1 > c) ? sBeta[rbase+1] * m[1] : 0.f;
      o.z = (rbase+2 > c) ? sBeta[rbase+2] * m[2] : 0.f;
      o.w = (rbase+3 > c) ? sBeta[rbase+3] * m[3] : 0.f;
      *(float4*)&sMT[c][rbase] = o;
    }
  }
  __syncthreads();

  // T' solve: thread c in [0,64): forward-substitute e_c, triangular-blocked
  if (tid < 64) {
    const int c = tid;
    float a[64];
    #pragma unroll
    for (int i = 0; i < 64; ++i) a[i] = (i == c) ? 1.f : 0.f;
    #pragma unroll
    for (int ib = 0; ib < 4; ++ib) {
      #pragma unroll
      for (int i2 = 0; i2 < 16; ++i2) {
        const int i = ib * 16 + i2;
        const float wi = a[i];
        #pragma unroll
        for (int j4 = ib * 4; j4 < 16; ++j4) {
          const float4 m = *(const float4*)&sMT[i][j4 * 4];  // broadcast read
          a[j4*4+0] = fmaf(-m.x, wi, a[j4*4+0]);
          a[j4*4+1] = fmaf(-m.y, wi, a[j4*4+1]);
          a[j4*4+2] = fmaf(-m.z, wi, a[j4*4+2]);
          a[j4*4+3] = fmaf(-m.w, wi, a[j4*4+3]);
        }
      }
    }
    const float bc = sBeta[c];
    const size_t obase = (size_t)bx * 4096;
    #pragma unroll
    for (int i = 0; i < 64; ++i) tb[obase + i * 64 + c] = f2bf(a[i] * bc);
  }
}

// -------- DeltaNet fused scan+output: one block per (b,h), S in MFMA accs -----
// v read directly from qkvi (bf16, stride 4096, offset 2048).
__global__ __launch_bounds__(256, 1) void delta_fused(const u16* __restrict__ kb,
    const u16* __restrict__ tb, const u16* __restrict__ qb,
    const u16* __restrict__ qkvi, u16* __restrict__ dOutb) {
  const int bh = blockIdx.x;
  const int b = bh >> 4, h = bh & 15;
  const int tid = threadIdx.x;
  const int lane = tid & 63, wv = tid >> 6;
  const int l15 = lane & 15, l4 = lane >> 4;
  const int fr = tid >> 2, fe0 = (tid & 3) * 16;

  __shared__ __align__(16) u16 sK [64][72];   // khat   [c][dk]
  __shared__ __align__(16) u16 sKT[64][72];   // khat^T [dk][c]
  __shared__ __align__(16) u16 sT [64][72];   // T'     [c][j]
  __shared__ __align__(16) u16 sQ [64][72];   // qhat   [r][dk]
  __shared__ __align__(16) u16 sV [64][72];   // v      [c][dv]
  __shared__ __align__(16) u16 sSt[64][72];   // S^T    [dv][dk]
  __shared__ __align__(16) u16 sYt[64][72];   // Y^T    [dv][c]
  __shared__ __align__(16) u16 sUt[64][72];   // u_adj^T[dv][c]
  __shared__ __align__(16) u16 sA [64][72];   // attn   [r][c]

  f32x4 Sacc[4] = {};   // S[dk = 16wv+l4*4+j][dv = dt*16+l15]

  uint4 pk0, pk1, pt0, pt1, pq0, pq1, pv0, pv1;
  {
    const size_t bs = (size_t)(bh * 16) * 4096;
    const size_t vrow = ((size_t)(b * 1024 + fr)) * 4096 + 2048 + h * 64 + fe0;
    pk0 = *(const uint4*)(kb + bs + tid*16); pk1 = *(const uint4*)(kb + bs + tid*16 + 8);
    pt0 = *(const uint4*)(tb + bs + tid*16); pt1 = *(const uint4*)(tb + bs + tid*16 + 8);
    pq0 = *(const uint4*)(qb + bs + tid*16); pq1 = *(const uint4*)(qb + bs + tid*16 + 8);
    pv0 = *(const uint4*)(qkvi + vrow);      pv1 = *(const uint4*)(qkvi + vrow + 8);
  }

  for (int g = 0; g < 16; ++g) {
    __syncthreads();                           // BAR_A: prev phase reads done
    *(uint4*)&sK[fr][fe0] = pk0; *(uint4*)&sK[fr][fe0+8] = pk1;
    *(uint4*)&sT[fr][fe0] = pt0; *(uint4*)&sT[fr][fe0+8] = pt1;
    *(uint4*)&sQ[fr][fe0] = pq0; *(uint4*)&sQ[fr][fe0+8] = pq1;
    *(uint4*)&sV[fr][fe0] = pv0; *(uint4*)&sV[fr][fe0+8] = pv1;
    {
      u32 kk[8] = {pk0.x, pk0.y, pk0.z, pk0.w, pk1.x, pk1.y, pk1.z, pk1.w};
      #pragma unroll
      for (int i = 0; i < 8; ++i) {
        sKT[fe0 + 2*i][fr]     = (u16)kk[i];
        sKT[fe0 + 2*i + 1][fr] = (u16)(kk[i] >> 16);
      }
    }
    #pragma unroll
    for (int dt = 0; dt < 4; ++dt) {
      u32 lo = (u32)f2bf(Sacc[dt][0]) | ((u32)f2bf(Sacc[dt][1]) << 16);
      u32 hi = (u32)f2bf(Sacc[dt][2]) | ((u32)f2bf(Sacc[dt][3]) << 16);
      *(u32*)&sSt[dt*16 + l15][16*wv + l4*4]     = lo;
      *(u32*)&sSt[dt*16 + l15][16*wv + l4*4 + 2] = hi;
    }
    __syncthreads();                           // BAR_B: LDS ready
    if (g < 15) {
      const size_t bs = (size_t)(bh * 16 + g + 1) * 4096;
      const size_t vrow = ((size_t)(b * 1024 + (g + 1) * 64 + fr)) * 4096 + 2048 + h * 64 + fe0;
      pk0 = *(const uint4*)(kb + bs + tid*16); pk1 = *(const uint4*)(kb + bs + tid*16 + 8);
      pt0 = *(const uint4*)(tb + bs + tid*16); pt1 = *(const uint4*)(tb + bs + tid*16 + 8);
      pq0 = *(const uint4*)(qb + bs + tid*16); pq1 = *(const uint4*)(qb + bs + tid*16 + 8);
      pv0 = *(const uint4*)(qkvi + vrow);      pv1 = *(const uint4*)(qkvi + vrow + 8);
    }
    // ---- phase A: attn = q k^T ; Y = khat@S ; o1 = q@S ----
    bf16x8 qf0 = *(const bf16x8*)&sQ[16*wv + l15][l4*8];
    bf16x8 qf1 = *(const bf16x8*)&sQ[16*wv + l15][32 + l4*8];
    bf16x8 kr0 = *(const bf16x8*)&sK[16*wv + l15][l4*8];
    bf16x8 kr1 = *(const bf16x8*)&sK[16*wv + l15][32 + l4*8];
    f32x4 aacc[4] = {}, yacc[4] = {}, oacc[4] = {};
    #pragma unroll
    for (int ct = 0; ct < 4; ++ct) {
      bf16x8 kc0 = *(const bf16x8*)&sK[ct*16 + l15][l4*8];
      bf16x8 kc1 = *(const bf16x8*)&sK[ct*16 + l15][32 + l4*8];
      aacc[ct] = __builtin_amdgcn_mfma_f32_16x16x32_bf16(qf0, kc0, aacc[ct], 0, 0, 0);
      aacc[ct] = __builtin_amdgcn_mfma_f32_16x16x32_bf16(qf1, kc1, aacc[ct], 0, 0, 0);
    }
    #pragma unroll
    for (int dt = 0; dt < 4; ++dt) {
      bf16x8 s0 = *(const bf16x8*)&sSt[dt*16 + l15][l4*8];
      bf16x8 s1 = *(const bf16x8*)&sSt[dt*16 + l15][32 + l4*8];
      yacc[dt] = __builtin_amdgcn_mfma_f32_16x16x32_bf16(kr0, s0, yacc[dt], 0, 0, 0);
      yacc[dt] = __builtin_amdgcn_mfma_f32_16x16x32_bf16(kr1, s1, yacc[dt], 0, 0, 0);
      oacc[dt] = __builtin_amdgcn_mfma_f32_16x16x32_bf16(qf0, s0, oacc[dt], 0, 0, 0);
      oacc[dt] = __builtin_amdgcn_mfma_f32_16x16x32_bf16(qf1, s1, oacc[dt], 0, 0, 0);
    }
    // Y^T = (v - khat@S)^T -> sYt bf16 ; attn -> sA (tril)
    #pragma unroll
    for (int dt = 0; dt < 4; ++dt) {
      float y0 = bf2f(sV[16*wv + l4*4 + 0][dt*16 + l15]) - yacc[dt][0];
      float y1 = bf2f(sV[16*wv + l4*4 + 1][dt*16 + l15]) - yacc[dt][1];
      float y2 = bf2f(sV[16*wv + l4*4 + 2][dt*16 + l15]) - yacc[dt][2];
      float y3 = bf2f(sV[16*wv + l4*4 + 3][dt*16 + l15]) - yacc[dt][3];
      u32 lo = (u32)f2bf(y0) | ((u32)f2bf(y1) << 16);
      u32 hi = (u32)f2bf(y2) | ((u32)f2bf(y3) << 16);
      *(u32*)&sYt[dt*16 + l15][16*wv + l4*4]     = lo;
      *(u32*)&sYt[dt*16 + l15][16*wv + l4*4 + 2] = hi;
    }
    #pragma unroll
    for (int ct = 0; ct < 4; ++ct)
      #pragma unroll
      for (int j = 0; j < 4; ++j) {
        int r = 16*wv + l4*4 + j, c = ct*16 + l15;
        sA[r][c] = f2bf((r >= c) ? aacc[ct][j] : 0.f);
      }
    __syncthreads();                           // BAR_C: sYt/sA visible
    // ---- phase B1: u_adj = T' @ Y ----
    bf16x8 tf0 = *(const bf16x8*)&sT[16*wv + l15][l4*8];
    bf16x8 tf1 = *(const bf16x8*)&sT[16*wv + l15][32 + l4*8];
    f32x4 uacc[4] = {};
    #pragma unroll
    for (int dt = 0; dt < 4; ++dt) {
      bf16x8 y0 = *(const bf16x8*)&sYt[dt*16 + l15][l4*8];
      bf16x8 y1 = *(const bf16x8*)&sYt[dt*16 + l15][32 + l4*8];
      uacc[dt] = __builtin_amdgcn_mfma_f32_16x16x32_bf16(tf0, y0, uacc[dt], 0, 0, 0);
      uacc[dt] = __builtin_amdgcn_mfma_f32_16x16x32_bf16(tf1, y1, uacc[dt], 0, 0, 0);
    }
    #pragma unroll
    for (int dt = 0; dt < 4; ++dt) {
      u32 lo = (u32)f2bf(uacc[dt][0]) | ((u32)f2bf(uacc[dt][1]) << 16);
      u32 hi = (u32)f2bf(uacc[dt][2]) | ((u32)f2bf(uacc[dt][3]) << 16);
      *(u32*)&sUt[dt*16 + l15][16*wv + l4*4]     = lo;
      *(u32*)&sUt[dt*16 + l15][16*wv + l4*4 + 2] = hi;
    }
    __syncthreads();                           // BAR_D: sUt visible
    // ---- phase B2: o += attn@u_adj ; S += khat^T@u_adj ----
    bf16x8 af0 = *(const bf16x8*)&sA[16*wv + l15][l4*8];
    bf16x8 af1 = *(const bf16x8*)&sA[16*wv + l15][32 + l4*8];
    bf16x8 kt0 = *(const bf16x8*)&sKT[16*wv + l15][l4*8];
    bf16x8 kt1 = *(const bf16x8*)&sKT[16*wv + l15][32 + l4*8];
    #pragma unroll
    for (int dt = 0; dt < 4; ++dt) {
      bf16x8 u0 = *(const bf16x8*)&sUt[dt*16 + l15][l4*8];
      bf16x8 u1 = *(const bf16x8*)&sUt[dt*16 + l15][32 + l4*8];
      oacc[dt] = __builtin_amdgcn_mfma_f32_16x16x32_bf16(af0, u0, oacc[dt], 0, 0, 0);
      oacc[dt] = __builtin_amdgcn_mfma_f32_16x16x32_bf16(af1, u1, oacc[dt], 0, 0, 0);
      Sacc[dt] = __builtin_amdgcn_mfma_f32_16x16x32_bf16(kt0, u0, Sacc[dt], 0, 0, 0);
      Sacc[dt] = __builtin_amdgcn_mfma_f32_16x16x32_bf16(kt1, u1, Sacc[dt], 0, 0, 0);
    }
    #pragma unroll
    for (int dt = 0; dt < 4; ++dt)
      #pragma unroll
      for (int j = 0; j < 4; ++j) {
        int r = 16*wv + l4*4 + j;
        dOutb[((size_t)(b * 1024 + g * 64 + r)) * 1024 + h * 64 + dt*16 + l15] = f2bf(oacc[dt][j]);
      }
  }
}

// ------- fused FIR + mix + gating + ctx, 8 tokens/block, bf16 qkvi ------------
__global__ __launch_bounds__(256) void paths2(const u16* __restrict__ qkvi,
    const u16* __restrict__ dOutb, const float* __restrict__ gp,
    const float* __restrict__ g2L, const float* __restrict__ fir_s,
    const float* __restrict__ fir_l, const float* __restrict__ mix,
    const float* __restrict__ idlog, u16* __restrict__ ctxb,
    float* __restrict__ entAcc) {
  const int bid = ((blockIdx.x & 7) << 6) | (blockIdx.x >> 3);  // XCD-contiguous
  const int b = bid >> 7, n0 = (bid & 127) * TOK;
  const int tid = threadIdx.x;
  __shared__ u16 sV[TOK + 6][1024];
  __shared__ u16 sFS[TOK][1024], sFL[TOK][1024];
  __shared__ float sMix[256];
  __shared__ float sWg[TOK][16][5];
  __shared__ float sIdg[TOK][16];
  __shared__ float sEnt[128];
  sMix[tid] = mix[tid];

  // stage V rows n0-6 .. n0+TOK-1 (bf16, 2 rows per pass)
  #pragma unroll
  for (int i = 0; i < 7; ++i) {
    int r = i * 2 + (tid >> 7);
    int t = n0 - 6 + r;
    int col = (tid & 127) * 8;
    uint4 v = make_uint4(0, 0, 0, 0);
    if (t >= 0)
      v = *(const uint4*)(qkvi + ((size_t)b * 1024 + t) * 4096 + 2048 + col);
    *(uint4*)&sV[r][col] = v;
  }

  if (tid < 128) {
    const int tok = tid >> 4, hh = tid & 15;
    const size_t bn = (size_t)b * 1024 + n0 + tok;
    float pl[5], lp[5];
    #pragma unroll
    for (int p = 0; p < 5; ++p) pl[p] = gp[bn * 96 + 16 + hh * 5 + p];
    float mx = pl[0];
    #pragma unroll
    for (int p = 1; p < 5; ++p) mx = fmaxf(mx, pl[p]);
    float s = 0.f;
    #pragma unroll
    for (int p = 0; p < 5; ++p) { pl[p] = expf(pl[p] - mx); s += pl[p]; }
    float inv = 1.f / s, e1 = 0.f;
    #pragma unroll
    for (int p = 0; p < 5; ++p) {
      float prob = pl[p] * inv;
      lp[p] = logf(prob + 1e-8f);
      e1 -= prob * lp[p];
    }
    float gl[5];
    #pragma unroll
    for (int p = 0; p < 5; ++p) gl[p] = g2L[bn * 80 + hh * 5 + p] + lp[p];
    float mx2 = gl[0];
    #pragma unroll
    for (int p = 1; p < 5; ++p) mx2 = fmaxf(mx2, gl[p]);
    float s2 = 0.f;
    #pragma unroll
    for (int p = 0; p < 5; ++p) { gl[p] = expf(gl[p] - mx2); s2 += gl[p]; }
    float inv2 = 1.f / s2, e2 = 0.f;
    #pragma unroll
    for (int p = 0; p < 5; ++p) {
      float w = gl[p] * inv2;
      sWg[tok][hh][p] = w;
      e2 -= w * logf(w + 1e-8f);
    }
    sEnt[tid] = e1 + e2;
    sIdg[tok][hh] = sigmoid_f(gp[bn * 96 + hh]) * sigmoid_f(idlog[hh]);
  }
  __syncthreads();

  #pragma unroll
  for (int i = 0; i < 4; ++i) {
    const int idx = tid + i * 256;
    float fl7[7], fs3[3];
    #pragma unroll
    for (int j = 0; j < 7; ++j) fl7[j] = fir_l[(size_t)idx * 7 + j];
    #pragma unroll
    for (int j = 0; j < 3; ++j) fs3[j] = fir_s[(size_t)idx * 3 + j];
    #pragma unroll
    for (int tok = 0; tok < TOK; ++tok) {
      float accs = 0.f, accl = 0.f;
      #pragma unroll
      for (int j = 0; j < 7; ++j) {
        float vv = bf2f(sV[tok + j][idx]);
        accl = fmaf(fl7[j], vv, accl);
        if (j >= 4) accs = fmaf(fs3[j - 4], vv, accs);
      }
      sFS[tok][idx] = f2bf(accs);
      sFL[tok][idx] = f2bf(accl);
    }
  }
  __syncthreads();

  #pragma unroll
  for (int i = 0; i < 4; ++i) {
    const int idx = tid + i * 256;
    const int gg = idx >> 6, d = idx & 63;
    #pragma unroll
    for (int tok = 0; tok < TOK; ++tok) {
      float as = bf2f(sFS[tok][idx]), al = bf2f(sFL[tok][idx]);
      #pragma unroll
      for (int hh = 0; hh < 16; ++hh) {
        float m = sMix[hh * 16 + gg];
        as = fmaf(bf2f(sFS[tok][hh * 64 + d]), m, as);
        al = fmaf(bf2f(sFL[tok][hh * 64 + d]), m, al);
      }
      const size_t bn = (size_t)b * 1024 + n0 + tok;
      float w0 = sWg[tok][gg][0], w1 = sWg[tok][gg][1], w2 = sWg[tok][gg][2];
      float w3 = sWg[tok][gg][3], w4 = sWg[tok][gg][4];
      float dv = bf2f(dOutb[bn * 1024 + idx]);
      float vv = bf2f(sV[tok + 6][idx]);
      float iv = bf2f(qkvi[bn * 4096 + 3072 + idx]) * sIdg[tok][gg];
      ctxb[bn * 1024 + idx] = f2bf(w0*as + w1*al + w2*dv + w3*vv + w4*iv);
    }
  }
  if (tid == 0) {
    float s = 0.f;
    #pragma unroll
    for (int i = 0; i < 128; ++i) s += sEnt[i];
    atomicAdd(entAcc, s);
  }
}

__global__ void zero_ent(float* e) { e[0] = 0.f; }
__global__ void ent_fin(const float* __restrict__ e, float* __restrict__ dst) {
  dst[0] = e[0] * (1.0f / 65536.0f);
}

// ---------------- host launcher ----------------------------------------------
extern "C" void kernel_launch(void* const* d_in, const int* in_sizes, int n_in,
                              void* d_out, int out_size, void* d_ws, size_t ws_size,
                              hipStream_t stream) {
  (void)in_sizes; (void)n_in; (void)out_size; (void)ws_size;
  const float* x       = (const float*)d_in[0];
  const float* W_qkv   = (const float*)d_in[1];
  const float* W_id    = (const float*)d_in[2];
  const float* W_gate  = (const float*)d_in[3];
  const float* b_gate  = (const float*)d_in[4];
  const float* idlog   = (const float*)d_in[5];
  const float* fir_s   = (const float*)d_in[6];
  const float* fir_l   = (const float*)d_in[7];
  const float* mix     = (const float*)d_in[8];
  const float* W_prune = (const float*)d_in[9];
  const float* b_prune = (const float*)d_in[10];
  const float* W_g1    = (const float*)d_in[11];
  const float* b_g1    = (const float*)d_in[12];
  const float* W_g2    = (const float*)d_in[13];
  const float* b_g2    = (const float*)d_in[14];
  const float* W_proj  = (const float*)d_in[15];
  const float* b_proj  = (const float*)d_in[16];
  float* out = (float*)d_out;

  float* ws    = (float*)d_ws;
  float* qkviF = ws;                         // bf16 4096x4096 (8,388,608 fl)
  float* gp    = ws + 8388608;               // 4096 x 96 fp32
  float* g2l   = gp + 393216;                // 4096 x 80 fp32
  float* kbF   = g2l + 327680;               // bf16 chunk-major (2,097,152 fl)
  float* tbF   = kbF + 2097152;
  float* qbF   = tbF + 2097152;
  float* dOb   = qbF + 2097152;              // bf16 4096x1024
  float* entA  = dOb + 2097152;              // 1 fl
  float* cb1   = entA + 8;                   // 128 fl
  float* cb2   = cb1 + 128;                  // 128 fl

  u16* qkvi  = (u16*)qkviF;
  u16* kb16  = (u16*)kbF;
  u16* tb16  = (u16*)tbF;
  u16* qb16  = (u16*)qbF;
  u16* dOutb = (u16*)dOb;

  // pre-delta staging aliases (dead before their regions are overwritten)
  u16* xb     = kb16;                        // 4096x1024 bf16
  u16* wqT    = tb16;                        // 4096x1024 bf16 (W_qkv|W_id ^T)
  u16* wg1T   = qb16;                        // 1024x1024 bf16
  u16* catGP  = qb16 + 1048576;              // 128x1024 bf16
  u16* catG2  = qb16 + 1179648;              // 128x1024 bf16
  u16* hb16   = (u16*)dOb;                   // 4096x1024 bf16 (gelu out)
  // post-delta aliases
  u16* ctxb   = kb16;                        // kb dead after delta_fused
  u16* wprojT = tb16;                        // tb dead after delta_fused

  // casts + weight transposes
  conv_bf16<<<2048, 256, 0, stream>>>(x, xb, 524288);
  conv_wt<<<dim3(96, 32), 256, 0, stream>>>(W_qkv, wqT, 1024, 3072, 0);
  conv_wt<<<dim3(32, 32), 256, 0, stream>>>(W_id,  wqT, 1024, 1024, 3072);
  conv_wt<<<dim3(32, 32), 256, 0, stream>>>(W_g1,  wg1T, 1024, 1024, 0);
  conv_wt<<<dim3(1, 32),  256, 0, stream>>>(W_gate,  catGP, 1024, 16, 0);
  conv_wt<<<dim3(3, 32),  256, 0, stream>>>(W_prune, catGP, 1024, 80, 16);
  conv_wt<<<dim3(3, 32),  256, 0, stream>>>(W_g2,    catG2, 1024, 80, 0);
  hipMemsetAsync(catGP + 96 * 1024, 0, 32 * 1024 * sizeof(u16), stream);
  hipMemsetAsync(catG2 + 80 * 1024, 0, 48 * 1024 * sizeof(u16), stream);
  bias_cat<<<1, 256, 0, stream>>>(b_gate, b_prune, b_g2, cb1, cb2);

  // projections: fused qkv+id (bf16 out), gelu(g1) bf16 out, skinny gates
  gemm_mfma<0,1><<<dim3(32, 32), 256, 0, stream>>>(xb, wqT, nullptr, (float*)qkvi, BN_, 4096, 1024, 4096);
  gemm_mfma<1,1><<<dim3(8, 32), 256, 0, stream>>>(xb, wg1T, b_g1, (float*)hb16, BN_, 1024, 1024, 1024);
  gemm_mfma<0,0><<<dim3(1, 32), 256, 0, stream>>>(xb, catGP, cb1, gp, BN_, 128, 1024, 96);
  gemm_mfma<0,0><<<dim3(1, 32), 256, 0, stream>>>(hb16, catG2, cb2, g2l, BN_, 128, 1024, 80);

  // delta rule
  delta_prep<<<1024, 256, 0, stream>>>(qkvi, kb16, tb16, qb16);
  delta_fused<<<64, 256, 0, stream>>>(kb16, tb16, qb16, qkvi, dOutb);

  // fused paths + gating (8 tokens/block)
  zero_ent<<<1, 1, 0, stream>>>(entA);
  paths2<<<512, 256, 0, stream>>>(qkvi, dOutb, gp, g2l,
                                  fir_s, fir_l, mix, idlog, ctxb, entA);

  // output projection + entropy scalar
  conv_wt<<<dim3(32, 32), 256, 0, stream>>>(W_proj, wprojT, 1024, 1024, 0);
  gemm_mfma<0,0><<<dim3(8, 32), 256, 0, stream>>>(ctxb, wprojT, b_proj, out, BN_, 1024, 1024, 1024);
  ent_fin<<<1, 1, 0, stream>>>(entA, out + 4194304);
}

// Round 11
// 294.344 us; speedup vs baseline: 4.6385x; 1.0290x over previous
//
#include <hip/hip_runtime.h>
#include <math.h>

#define B_ 4
#define N_ 1024
#define C_ 1024
#define H_ 16
#define D_ 64
#define P_ 5
#define BN_ (B_*N_)
#define TOK 8

typedef unsigned int u32;
typedef unsigned short u16;
typedef __attribute__((ext_vector_type(8))) short bf16x8;
typedef __attribute__((ext_vector_type(4))) float f32x4;

__device__ __forceinline__ float gelu_f(float x){
  float x3 = x*x*x;
  return 0.5f*x*(1.0f + tanhf(0.7978845608028654f*(x + 0.044715f*x3)));
}
__device__ __forceinline__ float sigmoid_f(float x){ return 1.0f/(1.0f+expf(-x)); }

__device__ __forceinline__ u16 f2bf(float f) {
  u32 u = __float_as_uint(f);
  u32 r = u + 0x7fffu + ((u >> 16) & 1u);
  return (u16)(r >> 16);
}
__device__ __forceinline__ float bf2f(u16 v){ return __uint_as_float(((u32)v) << 16); }

__device__ __forceinline__ void unpack8(uint4 v, float* f) {
  f[0]=bf2f((u16)v.x); f[1]=bf2f((u16)(v.x>>16));
  f[2]=bf2f((u16)v.y); f[3]=bf2f((u16)(v.y>>16));
  f[4]=bf2f((u16)v.z); f[5]=bf2f((u16)(v.z>>16));
  f[6]=bf2f((u16)v.w); f[7]=bf2f((u16)(v.w>>16));
}

__device__ __forceinline__ void gload16(const void* g, void* l) {
  __builtin_amdgcn_global_load_lds((const __attribute__((address_space(1))) u32*)g,
                                   (__attribute__((address_space(3))) u32*)l, 16, 0, 0);
}

// ---------------- fp32 -> bf16 elementwise cast (8 elems/thread) --------------
__global__ __launch_bounds__(256) void conv_bf16(const float* __restrict__ in,
    u16* __restrict__ out, int n8) {
  int i = blockIdx.x * 256 + threadIdx.x;
  if (i >= n8) return;
  const float4* p = (const float4*)in + (size_t)i * 2;
  float4 a = p[0], b = p[1];
  uint4 o;
  o.x = (u32)f2bf(a.x) | ((u32)f2bf(a.y) << 16);
  o.y = (u32)f2bf(a.z) | ((u32)f2bf(a.w) << 16);
  o.z = (u32)f2bf(b.x) | ((u32)f2bf(b.y) << 16);
  o.w = (u32)f2bf(b.z) | ((u32)f2bf(b.w) << 16);
  *(uint4*)(out + (size_t)i * 8) = o;
}

// ------- fp32 [K][Nn] -> bf16 [Nn][K] transpose cast, guarded, with row offset
__global__ __launch_bounds__(256) void conv_wt(const float* __restrict__ W,
    u16* __restrict__ Wt, int K, int Nn, int roff) {
  __shared__ float t[32][33];
  int c0 = blockIdx.x * 32, r0 = blockIdx.y * 32;
  int tx = threadIdx.x & 31, ty = threadIdx.x >> 5;
  #pragma unroll
  for (int i = 0; i < 4; ++i) {
    int r = ty + i * 8;
    t[r][tx] = (c0 + tx < Nn) ? W[(size_t)(r0 + r) * Nn + c0 + tx] : 0.f;
  }
  __syncthreads();
  #pragma unroll
  for (int i = 0; i < 4; ++i) {
    int r = ty + i * 8;
    if (c0 + r < Nn)
      Wt[(size_t)(roff + c0 + r) * K + r0 + tx] = f2bf(t[tx][r]);
  }
}

// --------- bias concat: cb1 = [b_gate(16) | b_prune(80) | 0], cb2 = [b_g2(80)|0]
__global__ void bias_cat(const float* __restrict__ bg, const float* __restrict__ bp,
    const float* __restrict__ bg2, float* __restrict__ cb1, float* __restrict__ cb2) {
  int t = threadIdx.x;
  if (t < 128) cb1[t] = (t < 16) ? bg[t] : (t < 96 ? bp[t - 16] : 0.f);
  else { int c = t - 128; cb2[c] = (c < 80) ? bg2[c] : 0.f; }
}

// ---------------- bf16 MFMA GEMM, 3-buffer pipelined (counted vmcnt) ----------
// C = A(M,K) @ Bt(Nn,K)^T (+bias, +gelu). OBF=1: bf16 output.
template<int ACT, int OBF>
__global__ __launch_bounds__(256) void gemm_mfma(const u16* __restrict__ A,
    const u16* __restrict__ Bt, const float* __restrict__ bias,
    float* __restrict__ Cout, int M, int Nn, int K, int Ns) {
  __shared__ __align__(16) u16 lA[3][128 * 32];
  __shared__ __align__(16) u16 lB[3][128 * 32];
  const int tid = threadIdx.x;
  const int lane = tid & 63, wid = tid >> 6;
  const int wr = wid >> 1, wc = wid & 1;
  const int r16 = lane & 15, kq = lane >> 4;
  const int row0 = blockIdx.y * 128, col0 = blockIdx.x * 128;
  const int c0 = wid * 2;
  const int srow = lane >> 2;
  const int skoff = (lane & 3) * 8;
  const int T = K >> 5;

  // stage tile tk (k0 = tk*32) into buffer buf: 4 gload_lds per thread
  #define STAGE_T(buf, tk) { \
    const int k0_ = (tk) << 5; \
    _Pragma("unroll") \
    for (int s = 0; s < 2; ++s) { \
      int c = c0 + s; \
      int rt = c * 16 + srow; \
      gload16(A  + (size_t)(row0 + rt) * K + k0_ + skoff, &lA[buf][c * 512]); \
      gload16(Bt + (size_t)(col0 + rt) * K + k0_ + skoff, &lB[buf][c * 512]); \
    } }

  f32x4 acc[4][4] = {};
  STAGE_T(0, 0);
  if (T > 1) STAGE_T(1, 1);

  for (int t = 0; t < T; ++t) {
    // head fence: tile t landed for THIS wave; barrier makes it true for all.
    if (t < T - 1) asm volatile("s_waitcnt vmcnt(4)" ::: "memory");
    else           asm volatile("s_waitcnt vmcnt(0)" ::: "memory");
    __builtin_amdgcn_s_barrier();
    asm volatile("" ::: "memory");
    // stage tile t+2 into buf (t+2)%3 (last read at iter t-1, pre-barrier)
    if (t + 2 < T) { const int bnx = (t + 2) % 3; STAGE_T(bnx, t + 2); }
    // compute on buf t%3
    const int bc = t % 3;
    bf16x8 af[4], bfv[4];
    #pragma unroll
    for (int m = 0; m < 4; ++m)
      af[m] = *(const bf16x8*)&lA[bc][(wr * 64 + m * 16 + r16) * 32 + kq * 8];
    #pragma unroll
    for (int n = 0; n < 4; ++n)
      bfv[n] = *(const bf16x8*)&lB[bc][(wc * 64 + n * 16 + r16) * 32 + kq * 8];
    #pragma unroll
    for (int m = 0; m < 4; ++m)
      #pragma unroll
      for (int n = 0; n < 4; ++n)
        acc[m][n] = __builtin_amdgcn_mfma_f32_16x16x32_bf16(af[m], bfv[n], acc[m][n], 0, 0, 0);
  }
  #undef STAGE_T

  #pragma unroll
  for (int n = 0; n < 4; ++n) {
    int col = col0 + wc * 64 + n * 16 + r16;
    if (col >= Ns) continue;
    float bs = bias ? bias[col] : 0.0f;
    #pragma unroll
    for (int m = 0; m < 4; ++m) {
      int rowb = row0 + wr * 64 + m * 16 + kq * 4;
      #pragma unroll
      for (int r = 0; r < 4; ++r) {
        float v = acc[m][n][r] + bs;
        if (ACT == 1) v = gelu_f(v);
        if (OBF) ((u16*)Cout)[(size_t)(rowb + r) * Ns + col] = f2bf(v);
        else     Cout[(size_t)(rowb + r) * Ns + col] = v;
      }
    }
  }
}

// ---------------- DeltaNet prep: norms from bf16 qkvi, M via MFMA, T' ---------
__global__ __launch_bounds__(256) void delta_prep(const u16* __restrict__ qkvi,
    u16* __restrict__ kb, u16* __restrict__ tb, u16* __restrict__ qb) {
  const int bx = blockIdx.x;
  const int bh = bx >> 4, g = bx & 15;
  const int b = bh >> 4, h = bh & 15;
  const int n0 = g * 64;
  const int tid = threadIdx.x;
  __shared__ __align__(16) u16 sKb[64][72];
  __shared__ __align__(16) float sMT[64][68];  // M^T fp32, [c][r], upper zeroed
  __shared__ float sPart[64][8];
  __shared__ float sBeta[64];

  if (tid < 64) sBeta[tid] = 1.0f - 0.9f * (float)(n0 + tid) / 1023.0f;

  const int rr_ = tid >> 2, qd = tid & 3;
  const size_t rowoff = ((size_t)b * N_ + n0 + rr_) * 4096 + h * 64 + qd * 16;
  uint4 k0 = *(const uint4*)(qkvi + rowoff + 1024);
  uint4 k1 = *(const uint4*)(qkvi + rowoff + 1024 + 8);
  uint4 q0 = *(const uint4*)(qkvi + rowoff);
  uint4 q1 = *(const uint4*)(qkvi + rowoff + 8);
  float kv[16], qv[16];
  unpack8(k0, kv); unpack8(k1, kv + 8);
  unpack8(q0, qv); unpack8(q1, qv + 8);
  float ks = 0.f, qs = 0.f;
  #pragma unroll
  for (int j = 0; j < 16; ++j) {
    ks = fmaf(kv[j], kv[j], ks);
    qs = fmaf(qv[j], qv[j], qs);
  }
  sPart[rr_][qd] = ks; sPart[rr_][4 + qd] = qs;
  __syncthreads();
  const float ksc = rsqrtf(sPart[rr_][0]+sPart[rr_][1]+sPart[rr_][2]+sPart[rr_][3] + 1e-6f);
  const float qsc = rsqrtf(sPart[rr_][4]+sPart[rr_][5]+sPart[rr_][6]+sPart[rr_][7] + 1e-6f) * 0.125f;
  const size_t cbase = (size_t)bx * 4096 + rr_ * 64 + qd * 16;
  uint4 ko0, ko1, qo0, qo1;
  u32 kw[8], qw[8];
  #pragma unroll
  for (int j2 = 0; j2 < 8; ++j2) {
    kw[j2] = (u32)f2bf(kv[2*j2] * ksc) | ((u32)f2bf(kv[2*j2+1] * ksc) << 16);
    qw[j2] = (u32)f2bf(qv[2*j2] * qsc) | ((u32)f2bf(qv[2*j2+1] * qsc) << 16);
  }
  ko0 = make_uint4(kw[0], kw[1], kw[2], kw[3]); ko1 = make_uint4(kw[4], kw[5], kw[6], kw[7]);
  qo0 = make_uint4(qw[0], qw[1], qw[2], qw[3]); qo1 = make_uint4(qw[4], qw[5], qw[6], qw[7]);
  *(uint4*)(kb + cbase) = ko0; *(uint4*)(kb + cbase + 8) = ko1;
  *(uint4*)(qb + cbase) = qo0; *(uint4*)(qb + cbase + 8) = qo1;
  *(uint4*)&sKb[rr_][qd * 16] = ko0; *(uint4*)&sKb[rr_][qd * 16 + 8] = ko1;
  __syncthreads();

  {
    const int lane = tid & 63, wv = tid >> 6;
    const int l15 = lane & 15, l4 = lane >> 4;
    bf16x8 ka0 = *(const bf16x8*)&sKb[16*wv + l15][l4*8];
    bf16x8 ka1 = *(const bf16x8*)&sKb[16*wv + l15][32 + l4*8];
    #pragma unroll
    for (int ct = 0; ct < 4; ++ct) {
      bf16x8 kc0 = *(const bf16x8*)&sKb[ct*16 + l15][l4*8];
      bf16x8 kc1 = *(const bf16x8*)&sKb[ct*16 + l15][32 + l4*8];
      f32x4 m = {};
      m = __builtin_amdgcn_mfma_f32_16x16x32_bf16(ka0, kc0, m, 0, 0, 0);
      m = __builtin_amdgcn_mfma_f32_16x16x32_bf16(ka1, kc1, m, 0, 0, 0);
      const int c = ct*16 + l15, rbase = 16*wv + l4*4;
      float4 o;
      o.x = (rbase+0 > c) ? sBeta[rbase+0] * m[0] : 0.f;
      o.y = (rbase+1 > c) ? sBeta[rbase+1] * m[1] : 0.f;
      o.z = (rbase+2 > c) ? sBeta[rbase+2] * m[2] : 0.f;
      o.w = (rbase+3 > c) ? sBeta[rbase+3] * m[3] : 0.f;
      *(float4*)&sMT[c][rbase] = o;
    }
  }
  __syncthreads();

  if (tid < 64) {
    const int c = tid;
    float a[64];
    #pragma unroll
    for (int i = 0; i < 64; ++i) a[i] = (i == c) ? 1.f : 0.f;
    #pragma unroll
    for (int ib = 0; ib < 4; ++ib) {
      #pragma unroll
      for (int i2 = 0; i2 < 16; ++i2) {
        const int i = ib * 16 + i2;
        const float wi = a[i];
        #pragma unroll
        for (int j4 = ib * 4; j4 < 16; ++j4) {
          const float4 m = *(const float4*)&sMT[i][j4 * 4];  // broadcast read
          a[j4*4+0] = fmaf(-m.x, wi, a[j4*4+0]);
          a[j4*4+1] = fmaf(-m.y, wi, a[j4*4+1]);
          a[j4*4+2] = fmaf(-m.z, wi, a[j4*4+2]);
          a[j4*4+3] = fmaf(-m.w, wi, a[j4*4+3]);
        }
      }
    }
    const float bc = sBeta[c];
    const size_t obase = (size_t)bx * 4096;
    #pragma unroll
    for (int i = 0; i < 64; ++i) tb[obase + i * 64 + c] = f2bf(a[i] * bc);
  }
}

// -------- DeltaNet fused scan+output: one block per (b,h), S in MFMA accs -----
__global__ __launch_bounds__(256, 1) void delta_fused(const u16* __restrict__ kb,
    const u16* __restrict__ tb, const u16* __restrict__ qb,
    const u16* __restrict__ qkvi, u16* __restrict__ dOutb) {
  const int bh = blockIdx.x;
  const int b = bh >> 4, h = bh & 15;
  const int tid = threadIdx.x;
  const int lane = tid & 63, wv = tid >> 6;
  const int l15 = lane & 15, l4 = lane >> 4;
  const int fr = tid >> 2, fe0 = (tid & 3) * 16;

  __shared__ __align__(16) u16 sK [64][72];
  __shared__ __align__(16) u16 sKT[64][72];
  __shared__ __align__(16) u16 sT [64][72];
  __shared__ __align__(16) u16 sQ [64][72];
  __shared__ __align__(16) u16 sV [64][72];
  __shared__ __align__(16) u16 sSt[64][72];
  __shared__ __align__(16) u16 sYt[64][72];
  __shared__ __align__(16) u16 sUt[64][72];
  __shared__ __align__(16) u16 sA [64][72];

  f32x4 Sacc[4] = {};

  uint4 pk0, pk1, pt0, pt1, pq0, pq1, pv0, pv1;
  {
    const size_t bs = (size_t)(bh * 16) * 4096;
    const size_t vrow = ((size_t)(b * 1024 + fr)) * 4096 + 2048 + h * 64 + fe0;
    pk0 = *(const uint4*)(kb + bs + tid*16); pk1 = *(const uint4*)(kb + bs + tid*16 + 8);
    pt0 = *(const uint4*)(tb + bs + tid*16); pt1 = *(const uint4*)(tb + bs + tid*16 + 8);
    pq0 = *(const uint4*)(qb + bs + tid*16); pq1 = *(const uint4*)(qb + bs + tid*16 + 8);
    pv0 = *(const uint4*)(qkvi + vrow);      pv1 = *(const uint4*)(qkvi + vrow + 8);
  }

  for (int g = 0; g < 16; ++g) {
    __syncthreads();
    *(uint4*)&sK[fr][fe0] = pk0; *(uint4*)&sK[fr][fe0+8] = pk1;
    *(uint4*)&sT[fr][fe0] = pt0; *(uint4*)&sT[fr][fe0+8] = pt1;
    *(uint4*)&sQ[fr][fe0] = pq0; *(uint4*)&sQ[fr][fe0+8] = pq1;
    *(uint4*)&sV[fr][fe0] = pv0; *(uint4*)&sV[fr][fe0+8] = pv1;
    {
      u32 kk[8] = {pk0.x, pk0.y, pk0.z, pk0.w, pk1.x, pk1.y, pk1.z, pk1.w};
      #pragma unroll
      for (int i = 0; i < 8; ++i) {
        sKT[fe0 + 2*i][fr]     = (u16)kk[i];
        sKT[fe0 + 2*i + 1][fr] = (u16)(kk[i] >> 16);
      }
    }
    #pragma unroll
    for (int dt = 0; dt < 4; ++dt) {
      u32 lo = (u32)f2bf(Sacc[dt][0]) | ((u32)f2bf(Sacc[dt][1]) << 16);
      u32 hi = (u32)f2bf(Sacc[dt][2]) | ((u32)f2bf(Sacc[dt][3]) << 16);
      *(u32*)&sSt[dt*16 + l15][16*wv + l4*4]     = lo;
      *(u32*)&sSt[dt*16 + l15][16*wv + l4*4 + 2] = hi;
    }
    __syncthreads();
    if (g < 15) {
      const size_t bs = (size_t)(bh * 16 + g + 1) * 4096;
      const size_t vrow = ((size_t)(b * 1024 + (g + 1) * 64 + fr)) * 4096 + 2048 + h * 64 + fe0;
      pk0 = *(const uint4*)(kb + bs + tid*16); pk1 = *(const uint4*)(kb + bs + tid*16 + 8);
      pt0 = *(const uint4*)(tb + bs + tid*16); pt1 = *(const uint4*)(tb + bs + tid*16 + 8);
      pq0 = *(const uint4*)(qb + bs + tid*16); pq1 = *(const uint4*)(qb + bs + tid*16 + 8);
      pv0 = *(const uint4*)(qkvi + vrow);      pv1 = *(const uint4*)(qkvi + vrow + 8);
    }
    bf16x8 qf0 = *(const bf16x8*)&sQ[16*wv + l15][l4*8];
    bf16x8 qf1 = *(const bf16x8*)&sQ[16*wv + l15][32 + l4*8];
    bf16x8 kr0 = *(const bf16x8*)&sK[16*wv + l15][l4*8];
    bf16x8 kr1 = *(const bf16x8*)&sK[16*wv + l15][32 + l4*8];
    f32x4 aacc[4] = {}, yacc[4] = {}, oacc[4] = {};
    #pragma unroll
    for (int ct = 0; ct < 4; ++ct) {
      bf16x8 kc0 = *(const bf16x8*)&sK[ct*16 + l15][l4*8];
      bf16x8 kc1 = *(const bf16x8*)&sK[ct*16 + l15][32 + l4*8];
      aacc[ct] = __builtin_amdgcn_mfma_f32_16x16x32_bf16(qf0, kc0, aacc[ct], 0, 0, 0);
      aacc[ct] = __builtin_amdgcn_mfma_f32_16x16x32_bf16(qf1, kc1, aacc[ct], 0, 0, 0);
    }
    #pragma unroll
    for (int dt = 0; dt < 4; ++dt) {
      bf16x8 s0 = *(const bf16x8*)&sSt[dt*16 + l15][l4*8];
      bf16x8 s1 = *(const bf16x8*)&sSt[dt*16 + l15][32 + l4*8];
      yacc[dt] = __builtin_amdgcn_mfma_f32_16x16x32_bf16(kr0, s0, yacc[dt], 0, 0, 0);
      yacc[dt] = __builtin_amdgcn_mfma_f32_16x16x32_bf16(kr1, s1, yacc[dt], 0, 0, 0);
      oacc[dt] = __builtin_amdgcn_mfma_f32_16x16x32_bf16(qf0, s0, oacc[dt], 0, 0, 0);
      oacc[dt] = __builtin_amdgcn_mfma_f32_16x16x32_bf16(qf1, s1, oacc[dt], 0, 0, 0);
    }
    #pragma unroll
    for (int dt = 0; dt < 4; ++dt) {
      float y0 = bf2f(sV[16*wv + l4*4 + 0][dt*16 + l15]) - yacc[dt][0];
      float y1 = bf2f(sV[16*wv + l4*4 + 1][dt*16 + l15]) - yacc[dt][1];
      float y2 = bf2f(sV[16*wv + l4*4 + 2][dt*16 + l15]) - yacc[dt][2];
      float y3 = bf2f(sV[16*wv + l4*4 + 3][dt*16 + l15]) - yacc[dt][3];
      u32 lo = (u32)f2bf(y0) | ((u32)f2bf(y1) << 16);
      u32 hi = (u32)f2bf(y2) | ((u32)f2bf(y3) << 16);
      *(u32*)&sYt[dt*16 + l15][16*wv + l4*4]     = lo;
      *(u32*)&sYt[dt*16 + l15][16*wv + l4*4 + 2] = hi;
    }
    #pragma unroll
    for (int ct = 0; ct < 4; ++ct)
      #pragma unroll
      for (int j = 0; j < 4; ++j) {
        int r = 16*wv + l4*4 + j, c = ct*16 + l15;
        sA[r][c] = f2bf((r >= c) ? aacc[ct][j] : 0.f);
      }
    __syncthreads();
    bf16x8 tf0 = *(const bf16x8*)&sT[16*wv + l15][l4*8];
    bf16x8 tf1 = *(const bf16x8*)&sT[16*wv + l15][32 + l4*8];
    f32x4 uacc[4] = {};
    #pragma unroll
    for (int dt = 0; dt < 4; ++dt) {
      bf16x8 y0 = *(const bf16x8*)&sYt[dt*16 + l15][l4*8];
      bf16x8 y1 = *(const bf16x8*)&sYt[dt*16 + l15][32 + l4*8];
      uacc[dt] = __builtin_amdgcn_mfma_f32_16x16x32_bf16(tf0, y0, uacc[dt], 0, 0, 0);
      uacc[dt] = __builtin_amdgcn_mfma_f32_16x16x32_bf16(tf1, y1, uacc[dt], 0, 0, 0);
    }
    #pragma unroll
    for (int dt = 0; dt < 4; ++dt) {
      u32 lo = (u32)f2bf(uacc[dt][0]) | ((u32)f2bf(uacc[dt][1]) << 16);
      u32 hi = (u32)f2bf(uacc[dt][2]) | ((u32)f2bf(uacc[dt][3]) << 16);
      *(u32*)&sUt[dt*16 + l15][16*wv + l4*4]     = lo;
      *(u32*)&sUt[dt*16 + l15][16*wv + l4*4 + 2] = hi;
    }
    __syncthreads();
    bf16x8 af0 = *(const bf16x8*)&sA[16*wv + l15][l4*8];
    bf16x8 af1 = *(const bf16x8*)&sA[16*wv + l15][32 + l4*8];
    bf16x8 kt0 = *(const bf16x8*)&sKT[16*wv + l15][l4*8];
    bf16x8 kt1 = *(const bf16x8*)&sKT[16*wv + l15][32 + l4*8];
    #pragma unroll
    for (int dt = 0; dt < 4; ++dt) {
      bf16x8 u0 = *(const bf16x8*)&sUt[dt*16 + l15][l4*8];
      bf16x8 u1 = *(const bf16x8*)&sUt[dt*16 + l15][32 + l4*8];
      oacc[dt] = __builtin_amdgcn_mfma_f32_16x16x32_bf16(af0, u0, oacc[dt], 0, 0, 0);
      oacc[dt] = __builtin_amdgcn_mfma_f32_16x16x32_bf16(af1, u1, oacc[dt], 0, 0, 0);
      Sacc[dt] = __builtin_amdgcn_mfma_f32_16x16x32_bf16(kt0, u0, Sacc[dt], 0, 0, 0);
      Sacc[dt] = __builtin_amdgcn_mfma_f32_16x16x32_bf16(kt1, u1, Sacc[dt], 0, 0, 0);
    }
    #pragma unroll
    for (int dt = 0; dt < 4; ++dt)
      #pragma unroll
      for (int j = 0; j < 4; ++j) {
        int r = 16*wv + l4*4 + j;
        dOutb[((size_t)(b * 1024 + g * 64 + r)) * 1024 + h * 64 + dt*16 + l15] = f2bf(oacc[dt][j]);
      }
  }
}

// ------- fused FIR + mix + gating + ctx, 8 tokens/block, bf16 qkvi ------------
__global__ __launch_bounds__(256) void paths2(const u16* __restrict__ qkvi,
    const u16* __restrict__ dOutb, const float* __restrict__ gp,
    const float* __restrict__ g2L, const float* __restrict__ fir_s,
    const float* __restrict__ fir_l, const float* __restrict__ mix,
    const float* __restrict__ idlog, u16* __restrict__ ctxb,
    float* __restrict__ entAcc) {
  const int bid = ((blockIdx.x & 7) << 6) | (blockIdx.x >> 3);  // XCD-contiguous
  const int b = bid >> 7, n0 = (bid & 127) * TOK;
  const int tid = threadIdx.x;
  __shared__ u16 sV[TOK + 6][1024];
  __shared__ u16 sFS[TOK][1024], sFL[TOK][1024];
  __shared__ float sMix[256];
  __shared__ float sWg[TOK][16][5];
  __shared__ float sIdg[TOK][16];
  __shared__ float sEnt[128];
  sMix[tid] = mix[tid];

  #pragma unroll
  for (int i = 0; i < 7; ++i) {
    int r = i * 2 + (tid >> 7);
    int t = n0 - 6 + r;
    int col = (tid & 127) * 8;
    uint4 v = make_uint4(0, 0, 0, 0);
    if (t >= 0)
      v = *(const uint4*)(qkvi + ((size_t)b * 1024 + t) * 4096 + 2048 + col);
    *(uint4*)&sV[r][col] = v;
  }

  if (tid < 128) {
    const int tok = tid >> 4, hh = tid & 15;
    const size_t bn = (size_t)b * 1024 + n0 + tok;
    float pl[5], lp[5];
    #pragma unroll
    for (int p = 0; p < 5; ++p) pl[p] = gp[bn * 96 + 16 + hh * 5 + p];
    float mx = pl[0];
    #pragma unroll
    for (int p = 1; p < 5; ++p) mx = fmaxf(mx, pl[p]);
    float s = 0.f;
    #pragma unroll
    for (int p = 0; p < 5; ++p) { pl[p] = expf(pl[p] - mx); s += pl[p]; }
    float inv = 1.f / s, e1 = 0.f;
    #pragma unroll
    for (int p = 0; p < 5; ++p) {
      float prob = pl[p] * inv;
      lp[p] = logf(prob + 1e-8f);
      e1 -= prob * lp[p];
    }
    float gl[5];
    #pragma unroll
    for (int p = 0; p < 5; ++p) gl[p] = g2L[bn * 80 + hh * 5 + p] + lp[p];
    float mx2 = gl[0];
    #pragma unroll
    for (int p = 1; p < 5; ++p) mx2 = fmaxf(mx2, gl[p]);
    float s2 = 0.f;
    #pragma unroll
    for (int p = 0; p < 5; ++p) { gl[p] = expf(gl[p] - mx2); s2 += gl[p]; }
    float inv2 = 1.f / s2, e2 = 0.f;
    #pragma unroll
    for (int p = 0; p < 5; ++p) {
      float w = gl[p] * inv2;
      sWg[tok][hh][p] = w;
      e2 -= w * logf(w + 1e-8f);
    }
    sEnt[tid] = e1 + e2;
    sIdg[tok][hh] = sigmoid_f(gp[bn * 96 + hh]) * sigmoid_f(idlog[hh]);
  }
  __syncthreads();

  #pragma unroll
  for (int i = 0; i < 4; ++i) {
    const int idx = tid + i * 256;
    float fl7[7], fs3[3];
    #pragma unroll
    for (int j = 0; j < 7; ++j) fl7[j] = fir_l[(size_t)idx * 7 + j];
    #pragma unroll
    for (int j = 0; j < 3; ++j) fs3[j] = fir_s[(size_t)idx * 3 + j];
    #pragma unroll
    for (int tok = 0; tok < TOK; ++tok) {
      float accs = 0.f, accl = 0.f;
      #pragma unroll
      for (int j = 0; j < 7; ++j) {
        float vv = bf2f(sV[tok + j][idx]);
        accl = fmaf(fl7[j], vv, accl);
        if (j >= 4) accs = fmaf(fs3[j - 4], vv, accs);
      }
      sFS[tok][idx] = f2bf(accs);
      sFL[tok][idx] = f2bf(accl);
    }
  }
  __syncthreads();

  #pragma unroll
  for (int i = 0; i < 4; ++i) {
    const int idx = tid + i * 256;
    const int gg = idx >> 6, d = idx & 63;
    #pragma unroll
    for (int tok = 0; tok < TOK; ++tok) {
      float as = bf2f(sFS[tok][idx]), al = bf2f(sFL[tok][idx]);
      #pragma unroll
      for (int hh = 0; hh < 16; ++hh) {
        float m = sMix[hh * 16 + gg];
        as = fmaf(bf2f(sFS[tok][hh * 64 + d]), m, as);
        al = fmaf(bf2f(sFL[tok][hh * 64 + d]), m, al);
      }
      const size_t bn = (size_t)b * 1024 + n0 + tok;
      float w0 = sWg[tok][gg][0], w1 = sWg[tok][gg][1], w2 = sWg[tok][gg][2];
      float w3 = sWg[tok][gg][3], w4 = sWg[tok][gg][4];
      float dv = bf2f(dOutb[bn * 1024 + idx]);
      float vv = bf2f(sV[tok + 6][idx]);
      float iv = bf2f(qkvi[bn * 4096 + 3072 + idx]) * sIdg[tok][gg];
      ctxb[bn * 1024 + idx] = f2bf(w0*as + w1*al + w2*dv + w3*vv + w4*iv);
    }
  }
  if (tid == 0) {
    float s = 0.f;
    #pragma unroll
    for (int i = 0; i < 128; ++i) s += sEnt[i];
    atomicAdd(entAcc, s);
  }
}

__global__ void zero_ent(float* e) { e[0] = 0.f; }
__global__ void ent_fin(const float* __restrict__ e, float* __restrict__ dst) {
  dst[0] = e[0] * (1.0f / 65536.0f);
}

// ---------------- host launcher ----------------------------------------------
extern "C" void kernel_launch(void* const* d_in, const int* in_sizes, int n_in,
                              void* d_out, int out_size, void* d_ws, size_t ws_size,
                              hipStream_t stream) {
  (void)in_sizes; (void)n_in; (void)out_size; (void)ws_size;
  const float* x       = (const float*)d_in[0];
  const float* W_qkv   = (const float*)d_in[1];
  const float* W_id    = (const float*)d_in[2];
  const float* W_gate  = (const float*)d_in[3];
  const float* b_gate  = (const float*)d_in[4];
  const float* idlog   = (const float*)d_in[5];
  const float* fir_s   = (const float*)d_in[6];
  const float* fir_l   = (const float*)d_in[7];
  const float* mix     = (const float*)d_in[8];
  const float* W_prune = (const float*)d_in[9];
  const float* b_prune = (const float*)d_in[10];
  const float* W_g1    = (const float*)d_in[11];
  const float* b_g1    = (const float*)d_in[12];
  const float* W_g2    = (const float*)d_in[13];
  const float* b_g2    = (const float*)d_in[14];
  const float* W_proj  = (const float*)d_in[15];
  const float* b_proj  = (const float*)d_in[16];
  float* out = (float*)d_out;

  float* ws    = (float*)d_ws;
  float* qkviF = ws;                         // bf16 4096x4096 (8,388,608 fl)
  float* gp    = ws + 8388608;               // 4096 x 96 fp32
  float* g2l   = gp + 393216;                // 4096 x 80 fp32
  float* kbF   = g2l + 327680;               // bf16 chunk-major (2,097,152 fl)
  float* tbF   = kbF + 2097152;
  float* qbF   = tbF + 2097152;
  float* dOb   = qbF + 2097152;              // bf16 4096x1024
  float* entA  = dOb + 2097152;              // 1 fl
  float* cb1   = entA + 8;                   // 128 fl
  float* cb2   = cb1 + 128;                  // 128 fl

  u16* qkvi  = (u16*)qkviF;
  u16* kb16  = (u16*)kbF;
  u16* tb16  = (u16*)tbF;
  u16* qb16  = (u16*)qbF;
  u16* dOutb = (u16*)dOb;

  // pre-delta staging aliases (dead before their regions are overwritten)
  u16* xb     = kb16;                        // 4096x1024 bf16
  u16* wqT    = tb16;                        // 4096x1024 bf16 (W_qkv|W_id ^T)
  u16* wg1T   = qb16;                        // 1024x1024 bf16
  u16* catGP  = qb16 + 1048576;              // 128x1024 bf16
  u16* catG2  = qb16 + 1179648;              // 128x1024 bf16
  u16* hb16   = (u16*)dOb;                   // 4096x1024 bf16 (gelu out)
  // post-delta aliases
  u16* ctxb   = kb16;                        // kb dead after delta_fused
  u16* wprojT = tb16;                        // tb dead after delta_fused

  // casts + weight transposes
  conv_bf16<<<2048, 256, 0, stream>>>(x, xb, 524288);
  conv_wt<<<dim3(96, 32), 256, 0, stream>>>(W_qkv, wqT, 1024, 3072, 0);
  conv_wt<<<dim3(32, 32), 256, 0, stream>>>(W_id,  wqT, 1024, 1024, 3072);
  conv_wt<<<dim3(32, 32), 256, 0, stream>>>(W_g1,  wg1T, 1024, 1024, 0);
  conv_wt<<<dim3(1, 32),  256, 0, stream>>>(W_gate,  catGP, 1024, 16, 0);
  conv_wt<<<dim3(3, 32),  256, 0, stream>>>(W_prune, catGP, 1024, 80, 16);
  conv_wt<<<dim3(3, 32),  256, 0, stream>>>(W_g2,    catG2, 1024, 80, 0);
  hipMemsetAsync(catGP + 96 * 1024, 0, 32 * 1024 * sizeof(u16), stream);
  hipMemsetAsync(catG2 + 80 * 1024, 0, 48 * 1024 * sizeof(u16), stream);
  bias_cat<<<1, 256, 0, stream>>>(b_gate, b_prune, b_g2, cb1, cb2);

  // projections: fused qkv+id (bf16 out), gelu(g1) bf16 out, skinny gates
  gemm_mfma<0,1><<<dim3(32, 32), 256, 0, stream>>>(xb, wqT, nullptr, (float*)qkvi, BN_, 4096, 1024, 4096);
  gemm_mfma<1,1><<<dim3(8, 32), 256, 0, stream>>>(xb, wg1T, b_g1, (float*)hb16, BN_, 1024, 1024, 1024);
  gemm_mfma<0,0><<<dim3(1, 32), 256, 0, stream>>>(xb, catGP, cb1, gp, BN_, 128, 1024, 96);
  gemm_mfma<0,0><<<dim3(1, 32), 256, 0, stream>>>(hb16, catG2, cb2, g2l, BN_, 128, 1024, 80);

  // delta rule
  delta_prep<<<1024, 256, 0, stream>>>(qkvi, kb16, tb16, qb16);
  delta_fused<<<64, 256, 0, stream>>>(kb16, tb16, qb16, qkvi, dOutb);

  // fused paths + gating (8 tokens/block)
  zero_ent<<<1, 1, 0, stream>>>(entA);
  paths2<<<512, 256, 0, stream>>>(qkvi, dOutb, gp, g2l,
                                  fir_s, fir_l, mix, idlog, ctxb, entA);

  // output projection + entropy scalar
  conv_wt<<<dim3(32, 32), 256, 0, stream>>>(W_proj, wprojT, 1024, 1024, 0);
  gemm_mfma<0,0><<<dim3(8, 32), 256, 0, stream>>>(ctxb, wprojT, b_proj, out, BN_, 1024, 1024, 1024);
  ent_fin<<<1, 1, 0, stream>>>(entA, out + 4194304);
}

// Round 12
// 291.552 us; speedup vs baseline: 4.6829x; 1.0096x over previous
//
#include <hip/hip_runtime.h>
#include <math.h>

#define B_ 4
#define N_ 1024
#define C_ 1024
#define H_ 16
#define D_ 64
#define P_ 5
#define BN_ (B_*N_)
#define TOK 8

typedef unsigned int u32;
typedef unsigned short u16;
typedef __attribute__((ext_vector_type(8))) short bf16x8;
typedef __attribute__((ext_vector_type(4))) float f32x4;

__device__ __forceinline__ float gelu_f(float x){
  float x3 = x*x*x;
  return 0.5f*x*(1.0f + tanhf(0.7978845608028654f*(x + 0.044715f*x3)));
}
__device__ __forceinline__ float sigmoid_f(float x){ return 1.0f/(1.0f+expf(-x)); }

__device__ __forceinline__ u16 f2bf(float f) {
  u32 u = __float_as_uint(f);
  u32 r = u + 0x7fffu + ((u >> 16) & 1u);
  return (u16)(r >> 16);
}
__device__ __forceinline__ float bf2f(u16 v){ return __uint_as_float(((u32)v) << 16); }

__device__ __forceinline__ void unpack8(uint4 v, float* f) {
  f[0]=bf2f((u16)v.x); f[1]=bf2f((u16)(v.x>>16));
  f[2]=bf2f((u16)v.y); f[3]=bf2f((u16)(v.y>>16));
  f[4]=bf2f((u16)v.z); f[5]=bf2f((u16)(v.z>>16));
  f[6]=bf2f((u16)v.w); f[7]=bf2f((u16)(v.w>>16));
}

__device__ __forceinline__ void gload16(const void* g, void* l) {
  __builtin_amdgcn_global_load_lds((const __attribute__((address_space(1))) u32*)g,
                                   (__attribute__((address_space(3))) u32*)l, 16, 0, 0);
}

// ---------------- fp32 -> bf16 elementwise cast (8 elems/thread) --------------
__global__ __launch_bounds__(256) void conv_bf16(const float* __restrict__ in,
    u16* __restrict__ out, int n8) {
  int i = blockIdx.x * 256 + threadIdx.x;
  if (i >= n8) return;
  const float4* p = (const float4*)in + (size_t)i * 2;
  float4 a = p[0], b = p[1];
  uint4 o;
  o.x = (u32)f2bf(a.x) | ((u32)f2bf(a.y) << 16);
  o.y = (u32)f2bf(a.z) | ((u32)f2bf(a.w) << 16);
  o.z = (u32)f2bf(b.x) | ((u32)f2bf(b.y) << 16);
  o.w = (u32)f2bf(b.z) | ((u32)f2bf(b.w) << 16);
  *(uint4*)(out + (size_t)i * 8) = o;
}

// ------- fp32 [K][Nn] -> bf16 [Nn][K] transpose cast, guarded, with row offset
__global__ __launch_bounds__(256) void conv_wt(const float* __restrict__ W,
    u16* __restrict__ Wt, int K, int Nn, int roff) {
  __shared__ float t[32][33];
  int c0 = blockIdx.x * 32, r0 = blockIdx.y * 32;
  int tx = threadIdx.x & 31, ty = threadIdx.x >> 5;
  #pragma unroll
  for (int i = 0; i < 4; ++i) {
    int r = ty + i * 8;
    t[r][tx] = (c0 + tx < Nn) ? W[(size_t)(r0 + r) * Nn + c0 + tx] : 0.f;
  }
  __syncthreads();
  #pragma unroll
  for (int i = 0; i < 4; ++i) {
    int r = ty + i * 8;
    if (c0 + r < Nn)
      Wt[(size_t)(roff + c0 + r) * K + r0 + tx] = f2bf(t[tx][r]);
  }
}

// --------- bias concat: cb1 = [b_gate(16) | b_prune(80) | 0], cb2 = [b_g2(80)|0]
__global__ void bias_cat(const float* __restrict__ bg, const float* __restrict__ bp,
    const float* __restrict__ bg2, float* __restrict__ cb1, float* __restrict__ cb2) {
  int t = threadIdx.x;
  if (t < 128) cb1[t] = (t < 16) ? bg[t] : (t < 96 ? bp[t - 16] : 0.f);
  else { int c = t - 128; cb2[c] = (c < 80) ? bg2[c] : 0.f; }
}

// ------ bf16 MFMA GEMM, 3-buffer pipelined (counted vmcnt) + 2-way swizzle ----
// C = A(M,K) @ Bt(Nn,K)^T (+bias, +gelu). OBF=1: bf16 output.
// LDS k-slot swizzle: LDS[row][slot] holds global k-seg (slot ^ ((row>>1)&3));
// source-permuted at stage (linear LDS dest), XOR'd back at fragment read.
template<int ACT, int OBF>
__global__ __launch_bounds__(256) void gemm_mfma(const u16* __restrict__ A,
    const u16* __restrict__ Bt, const float* __restrict__ bias,
    float* __restrict__ Cout, int M, int Nn, int K, int Ns) {
  __shared__ __align__(16) u16 lA[3][128 * 32];
  __shared__ __align__(16) u16 lB[3][128 * 32];
  const int tid = threadIdx.x;
  const int lane = tid & 63, wid = tid >> 6;
  const int wr = wid >> 1, wc = wid & 1;
  const int r16 = lane & 15, kq = lane >> 4;
  const int row0 = blockIdx.y * 128, col0 = blockIdx.x * 128;
  const int c0 = wid * 2;
  const int srow = lane >> 2;
  // swizzled global k-seg for this lane's staging slot
  const int skoff = (((lane & 3) ^ ((srow >> 1) & 3)) << 3);
  const int rsw = ((r16 >> 1) & 3);    // read-side slot XOR
  const int T = K >> 5;

  #define STAGE_T(buf, tk) { \
    const int k0_ = (tk) << 5; \
    _Pragma("unroll") \
    for (int s = 0; s < 2; ++s) { \
      int c = c0 + s; \
      int rt = c * 16 + srow; \
      gload16(A  + (size_t)(row0 + rt) * K + k0_ + skoff, &lA[buf][c * 512]); \
      gload16(Bt + (size_t)(col0 + rt) * K + k0_ + skoff, &lB[buf][c * 512]); \
    } }

  f32x4 acc[4][4] = {};
  STAGE_T(0, 0);
  if (T > 1) STAGE_T(1, 1);

  for (int t = 0; t < T; ++t) {
    if (t < T - 1) asm volatile("s_waitcnt vmcnt(4)" ::: "memory");
    else           asm volatile("s_waitcnt vmcnt(0)" ::: "memory");
    __builtin_amdgcn_s_barrier();
    asm volatile("" ::: "memory");
    if (t + 2 < T) { const int bnx = (t + 2) % 3; STAGE_T(bnx, t + 2); }
    const int bc = t % 3;
    const int ko = ((kq ^ rsw) << 3);
    bf16x8 af[4], bfv[4];
    #pragma unroll
    for (int m = 0; m < 4; ++m)
      af[m] = *(const bf16x8*)&lA[bc][(wr * 64 + m * 16 + r16) * 32 + ko];
    #pragma unroll
    for (int n = 0; n < 4; ++n)
      bfv[n] = *(const bf16x8*)&lB[bc][(wc * 64 + n * 16 + r16) * 32 + ko];
    #pragma unroll
    for (int m = 0; m < 4; ++m)
      #pragma unroll
      for (int n = 0; n < 4; ++n)
        acc[m][n] = __builtin_amdgcn_mfma_f32_16x16x32_bf16(af[m], bfv[n], acc[m][n], 0, 0, 0);
  }
  #undef STAGE_T

  #pragma unroll
  for (int n = 0; n < 4; ++n) {
    int col = col0 + wc * 64 + n * 16 + r16;
    if (col >= Ns) continue;
    float bs = bias ? bias[col] : 0.0f;
    #pragma unroll
    for (int m = 0; m < 4; ++m) {
      int rowb = row0 + wr * 64 + m * 16 + kq * 4;
      #pragma unroll
      for (int r = 0; r < 4; ++r) {
        float v = acc[m][n][r] + bs;
        if (ACT == 1) v = gelu_f(v);
        if (OBF) ((u16*)Cout)[(size_t)(rowb + r) * Ns + col] = f2bf(v);
        else     Cout[(size_t)(rowb + r) * Ns + col] = v;
      }
    }
  }
}

// ---------------- DeltaNet prep: norms from bf16 qkvi, M via MFMA, T' ---------
__global__ __launch_bounds__(256) void delta_prep(const u16* __restrict__ qkvi,
    u16* __restrict__ kb, u16* __restrict__ tb, u16* __restrict__ qb) {
  const int bx = blockIdx.x;
  const int bh = bx >> 4, g = bx & 15;
  const int b = bh >> 4, h = bh & 15;
  const int n0 = g * 64;
  const int tid = threadIdx.x;
  __shared__ __align__(16) u16 sKb[64][72];
  __shared__ __align__(16) float sMT[64][68];  // M^T fp32, [c][r], upper zeroed
  __shared__ float sPart[64][8];
  __shared__ float sBeta[64];

  if (tid < 64) sBeta[tid] = 1.0f - 0.9f * (float)(n0 + tid) / 1023.0f;

  const int rr_ = tid >> 2, qd = tid & 3;
  const size_t rowoff = ((size_t)b * N_ + n0 + rr_) * 4096 + h * 64 + qd * 16;
  uint4 k0 = *(const uint4*)(qkvi + rowoff + 1024);
  uint4 k1 = *(const uint4*)(qkvi + rowoff + 1024 + 8);
  uint4 q0 = *(const uint4*)(qkvi + rowoff);
  uint4 q1 = *(const uint4*)(qkvi + rowoff + 8);
  float kv[16], qv[16];
  unpack8(k0, kv); unpack8(k1, kv + 8);
  unpack8(q0, qv); unpack8(q1, qv + 8);
  float ks = 0.f, qs = 0.f;
  #pragma unroll
  for (int j = 0; j < 16; ++j) {
    ks = fmaf(kv[j], kv[j], ks);
    qs = fmaf(qv[j], qv[j], qs);
  }
  sPart[rr_][qd] = ks; sPart[rr_][4 + qd] = qs;
  __syncthreads();
  const float ksc = rsqrtf(sPart[rr_][0]+sPart[rr_][1]+sPart[rr_][2]+sPart[rr_][3] + 1e-6f);
  const float qsc = rsqrtf(sPart[rr_][4]+sPart[rr_][5]+sPart[rr_][6]+sPart[rr_][7] + 1e-6f) * 0.125f;
  const size_t cbase = (size_t)bx * 4096 + rr_ * 64 + qd * 16;
  uint4 ko0, ko1, qo0, qo1;
  u32 kw[8], qw[8];
  #pragma unroll
  for (int j2 = 0; j2 < 8; ++j2) {
    kw[j2] = (u32)f2bf(kv[2*j2] * ksc) | ((u32)f2bf(kv[2*j2+1] * ksc) << 16);
    qw[j2] = (u32)f2bf(qv[2*j2] * qsc) | ((u32)f2bf(qv[2*j2+1] * qsc) << 16);
  }
  ko0 = make_uint4(kw[0], kw[1], kw[2], kw[3]); ko1 = make_uint4(kw[4], kw[5], kw[6], kw[7]);
  qo0 = make_uint4(qw[0], qw[1], qw[2], qw[3]); qo1 = make_uint4(qw[4], qw[5], qw[6], qw[7]);
  *(uint4*)(kb + cbase) = ko0; *(uint4*)(kb + cbase + 8) = ko1;
  *(uint4*)(qb + cbase) = qo0; *(uint4*)(qb + cbase + 8) = qo1;
  *(uint4*)&sKb[rr_][qd * 16] = ko0; *(uint4*)&sKb[rr_][qd * 16 + 8] = ko1;
  __syncthreads();

  {
    const int lane = tid & 63, wv = tid >> 6;
    const int l15 = lane & 15, l4 = lane >> 4;
    bf16x8 ka0 = *(const bf16x8*)&sKb[16*wv + l15][l4*8];
    bf16x8 ka1 = *(const bf16x8*)&sKb[16*wv + l15][32 + l4*8];
    #pragma unroll
    for (int ct = 0; ct < 4; ++ct) {
      bf16x8 kc0 = *(const bf16x8*)&sKb[ct*16 + l15][l4*8];
      bf16x8 kc1 = *(const bf16x8*)&sKb[ct*16 + l15][32 + l4*8];
      f32x4 m = {};
      m = __builtin_amdgcn_mfma_f32_16x16x32_bf16(ka0, kc0, m, 0, 0, 0);
      m = __builtin_amdgcn_mfma_f32_16x16x32_bf16(ka1, kc1, m, 0, 0, 0);
      const int c = ct*16 + l15, rbase = 16*wv + l4*4;
      float4 o;
      o.x = (rbase+0 > c) ? sBeta[rbase+0] * m[0] : 0.f;
      o.y = (rbase+1 > c) ? sBeta[rbase+1] * m[1] : 0.f;
      o.z = (rbase+2 > c) ? sBeta[rbase+2] * m[2] : 0.f;
      o.w = (rbase+3 > c) ? sBeta[rbase+3] * m[3] : 0.f;
      *(float4*)&sMT[c][rbase] = o;
    }
  }
  __syncthreads();

  if (tid < 64) {
    const int c = tid;
    float a[64];
    #pragma unroll
    for (int i = 0; i < 64; ++i) a[i] = (i == c) ? 1.f : 0.f;
    #pragma unroll
    for (int ib = 0; ib < 4; ++ib) {
      #pragma unroll
      for (int i2 = 0; i2 < 16; ++i2) {
        const int i = ib * 16 + i2;
        const float wi = a[i];
        #pragma unroll
        for (int j4 = ib * 4; j4 < 16; ++j4) {
          const float4 m = *(const float4*)&sMT[i][j4 * 4];  // broadcast read
          a[j4*4+0] = fmaf(-m.x, wi, a[j4*4+0]);
          a[j4*4+1] = fmaf(-m.y, wi, a[j4*4+1]);
          a[j4*4+2] = fmaf(-m.z, wi, a[j4*4+2]);
          a[j4*4+3] = fmaf(-m.w, wi, a[j4*4+3]);
        }
      }
    }
    const float bc = sBeta[c];
    const size_t obase = (size_t)bx * 4096;
    #pragma unroll
    for (int i = 0; i < 64; ++i) tb[obase + i * 64 + c] = f2bf(a[i] * bc);
  }
}

// -------- DeltaNet fused scan+output: one block per (b,h), S in MFMA accs -----
__global__ __launch_bounds__(256, 1) void delta_fused(const u16* __restrict__ kb,
    const u16* __restrict__ tb, const u16* __restrict__ qb,
    const u16* __restrict__ qkvi, u16* __restrict__ dOutb) {
  const int bh = blockIdx.x;
  const int b = bh >> 4, h = bh & 15;
  const int tid = threadIdx.x;
  const int lane = tid & 63, wv = tid >> 6;
  const int l15 = lane & 15, l4 = lane >> 4;
  const int fr = tid >> 2, fe0 = (tid & 3) * 16;

  __shared__ __align__(16) u16 sK [64][72];
  __shared__ __align__(16) u16 sKT[64][72];
  __shared__ __align__(16) u16 sT [64][72];
  __shared__ __align__(16) u16 sQ [64][72];
  __shared__ __align__(16) u16 sV [64][72];
  __shared__ __align__(16) u16 sSt[64][72];
  __shared__ __align__(16) u16 sYt[64][72];
  __shared__ __align__(16) u16 sUt[64][72];
  __shared__ __align__(16) u16 sA [64][72];

  f32x4 Sacc[4] = {};

  uint4 pk0, pk1, pt0, pt1, pq0, pq1, pv0, pv1;
  {
    const size_t bs = (size_t)(bh * 16) * 4096;
    const size_t vrow = ((size_t)(b * 1024 + fr)) * 4096 + 2048 + h * 64 + fe0;
    pk0 = *(const uint4*)(kb + bs + tid*16); pk1 = *(const uint4*)(kb + bs + tid*16 + 8);
    pt0 = *(const uint4*)(tb + bs + tid*16); pt1 = *(const uint4*)(tb + bs + tid*16 + 8);
    pq0 = *(const uint4*)(qb + bs + tid*16); pq1 = *(const uint4*)(qb + bs + tid*16 + 8);
    pv0 = *(const uint4*)(qkvi + vrow);      pv1 = *(const uint4*)(qkvi + vrow + 8);
  }

  for (int g = 0; g < 16; ++g) {
    __syncthreads();
    *(uint4*)&sK[fr][fe0] = pk0; *(uint4*)&sK[fr][fe0+8] = pk1;
    *(uint4*)&sT[fr][fe0] = pt0; *(uint4*)&sT[fr][fe0+8] = pt1;
    *(uint4*)&sQ[fr][fe0] = pq0; *(uint4*)&sQ[fr][fe0+8] = pq1;
    *(uint4*)&sV[fr][fe0] = pv0; *(uint4*)&sV[fr][fe0+8] = pv1;
    {
      u32 kk[8] = {pk0.x, pk0.y, pk0.z, pk0.w, pk1.x, pk1.y, pk1.z, pk1.w};
      #pragma unroll
      for (int i = 0; i < 8; ++i) {
        sKT[fe0 + 2*i][fr]     = (u16)kk[i];
        sKT[fe0 + 2*i + 1][fr] = (u16)(kk[i] >> 16);
      }
    }
    #pragma unroll
    for (int dt = 0; dt < 4; ++dt) {
      u32 lo = (u32)f2bf(Sacc[dt][0]) | ((u32)f2bf(Sacc[dt][1]) << 16);
      u32 hi = (u32)f2bf(Sacc[dt][2]) | ((u32)f2bf(Sacc[dt][3]) << 16);
      *(u32*)&sSt[dt*16 + l15][16*wv + l4*4]     = lo;
      *(u32*)&sSt[dt*16 + l15][16*wv + l4*4 + 2] = hi;
    }
    __syncthreads();
    if (g < 15) {
      const size_t bs = (size_t)(bh * 16 + g + 1) * 4096;
      const size_t vrow = ((size_t)(b * 1024 + (g + 1) * 64 + fr)) * 4096 + 2048 + h * 64 + fe0;
      pk0 = *(const uint4*)(kb + bs + tid*16); pk1 = *(const uint4*)(kb + bs + tid*16 + 8);
      pt0 = *(const uint4*)(tb + bs + tid*16); pt1 = *(const uint4*)(tb + bs + tid*16 + 8);
      pq0 = *(const uint4*)(qb + bs + tid*16); pq1 = *(const uint4*)(qb + bs + tid*16 + 8);
      pv0 = *(const uint4*)(qkvi + vrow);      pv1 = *(const uint4*)(qkvi + vrow + 8);
    }
    bf16x8 qf0 = *(const bf16x8*)&sQ[16*wv + l15][l4*8];
    bf16x8 qf1 = *(const bf16x8*)&sQ[16*wv + l15][32 + l4*8];
    bf16x8 kr0 = *(const bf16x8*)&sK[16*wv + l15][l4*8];
    bf16x8 kr1 = *(const bf16x8*)&sK[16*wv + l15][32 + l4*8];
    f32x4 aacc[4] = {}, yacc[4] = {}, oacc[4] = {};
    #pragma unroll
    for (int ct = 0; ct < 4; ++ct) {
      bf16x8 kc0 = *(const bf16x8*)&sK[ct*16 + l15][l4*8];
      bf16x8 kc1 = *(const bf16x8*)&sK[ct*16 + l15][32 + l4*8];
      aacc[ct] = __builtin_amdgcn_mfma_f32_16x16x32_bf16(qf0, kc0, aacc[ct], 0, 0, 0);
      aacc[ct] = __builtin_amdgcn_mfma_f32_16x16x32_bf16(qf1, kc1, aacc[ct], 0, 0, 0);
    }
    #pragma unroll
    for (int dt = 0; dt < 4; ++dt) {
      bf16x8 s0 = *(const bf16x8*)&sSt[dt*16 + l15][l4*8];
      bf16x8 s1 = *(const bf16x8*)&sSt[dt*16 + l15][32 + l4*8];
      yacc[dt] = __builtin_amdgcn_mfma_f32_16x16x32_bf16(kr0, s0, yacc[dt], 0, 0, 0);
      yacc[dt] = __builtin_amdgcn_mfma_f32_16x16x32_bf16(kr1, s1, yacc[dt], 0, 0, 0);
      oacc[dt] = __builtin_amdgcn_mfma_f32_16x16x32_bf16(qf0, s0, oacc[dt], 0, 0, 0);
      oacc[dt] = __builtin_amdgcn_mfma_f32_16x16x32_bf16(qf1, s1, oacc[dt], 0, 0, 0);
    }
    #pragma unroll
    for (int dt = 0; dt < 4; ++dt) {
      float y0 = bf2f(sV[16*wv + l4*4 + 0][dt*16 + l15]) - yacc[dt][0];
      float y1 = bf2f(sV[16*wv + l4*4 + 1][dt*16 + l15]) - yacc[dt][1];
      float y2 = bf2f(sV[16*wv + l4*4 + 2][dt*16 + l15]) - yacc[dt][2];
      float y3 = bf2f(sV[16*wv + l4*4 + 3][dt*16 + l15]) - yacc[dt][3];
      u32 lo = (u32)f2bf(y0) | ((u32)f2bf(y1) << 16);
      u32 hi = (u32)f2bf(y2) | ((u32)f2bf(y3) << 16);
      *(u32*)&sYt[dt*16 + l15][16*wv + l4*4]     = lo;
      *(u32*)&sYt[dt*16 + l15][16*wv + l4*4 + 2] = hi;
    }
    #pragma unroll
    for (int ct = 0; ct < 4; ++ct)
      #pragma unroll
      for (int j = 0; j < 4; ++j) {
        int r = 16*wv + l4*4 + j, c = ct*16 + l15;
        sA[r][c] = f2bf((r >= c) ? aacc[ct][j] : 0.f);
      }
    __syncthreads();
    bf16x8 tf0 = *(const bf16x8*)&sT[16*wv + l15][l4*8];
    bf16x8 tf1 = *(const bf16x8*)&sT[16*wv + l15][32 + l4*8];
    f32x4 uacc[4] = {};
    #pragma unroll
    for (int dt = 0; dt < 4; ++dt) {
      bf16x8 y0 = *(const bf16x8*)&sYt[dt*16 + l15][l4*8];
      bf16x8 y1 = *(const bf16x8*)&sYt[dt*16 + l15][32 + l4*8];
      uacc[dt] = __builtin_amdgcn_mfma_f32_16x16x32_bf16(tf0, y0, uacc[dt], 0, 0, 0);
      uacc[dt] = __builtin_amdgcn_mfma_f32_16x16x32_bf16(tf1, y1, uacc[dt], 0, 0, 0);
    }
    #pragma unroll
    for (int dt = 0; dt < 4; ++dt) {
      u32 lo = (u32)f2bf(uacc[dt][0]) | ((u32)f2bf(uacc[dt][1]) << 16);
      u32 hi = (u32)f2bf(uacc[dt][2]) | ((u32)f2bf(uacc[dt][3]) << 16);
      *(u32*)&sUt[dt*16 + l15][16*wv + l4*4]     = lo;
      *(u32*)&sUt[dt*16 + l15][16*wv + l4*4 + 2] = hi;
    }
    __syncthreads();
    bf16x8 af0 = *(const bf16x8*)&sA[16*wv + l15][l4*8];
    bf16x8 af1 = *(const bf16x8*)&sA[16*wv + l15][32 + l4*8];
    bf16x8 kt0 = *(const bf16x8*)&sKT[16*wv + l15][l4*8];
    bf16x8 kt1 = *(const bf16x8*)&sKT[16*wv + l15][32 + l4*8];
    #pragma unroll
    for (int dt = 0; dt < 4; ++dt) {
      bf16x8 u0 = *(const bf16x8*)&sUt[dt*16 + l15][l4*8];
      bf16x8 u1 = *(const bf16x8*)&sUt[dt*16 + l15][32 + l4*8];
      oacc[dt] = __builtin_amdgcn_mfma_f32_16x16x32_bf16(af0, u0, oacc[dt], 0, 0, 0);
      oacc[dt] = __builtin_amdgcn_mfma_f32_16x16x32_bf16(af1, u1, oacc[dt], 0, 0, 0);
      Sacc[dt] = __builtin_amdgcn_mfma_f32_16x16x32_bf16(kt0, u0, Sacc[dt], 0, 0, 0);
      Sacc[dt] = __builtin_amdgcn_mfma_f32_16x16x32_bf16(kt1, u1, Sacc[dt], 0, 0, 0);
    }
    #pragma unroll
    for (int dt = 0; dt < 4; ++dt)
      #pragma unroll
      for (int j = 0; j < 4; ++j) {
        int r = 16*wv + l4*4 + j;
        dOutb[((size_t)(b * 1024 + g * 64 + r)) * 1024 + h * 64 + dt*16 + l15] = f2bf(oacc[dt][j]);
      }
  }
}

// ------- fused FIR + mix + gating + ctx, 8 tokens/block, bf16 qkvi ------------
__global__ __launch_bounds__(256) void paths2(const u16* __restrict__ qkvi,
    const u16* __restrict__ dOutb, const float* __restrict__ gp,
    const float* __restrict__ g2L, const float* __restrict__ fir_s,
    const float* __restrict__ fir_l, const float* __restrict__ mix,
    const float* __restrict__ idlog, u16* __restrict__ ctxb,
    float* __restrict__ entAcc) {
  const int bid = ((blockIdx.x & 7) << 6) | (blockIdx.x >> 3);  // XCD-contiguous
  const int b = bid >> 7, n0 = (bid & 127) * TOK;
  const int tid = threadIdx.x;
  __shared__ u16 sV[TOK + 6][1024];
  __shared__ u16 sFS[TOK][1024], sFL[TOK][1024];
  __shared__ float sMix[256];
  __shared__ float sWg[TOK][16][5];
  __shared__ float sIdg[TOK][16];
  __shared__ float sEnt[128];
  sMix[tid] = mix[tid];

  #pragma unroll
  for (int i = 0; i < 7; ++i) {
    int r = i * 2 + (tid >> 7);
    int t = n0 - 6 + r;
    int col = (tid & 127) * 8;
    uint4 v = make_uint4(0, 0, 0, 0);
    if (t >= 0)
      v = *(const uint4*)(qkvi + ((size_t)b * 1024 + t) * 4096 + 2048 + col);
    *(uint4*)&sV[r][col] = v;
  }

  if (tid < 128) {
    const int tok = tid >> 4, hh = tid & 15;
    const size_t bn = (size_t)b * 1024 + n0 + tok;
    float pl[5], lp[5];
    #pragma unroll
    for (int p = 0; p < 5; ++p) pl[p] = gp[bn * 96 + 16 + hh * 5 + p];
    float mx = pl[0];
    #pragma unroll
    for (int p = 1; p < 5; ++p) mx = fmaxf(mx, pl[p]);
    float s = 0.f;
    #pragma unroll
    for (int p = 0; p < 5; ++p) { pl[p] = expf(pl[p] - mx); s += pl[p]; }
    float inv = 1.f / s, e1 = 0.f;
    #pragma unroll
    for (int p = 0; p < 5; ++p) {
      float prob = pl[p] * inv;
      lp[p] = logf(prob + 1e-8f);
      e1 -= prob * lp[p];
    }
    float gl[5];
    #pragma unroll
    for (int p = 0; p < 5; ++p) gl[p] = g2L[bn * 80 + hh * 5 + p] + lp[p];
    float mx2 = gl[0];
    #pragma unroll
    for (int p = 1; p < 5; ++p) mx2 = fmaxf(mx2, gl[p]);
    float s2 = 0.f;
    #pragma unroll
    for (int p = 0; p < 5; ++p) { gl[p] = expf(gl[p] - mx2); s2 += gl[p]; }
    float inv2 = 1.f / s2, e2 = 0.f;
    #pragma unroll
    for (int p = 0; p < 5; ++p) {
      float w = gl[p] * inv2;
      sWg[tok][hh][p] = w;
      e2 -= w * logf(w + 1e-8f);
    }
    sEnt[tid] = e1 + e2;
    sIdg[tok][hh] = sigmoid_f(gp[bn * 96 + hh]) * sigmoid_f(idlog[hh]);
  }
  __syncthreads();

  #pragma unroll
  for (int i = 0; i < 4; ++i) {
    const int idx = tid + i * 256;
    float fl7[7], fs3[3];
    #pragma unroll
    for (int j = 0; j < 7; ++j) fl7[j] = fir_l[(size_t)idx * 7 + j];
    #pragma unroll
    for (int j = 0; j < 3; ++j) fs3[j] = fir_s[(size_t)idx * 3 + j];
    #pragma unroll
    for (int tok = 0; tok < TOK; ++tok) {
      float accs = 0.f, accl = 0.f;
      #pragma unroll
      for (int j = 0; j < 7; ++j) {
        float vv = bf2f(sV[tok + j][idx]);
        accl = fmaf(fl7[j], vv, accl);
        if (j >= 4) accs = fmaf(fs3[j - 4], vv, accs);
      }
      sFS[tok][idx] = f2bf(accs);
      sFL[tok][idx] = f2bf(accl);
    }
  }
  __syncthreads();

  #pragma unroll
  for (int i = 0; i < 4; ++i) {
    const int idx = tid + i * 256;
    const int gg = idx >> 6, d = idx & 63;
    #pragma unroll
    for (int tok = 0; tok < TOK; ++tok) {
      float as = bf2f(sFS[tok][idx]), al = bf2f(sFL[tok][idx]);
      #pragma unroll
      for (int hh = 0; hh < 16; ++hh) {
        float m = sMix[hh * 16 + gg];
        as = fmaf(bf2f(sFS[tok][hh * 64 + d]), m, as);
        al = fmaf(bf2f(sFL[tok][hh * 64 + d]), m, al);
      }
      const size_t bn = (size_t)b * 1024 + n0 + tok;
      float w0 = sWg[tok][gg][0], w1 = sWg[tok][gg][1], w2 = sWg[tok][gg][2];
      float w3 = sWg[tok][gg][3], w4 = sWg[tok][gg][4];
      float dv = bf2f(dOutb[bn * 1024 + idx]);
      float vv = bf2f(sV[tok + 6][idx]);
      float iv = bf2f(qkvi[bn * 4096 + 3072 + idx]) * sIdg[tok][gg];
      ctxb[bn * 1024 + idx] = f2bf(w0*as + w1*al + w2*dv + w3*vv + w4*iv);
    }
  }
  if (tid == 0) {
    float s = 0.f;
    #pragma unroll
    for (int i = 0; i < 128; ++i) s += sEnt[i];
    atomicAdd(entAcc, s);
  }
}

__global__ void zero_ent(float* e) { e[0] = 0.f; }
__global__ void ent_fin(const float* __restrict__ e, float* __restrict__ dst) {
  dst[0] = e[0] * (1.0f / 65536.0f);
}

// ---------------- host launcher ----------------------------------------------
extern "C" void kernel_launch(void* const* d_in, const int* in_sizes, int n_in,
                              void* d_out, int out_size, void* d_ws, size_t ws_size,
                              hipStream_t stream) {
  (void)in_sizes; (void)n_in; (void)out_size; (void)ws_size;
  const float* x       = (const float*)d_in[0];
  const float* W_qkv   = (const float*)d_in[1];
  const float* W_id    = (const float*)d_in[2];
  const float* W_gate  = (const float*)d_in[3];
  const float* b_gate  = (const float*)d_in[4];
  const float* idlog   = (const float*)d_in[5];
  const float* fir_s   = (const float*)d_in[6];
  const float* fir_l   = (const float*)d_in[7];
  const float* mix     = (const float*)d_in[8];
  const float* W_prune = (const float*)d_in[9];
  const float* b_prune = (const float*)d_in[10];
  const float* W_g1    = (const float*)d_in[11];
  const float* b_g1    = (const float*)d_in[12];
  const float* W_g2    = (const float*)d_in[13];
  const float* b_g2    = (const float*)d_in[14];
  const float* W_proj  = (const float*)d_in[15];
  const float* b_proj  = (const float*)d_in[16];
  float* out = (float*)d_out;

  float* ws    = (float*)d_ws;
  float* qkviF = ws;                         // bf16 4096x4096 (8,388,608 fl)
  float* gp    = ws + 8388608;               // 4096 x 96 fp32
  float* g2l   = gp + 393216;                // 4096 x 80 fp32
  float* kbF   = g2l + 327680;               // bf16 chunk-major (2,097,152 fl)
  float* tbF   = kbF + 2097152;
  float* qbF   = tbF + 2097152;
  float* dOb   = qbF + 2097152;              // bf16 4096x1024
  float* entA  = dOb + 2097152;              // 1 fl
  float* cb1   = entA + 8;                   // 128 fl
  float* cb2   = cb1 + 128;                  // 128 fl

  u16* qkvi  = (u16*)qkviF;
  u16* kb16  = (u16*)kbF;
  u16* tb16  = (u16*)tbF;
  u16* qb16  = (u16*)qbF;
  u16* dOutb = (u16*)dOb;

  // pre-delta staging aliases (dead before their regions are overwritten)
  u16* xb     = kb16;                        // 4096x1024 bf16
  u16* wqT    = tb16;                        // 4096x1024 bf16 (W_qkv|W_id ^T)
  u16* wg1T   = qb16;                        // 1024x1024 bf16
  u16* catGP  = qb16 + 1048576;              // 128x1024 bf16
  u16* catG2  = qb16 + 1179648;              // 128x1024 bf16
  u16* hb16   = (u16*)dOb;                   // 4096x1024 bf16 (gelu out)
  // post-delta aliases
  u16* ctxb   = kb16;                        // kb dead after delta_fused
  u16* wprojT = tb16;                        // tb dead after delta_fused

  // casts + weight transposes
  conv_bf16<<<2048, 256, 0, stream>>>(x, xb, 524288);
  conv_wt<<<dim3(96, 32), 256, 0, stream>>>(W_qkv, wqT, 1024, 3072, 0);
  conv_wt<<<dim3(32, 32), 256, 0, stream>>>(W_id,  wqT, 1024, 1024, 3072);
  conv_wt<<<dim3(32, 32), 256, 0, stream>>>(W_g1,  wg1T, 1024, 1024, 0);
  conv_wt<<<dim3(1, 32),  256, 0, stream>>>(W_gate,  catGP, 1024, 16, 0);
  conv_wt<<<dim3(3, 32),  256, 0, stream>>>(W_prune, catGP, 1024, 80, 16);
  conv_wt<<<dim3(3, 32),  256, 0, stream>>>(W_g2,    catG2, 1024, 80, 0);
  hipMemsetAsync(catGP + 96 * 1024, 0, 32 * 1024 * sizeof(u16), stream);
  hipMemsetAsync(catG2 + 80 * 1024, 0, 48 * 1024 * sizeof(u16), stream);
  bias_cat<<<1, 256, 0, stream>>>(b_gate, b_prune, b_g2, cb1, cb2);

  // projections: fused qkv+id (bf16 out), gelu(g1) bf16 out, skinny gates
  gemm_mfma<0,1><<<dim3(32, 32), 256, 0, stream>>>(xb, wqT, nullptr, (float*)qkvi, BN_, 4096, 1024, 4096);
  gemm_mfma<1,1><<<dim3(8, 32), 256, 0, stream>>>(xb, wg1T, b_g1, (float*)hb16, BN_, 1024, 1024, 1024);
  gemm_mfma<0,0><<<dim3(1, 32), 256, 0, stream>>>(xb, catGP, cb1, gp, BN_, 128, 1024, 96);
  gemm_mfma<0,0><<<dim3(1, 32), 256, 0, stream>>>(hb16, catG2, cb2, g2l, BN_, 128, 1024, 80);

  // delta rule
  delta_prep<<<1024, 256, 0, stream>>>(qkvi, kb16, tb16, qb16);
  delta_fused<<<64, 256, 0, stream>>>(kb16, tb16, qb16, qkvi, dOutb);

  // fused paths + gating (8 tokens/block)
  zero_ent<<<1, 1, 0, stream>>>(entA);
  paths2<<<512, 256, 0, stream>>>(qkvi, dOutb, gp, g2l,
                                  fir_s, fir_l, mix, idlog, ctxb, entA);

  // output projection + entropy scalar
  conv_wt<<<dim3(32, 32), 256, 0, stream>>>(W_proj, wprojT, 1024, 1024, 0);
  gemm_mfma<0,0><<<dim3(8, 32), 256, 0, stream>>>(ctxb, wprojT, b_proj, out, BN_, 1024, 1024, 1024);
  ent_fin<<<1, 1, 0, stream>>>(entA, out + 4194304);
}